// Round 5
// baseline (503.387 us; speedup 1.0000x reference)
//
#include <hip/hip_runtime.h>
#include <cstdint>
#include <cstddef>

#define HDIM 128
#define DDIM 64
#define NTYPES 5
#define NGRAPHS 16
#define POOL_P 16
#define EPB 64   // edges (or atoms) per block, one per lane

static __device__ __forceinline__ float silu_f(float v) {
    return v / (1.0f + __expf(-v));
}

static __device__ __forceinline__ float4 ld4(const float* p) {
    return *reinterpret_cast<const float4*>(p);
}

static __device__ __forceinline__ void st4(float* p, float4 v) {
    *reinterpret_cast<float4*>(p) = v;
}

static __device__ __forceinline__ float4 add4(float4 a, float4 b) {
    return make_float4(a.x + b.x, a.y + b.y, a.z + b.z, a.w + b.w);
}

static __device__ __forceinline__ void silu_acc4(float4& s, float4 v) {
    s.x += silu_f(v.x);
    s.y += silu_f(v.y);
    s.z += silu_f(v.z);
    s.w += silu_f(v.w);
}

// ---------------- CSR build ----------------
__global__ void __launch_bounds__(256) count_k(const int* __restrict__ bdst,
                                               int* __restrict__ cnt, int BE) {
    int i = blockIdx.x * 256 + threadIdx.x;
    if (i < BE)
        __hip_atomic_fetch_add(&cnt[bdst[i]], 1, __ATOMIC_RELAXED, __HIP_MEMORY_SCOPE_AGENT);
}

__global__ void __launch_bounds__(256) bsum_k(const int* __restrict__ cnt,
                                              int* __restrict__ bsum, int E) {
    __shared__ int red[256];
    int t = threadIdx.x;
    int i = blockIdx.x * 256 + t;
    red[t] = (i < E) ? cnt[i] : 0;
    __syncthreads();
    #pragma unroll
    for (int off = 128; off > 0; off >>= 1) {
        if (t < off) red[t] += red[t + off];
        __syncthreads();
    }
    if (t == 0) bsum[blockIdx.x] = red[0];
}

__global__ void __launch_bounds__(1024) bscan_k(const int* __restrict__ bsum,
                                                int* __restrict__ bpre, int NB) {
    __shared__ int sh[1024];
    int t = threadIdx.x;
    int v0 = (t < NB) ? bsum[t] : 0;
    sh[t] = v0;
    __syncthreads();
    for (int off = 1; off < 1024; off <<= 1) {
        int v = (t >= off) ? sh[t - off] : 0;
        __syncthreads();
        sh[t] += v;
        __syncthreads();
    }
    if (t < NB) bpre[t] = sh[t] - v0;
}

__global__ void __launch_bounds__(256) offs_k(const int* __restrict__ cnt,
                                              const int* __restrict__ bpre,
                                              int* __restrict__ offs,
                                              int* __restrict__ cursor, int E) {
    __shared__ int sh[256];
    int t = threadIdx.x;
    int i = blockIdx.x * 256 + t;
    int v0 = (i < E) ? cnt[i] : 0;
    sh[t] = v0;
    __syncthreads();
    for (int off = 1; off < 256; off <<= 1) {
        int v = (t >= off) ? sh[t - off] : 0;
        __syncthreads();
        sh[t] += v;
        __syncthreads();
    }
    int ex = sh[t] - v0 + bpre[blockIdx.x];
    if (i < E) { offs[i] = ex; cursor[i] = ex; }
    if (i == E - 1) offs[E] = ex + v0;
}

__global__ void __launch_bounds__(256) scatter_k(const int* __restrict__ bsrc,
                                                 const int* __restrict__ bdst,
                                                 int* __restrict__ cursor,
                                                 int* __restrict__ srclist, int BE) {
    int i = blockIdx.x * 256 + threadIdx.x;
    if (i < BE) {
        int d = bdst[i];
        int p = __hip_atomic_fetch_add(&cursor[d], 1, __ATOMIC_RELAXED,
                                       __HIP_MEMORY_SCOPE_AGENT);
        srclist[p] = bsrc[i];
    }
}

// tt for BOTH layers
__global__ void __launch_bounds__(64) tt2_k(const float* __restrict__ emb,
                                            const float* __restrict__ mw1,
                                            const float* __restrict__ mb1,
                                            float* __restrict__ tt) {
    int b = blockIdx.x;
    int l = b / NTYPES, t = b % NTYPES, j = threadIdx.x;
    const float* embl = emb + (size_t)l * NTYPES * DDIM + (size_t)t * DDIM;
    const float* w1 = mw1 + (size_t)l * 192 * DDIM;
    float s = mb1[l * DDIM + j];
    #pragma unroll 8
    for (int k = 0; k < DDIM; ++k)
        s = fmaf(embl[k], w1[(HDIM + k) * DDIM + j], s);
    tt[(size_t)b * DDIM + j] = s;
}

// ---------------- atom-side projection ----------------
// pa[a] = AF[a] @ iw1[0:128]; qa[a] = AF[a] @ iw1[128:256]; na[a] = ||AF[a]||
// block = 4 waves; lane = atom; wave w owns outputs [16w,16w+16) of BOTH pa,qa.
__global__ void __launch_bounds__(256) atom_proj_k(
    const float* __restrict__ AF, const float* __restrict__ iw1,
    float* __restrict__ pa, float* __restrict__ qa, float* __restrict__ na, int N) {
    int lane = threadIdx.x & 63;
    int w = __builtin_amdgcn_readfirstlane((int)(threadIdx.x >> 6));
    int a = blockIdx.x * EPB + lane;
    bool ok = a < N;
    int ai = ok ? a : 0;
    const float* h = AF + (size_t)ai * HDIM;
    int j0 = w * 16;

    float ap[16], aq[16];
    #pragma unroll
    for (int jj = 0; jj < 16; ++jj) { ap[jj] = 0.f; aq[jj] = 0.f; }
    float nrm = 0.f;
    #pragma unroll 4
    for (int c = 0; c < 16; ++c) {          // K = 128 in chunks of 8
        float4 v0 = ld4(h + c * 8), v1 = ld4(h + c * 8 + 4);
        if (w == 0)
            nrm += v0.x * v0.x + v0.y * v0.y + v0.z * v0.z + v0.w * v0.w
                 + v1.x * v1.x + v1.y * v1.y + v1.z * v1.z + v1.w * v1.w;
        float xv[8] = {v0.x, v0.y, v0.z, v0.w, v1.x, v1.y, v1.z, v1.w};
        const float* wt = iw1 + (size_t)(c * 8) * DDIM + j0;
        const float* wb = iw1 + (size_t)(HDIM + c * 8) * DDIM + j0;
        #pragma unroll
        for (int kk = 0; kk < 8; ++kk) {
            const float* wtk = wt + (size_t)kk * DDIM;
            const float* wbk = wb + (size_t)kk * DDIM;
            #pragma unroll
            for (int jj = 0; jj < 16; ++jj) {
                ap[jj] = fmaf(xv[kk], wtk[jj], ap[jj]);
                aq[jj] = fmaf(xv[kk], wbk[jj], aq[jj]);
            }
        }
    }
    if (ok) {
        float* pr = pa + (size_t)a * DDIM + j0;
        float* qr = qa + (size_t)a * DDIM + j0;
        st4(pr + 0,  make_float4(ap[0],  ap[1],  ap[2],  ap[3]));
        st4(pr + 4,  make_float4(ap[4],  ap[5],  ap[6],  ap[7]));
        st4(pr + 8,  make_float4(ap[8],  ap[9],  ap[10], ap[11]));
        st4(pr + 12, make_float4(ap[12], ap[13], ap[14], ap[15]));
        st4(qr + 0,  make_float4(aq[0],  aq[1],  aq[2],  aq[3]));
        st4(qr + 4,  make_float4(aq[4],  aq[5],  aq[6],  aq[7]));
        st4(qr + 8,  make_float4(aq[8],  aq[9],  aq[10], aq[11]));
        st4(qr + 12, make_float4(aq[12], aq[13], aq[14], aq[15]));
        if (w == 0) na[a] = sqrtf(nrm);
    }
}

// ---------------- bond init (from atom projections) + layer-0 proj ----------------
// acc = pa[row] + qa[col] + b1; x = silu(acc)@iw2 + b2; sim via 4-way wave-split dot.
__global__ void __launch_bounds__(256) bond_init2_k(
    const float* __restrict__ AF, const int* __restrict__ row, const int* __restrict__ col,
    const float* __restrict__ pa, const float* __restrict__ qa, const float* __restrict__ na,
    const float* __restrict__ b1, const float* __restrict__ w2, const float* __restrict__ b2,
    const float* __restrict__ w1p /*[192][64] layer0 mw1*/,
    float* __restrict__ x, int* __restrict__ bt,
    float* __restrict__ pd, float* __restrict__ ps, int E) {
    __shared__ float hbuf[EPB][DDIM + 1];
    __shared__ float dotb[EPB][5];
    int lane = threadIdx.x & 63;
    int w = __builtin_amdgcn_readfirstlane((int)(threadIdx.x >> 6));
    int e = blockIdx.x * EPB + lane;
    bool ok = e < E;
    int eidx = ok ? e : 0;
    int r = row[eidx], c = col[eidx];
    int j0 = w * 16;

    // partial dot over K-chunk [32w, 32w+32)
    {
        const float* hi = AF + (size_t)r * HDIM + w * 32;
        const float* hj = AF + (size_t)c * HDIM + w * 32;
        float d = 0.f;
        #pragma unroll
        for (int k = 0; k < 32; k += 4) {
            float4 a4 = ld4(hi + k), b4 = ld4(hj + k);
            d += a4.x * b4.x + a4.y * b4.y + a4.z * b4.z + a4.w * b4.w;
        }
        dotb[lane][w] = d;
    }

    // layer-1 hidden slice: silu(pa[r] + qa[c] + b1)
    {
        const float* pr = pa + (size_t)r * DDIM + j0;
        const float* qc = qa + (size_t)c * DDIM + j0;
        #pragma unroll
        for (int q = 0; q < 4; ++q) {
            float4 pv = ld4(pr + q * 4);
            float4 qv = ld4(qc + q * 4);
            hbuf[lane][j0 + q * 4 + 0] = silu_f(pv.x + qv.x + b1[j0 + q * 4 + 0]);
            hbuf[lane][j0 + q * 4 + 1] = silu_f(pv.y + qv.y + b1[j0 + q * 4 + 1]);
            hbuf[lane][j0 + q * 4 + 2] = silu_f(pv.z + qv.z + b1[j0 + q * 4 + 2]);
            hbuf[lane][j0 + q * 4 + 3] = silu_f(pv.w + qv.w + b1[j0 + q * 4 + 3]);
        }
    }
    __syncthreads();

    if (w == 0) {
        float dot = dotb[lane][0] + dotb[lane][1] + dotb[lane][2] + dotb[lane][3];
        float nr = fmaxf(na[r], 1e-8f), nc = fmaxf(na[c], 1e-8f);
        float sim = dot / (nr * nc);
        int t = 0;
        if (sim > 0.8f) t = 1;
        if (sim > 0.9f) t = 2;
        if (sim < 0.3f) t = 3;
        if (ok) bt[e] = t;
    }

    // layer-2: x = h @ w2 + b2 (K=64 from LDS)
    float o[16];
    #pragma unroll
    for (int jj = 0; jj < 16; ++jj) o[jj] = b2[j0 + jj];
    #pragma unroll 4
    for (int k = 0; k < DDIM; ++k) {
        float hk = hbuf[lane][k];
        const float* wk = w2 + (size_t)k * DDIM + j0;
        #pragma unroll
        for (int jj = 0; jj < 16; ++jj) o[jj] = fmaf(hk, wk[jj], o[jj]);
    }
    if (ok) {
        float* xr = x + (size_t)e * DDIM + j0;
        st4(xr + 0,  make_float4(o[0],  o[1],  o[2],  o[3]));
        st4(xr + 4,  make_float4(o[4],  o[5],  o[6],  o[7]));
        st4(xr + 8,  make_float4(o[8],  o[9],  o[10], o[11]));
        st4(xr + 12, make_float4(o[12], o[13], o[14], o[15]));
    }
    __syncthreads();
    #pragma unroll
    for (int jj = 0; jj < 16; ++jj) hbuf[lane][j0 + jj] = o[jj];   // x row
    __syncthreads();

    // proj (layer 0): pd = x@W1[0:64], ps = x@W1[64:128]
    float apd[16], aps[16];
    #pragma unroll
    for (int jj = 0; jj < 16; ++jj) { apd[jj] = 0.f; aps[jj] = 0.f; }
    #pragma unroll 4
    for (int k = 0; k < DDIM; ++k) {
        float xk = hbuf[lane][k];
        const float* wd = w1p + (size_t)k * DDIM + j0;
        const float* wsv = w1p + (size_t)(DDIM + k) * DDIM + j0;
        #pragma unroll
        for (int jj = 0; jj < 16; ++jj) {
            apd[jj] = fmaf(xk, wd[jj], apd[jj]);
            aps[jj] = fmaf(xk, wsv[jj], aps[jj]);
        }
    }
    if (ok) {
        float* pr = pd + (size_t)e * DDIM + j0;
        float* qr = ps + (size_t)e * DDIM + j0;
        st4(pr + 0,  make_float4(apd[0],  apd[1],  apd[2],  apd[3]));
        st4(pr + 4,  make_float4(apd[4],  apd[5],  apd[6],  apd[7]));
        st4(pr + 8,  make_float4(apd[8],  apd[9],  apd[10], apd[11]));
        st4(pr + 12, make_float4(apd[12], apd[13], apd[14], apd[15]));
        st4(qr + 0,  make_float4(aps[0],  aps[1],  aps[2],  aps[3]));
        st4(qr + 4,  make_float4(aps[4],  aps[5],  aps[6],  aps[7]));
        st4(qr + 8,  make_float4(aps[8],  aps[9],  aps[10], aps[11]));
        st4(qr + 12, make_float4(aps[12], aps[13], aps[14], aps[15]));
    }
}

// proj for layer 1 (x from global)
__global__ void __launch_bounds__(256) proj_k(const float* __restrict__ x,
                                              const float* __restrict__ w1 /*[192][64]*/,
                                              float* __restrict__ pd, float* __restrict__ ps,
                                              int E) {
    int lane = threadIdx.x & 63;
    int w = __builtin_amdgcn_readfirstlane((int)(threadIdx.x >> 6));
    int e = blockIdx.x * EPB + lane;
    bool ok = e < E;
    int eidx = ok ? e : 0;
    int j0 = w * 16;
    const float* xr = x + (size_t)eidx * DDIM;

    float apd[16], aps[16];
    #pragma unroll
    for (int jj = 0; jj < 16; ++jj) { apd[jj] = 0.f; aps[jj] = 0.f; }
    #pragma unroll 2
    for (int c = 0; c < 16; ++c) {
        float4 v = ld4(xr + c * 4);
        float xv[4] = {v.x, v.y, v.z, v.w};
        #pragma unroll
        for (int kk = 0; kk < 4; ++kk) {
            int k = c * 4 + kk;
            const float* wd = w1 + (size_t)k * DDIM + j0;
            const float* wsv = w1 + (size_t)(DDIM + k) * DDIM + j0;
            #pragma unroll
            for (int jj = 0; jj < 16; ++jj) {
                apd[jj] = fmaf(xv[kk], wd[jj], apd[jj]);
                aps[jj] = fmaf(xv[kk], wsv[jj], aps[jj]);
            }
        }
    }
    if (ok) {
        float* pr = pd + (size_t)e * DDIM + j0;
        float* qr = ps + (size_t)e * DDIM + j0;
        st4(pr + 0,  make_float4(apd[0],  apd[1],  apd[2],  apd[3]));
        st4(pr + 4,  make_float4(apd[4],  apd[5],  apd[6],  apd[7]));
        st4(pr + 8,  make_float4(apd[8],  apd[9],  apd[10], apd[11]));
        st4(pr + 12, make_float4(apd[12], apd[13], apd[14], apd[15]));
        st4(qr + 0,  make_float4(aps[0],  aps[1],  aps[2],  aps[3]));
        st4(qr + 4,  make_float4(aps[4],  aps[5],  aps[6],  aps[7]));
        st4(qr + 8,  make_float4(aps[8],  aps[9],  aps[10], aps[11]));
        st4(qr + 12, make_float4(aps[12], aps[13], aps[14], aps[15]));
    }
}

// ---------------- fused gather + mm + update ----------------
__global__ void __launch_bounds__(256) layer_k(
    float* __restrict__ x, const float* __restrict__ pd, const float* __restrict__ ps,
    const float* __restrict__ tt_l, const int* __restrict__ bt,
    const int* __restrict__ offs, const int* __restrict__ srclist,
    const int* __restrict__ cnt,
    const float* __restrict__ w2m, const float* __restrict__ b2m,
    const float* __restrict__ uw1 /*[128][64]*/, const float* __restrict__ ub1,
    const float* __restrict__ uw2 /*[64][64]*/, const float* __restrict__ ub2, int E) {
    __shared__ float sb[EPB][DDIM + 1];
    __shared__ float mb[EPB][DDIM + 1];
    int lane = threadIdx.x & 63;
    int w = __builtin_amdgcn_readfirstlane((int)(threadIdx.x >> 6));
    int e = blockIdx.x * EPB + lane;
    bool ok = e < E;
    int eidx = ok ? e : 0;
    int j0 = w * 16;

    // ---- P1: gather (thread = (d_local, q)), 2-way unrolled ----
    {
        int d_local = threadIdx.x >> 2, q = threadIdx.x & 3;
        int d = blockIdx.x * EPB + d_local;
        if (d < E) {
            int jq = q * 16;
            const float* pr = pd + (size_t)d * DDIM + jq;
            const float* tp = tt_l + (size_t)bt[d] * DDIM + jq;
            float4 b0 = add4(ld4(pr + 0),  ld4(tp + 0));
            float4 b1 = add4(ld4(pr + 4),  ld4(tp + 4));
            float4 b2 = add4(ld4(pr + 8),  ld4(tp + 8));
            float4 b3 = add4(ld4(pr + 12), ld4(tp + 12));
            float4 s0 = make_float4(0, 0, 0, 0), s1 = s0, s2 = s0, s3 = s0;
            int p0 = offs[d], p1 = offs[d + 1];
            int p = p0;
            for (; p + 2 <= p1; p += 2) {
                const float* sa = ps + (size_t)srclist[p] * DDIM + jq;
                const float* sc = ps + (size_t)srclist[p + 1] * DDIM + jq;
                float4 u0 = ld4(sa + 0), u1 = ld4(sa + 4);
                float4 u2 = ld4(sa + 8), u3 = ld4(sa + 12);
                float4 v0 = ld4(sc + 0), v1 = ld4(sc + 4);
                float4 v2 = ld4(sc + 8), v3 = ld4(sc + 12);
                silu_acc4(s0, add4(b0, u0));
                silu_acc4(s1, add4(b1, u1));
                silu_acc4(s2, add4(b2, u2));
                silu_acc4(s3, add4(b3, u3));
                silu_acc4(s0, add4(b0, v0));
                silu_acc4(s1, add4(b1, v1));
                silu_acc4(s2, add4(b2, v2));
                silu_acc4(s3, add4(b3, v3));
            }
            if (p < p1) {
                const float* sa = ps + (size_t)srclist[p] * DDIM + jq;
                float4 u0 = ld4(sa + 0), u1 = ld4(sa + 4);
                float4 u2 = ld4(sa + 8), u3 = ld4(sa + 12);
                silu_acc4(s0, add4(b0, u0));
                silu_acc4(s1, add4(b1, u1));
                silu_acc4(s2, add4(b2, u2));
                silu_acc4(s3, add4(b3, u3));
            }
            st4(&sb[d_local][jq + 0],  s0);
            st4(&sb[d_local][jq + 4],  s1);
            st4(&sb[d_local][jq + 8],  s2);
            st4(&sb[d_local][jq + 12], s3);
        }
    }
    __syncthreads();

    // ---- P2: mm ----
    float degf = (float)cnt[eidx];
    float inv = 1.0f / fmaxf(degf, 1.0f);
    {
        float am[16];
        #pragma unroll
        for (int jj = 0; jj < 16; ++jj) am[jj] = degf * b2m[j0 + jj];
        #pragma unroll 4
        for (int k = 0; k < DDIM; ++k) {
            float sk = sb[lane][k];
            const float* wk = w2m + (size_t)k * DDIM + j0;
            #pragma unroll
            for (int jj = 0; jj < 16; ++jj) am[jj] = fmaf(sk, wk[jj], am[jj]);
        }
        #pragma unroll
        for (int jj = 0; jj < 16; ++jj) mb[lane][j0 + jj] = am[jj] * inv;
    }
    __syncthreads();

    // ---- P3: u-layer1 (mm from LDS, x from global) ----
    const float* xr = x + (size_t)eidx * DDIM;
    {
        float ah[16];
        #pragma unroll
        for (int jj = 0; jj < 16; ++jj) ah[jj] = ub1[j0 + jj];
        #pragma unroll 4
        for (int k = 0; k < DDIM; ++k) {
            float mk = mb[lane][k];
            const float* wk = uw1 + (size_t)k * DDIM + j0;
            #pragma unroll
            for (int jj = 0; jj < 16; ++jj) ah[jj] = fmaf(mk, wk[jj], ah[jj]);
        }
        #pragma unroll 2
        for (int c = 0; c < 16; ++c) {
            float4 v = ld4(xr + c * 4);
            float xv[4] = {v.x, v.y, v.z, v.w};
            #pragma unroll
            for (int kk = 0; kk < 4; ++kk) {
                const float* wk = uw1 + (size_t)(DDIM + c * 4 + kk) * DDIM + j0;
                #pragma unroll
                for (int jj = 0; jj < 16; ++jj) ah[jj] = fmaf(xv[kk], wk[jj], ah[jj]);
            }
        }
        #pragma unroll
        for (int jj = 0; jj < 16; ++jj) sb[lane][j0 + jj] = silu_f(ah[jj]);
    }
    __syncthreads();

    // ---- P4: u-layer2 + residual ----
    {
        float o[16];
        #pragma unroll
        for (int jj = 0; jj < 16; ++jj) o[jj] = ub2[j0 + jj];
        #pragma unroll 4
        for (int k = 0; k < DDIM; ++k) {
            float hk = sb[lane][k];
            const float* wk = uw2 + (size_t)k * DDIM + j0;
            #pragma unroll
            for (int jj = 0; jj < 16; ++jj) o[jj] = fmaf(hk, wk[jj], o[jj]);
        }
        if (ok) {
            float* xw = x + (size_t)e * DDIM + j0;
            #pragma unroll
            for (int q = 0; q < 4; ++q) {
                float4 xo = ld4(xw + q * 4);
                xo.x += o[q * 4 + 0];
                xo.y += o[q * 4 + 1];
                xo.z += o[q * 4 + 2];
                xo.w += o[q * 4 + 3];
                st4(xw + q * 4, xo);
            }
        }
    }
}

// ---------------- pooling ----------------
static __device__ __forceinline__ int lower_bound_bb(const int* __restrict__ row,
                                                     const int* __restrict__ batch,
                                                     int E, int g) {
    int lo = 0, hi = E;
    while (lo < hi) {
        int m = (lo + hi) >> 1;
        if (batch[row[m]] < g) lo = m + 1; else hi = m;
    }
    return lo;
}

__global__ void __launch_bounds__(64) pool_partial_k(
    const float* __restrict__ x, const int* __restrict__ row, const int* __restrict__ batch,
    float* __restrict__ gfeat, int E) {
    int g = blockIdx.x, p = blockIdx.y, j = threadIdx.x;
    int s = lower_bound_bb(row, batch, E, g);
    int t = lower_bound_bb(row, batch, E, g + 1);
    int cnt = t - s;
    int chunk = (cnt + POOL_P - 1) / POOL_P;
    int e0 = s + p * chunk;
    int e1 = min(e0 + chunk, t);
    float sum = 0.f;
    for (int e = e0; e < e1; ++e) sum += x[(size_t)e * DDIM + j];
    if (e0 < e1)
        __hip_atomic_fetch_add(&gfeat[g * DDIM + j], sum, __ATOMIC_RELAXED,
                               __HIP_MEMORY_SCOPE_AGENT);
}

__global__ void __launch_bounds__(64) pool_final_k(
    const int* __restrict__ row, const int* __restrict__ batch,
    float* __restrict__ gfeat, int E) {
    int g = blockIdx.x, j = threadIdx.x;
    int s = lower_bound_bb(row, batch, E, g);
    int t = lower_bound_bb(row, batch, E, g + 1);
    float cnt = fmaxf((float)(t - s), 1.0f);
    gfeat[g * DDIM + j] /= cnt;
}

extern "C" void kernel_launch(void* const* d_in, const int* in_sizes, int n_in,
                              void* d_out, int out_size, void* d_ws, size_t ws_size,
                              hipStream_t stream) {
    (void)n_in; (void)out_size; (void)ws_size;
    const float* AF    = (const float*)d_in[0];
    const int*   batch = (const int*)d_in[3];
    const int*   edge_index      = (const int*)d_in[4];
    const int*   bond_edge_index = (const int*)d_in[5];
    const float* iw1 = (const float*)d_in[6];
    const float* ib1 = (const float*)d_in[7];
    const float* iw2 = (const float*)d_in[8];
    const float* ib2 = (const float*)d_in[9];
    const float* emb = (const float*)d_in[10];
    const float* mw1 = (const float*)d_in[11];
    const float* mb1 = (const float*)d_in[12];
    const float* mw2 = (const float*)d_in[13];
    const float* mb2 = (const float*)d_in[14];
    const float* uw1 = (const float*)d_in[15];
    const float* ub1 = (const float*)d_in[16];
    const float* uw2 = (const float*)d_in[17];
    const float* ub2 = (const float*)d_in[18];

    const int N  = in_sizes[0] / HDIM;
    const int E  = in_sizes[4] / 2;
    const int BE = in_sizes[5] / 2;
    const int NB = (E + 255) / 256;
    const int EB = (E + EPB - 1) / EPB;
    const int AB = (N + EPB - 1) / EPB;

    float* xout  = (float*)d_out;                 // [E,64]
    float* gfeat = xout + (size_t)E * DDIM;       // [16,64]

    // workspace layout
    char* w = (char*)d_ws;
    float* tt       = (float*)w;  w += sizeof(float) * 2 * NTYPES * DDIM;
    int*   cnt      = (int*)w;    w += sizeof(int) * E;
    int*   offs     = (int*)w;    w += sizeof(int) * (E + 1);
    int*   cursor   = (int*)w;    w += sizeof(int) * E;
    int*   bt       = (int*)w;    w += sizeof(int) * E;
    int*   bsum     = (int*)w;    w += sizeof(int) * 1024;
    int*   bpre     = (int*)w;    w += sizeof(int) * 1024;
    int*   srclist  = (int*)w;    w += sizeof(int) * BE;
    w = (char*)(((uintptr_t)w + 15) & ~(uintptr_t)15);
    float* pd       = (float*)w;  w += sizeof(float) * (size_t)E * DDIM;
    float* ps       = (float*)w;  w += sizeof(float) * (size_t)E * DDIM;
    float* pa       = (float*)w;  w += sizeof(float) * (size_t)N * DDIM;
    float* qa       = (float*)w;  w += sizeof(float) * (size_t)N * DDIM;
    float* na       = (float*)w;  w += sizeof(float) * (size_t)N;

    const int* row  = edge_index;
    const int* col  = edge_index + E;
    const int* bsrc = bond_edge_index;
    const int* bdst = bond_edge_index + BE;

    // CSR build
    hipMemsetAsync(cnt, 0, (size_t)E * sizeof(int), stream);
    count_k<<<(BE + 255) / 256, 256, 0, stream>>>(bdst, cnt, BE);
    bsum_k<<<NB, 256, 0, stream>>>(cnt, bsum, E);
    bscan_k<<<1, 1024, 0, stream>>>(bsum, bpre, NB);
    offs_k<<<NB, 256, 0, stream>>>(cnt, bpre, offs, cursor, E);
    scatter_k<<<(BE + 255) / 256, 256, 0, stream>>>(bsrc, bdst, cursor, srclist, BE);

    // bond-type embeddings for both layers
    tt2_k<<<2 * NTYPES, 64, 0, stream>>>(emb, mw1, mb1, tt);

    // atom projections, then bond init + layer-0 proj
    atom_proj_k<<<AB, 256, 0, stream>>>(AF, iw1, pa, qa, na, N);
    bond_init2_k<<<EB, 256, 0, stream>>>(AF, row, col, pa, qa, na, ib1, iw2, ib2,
                                         mw1 /* layer 0 */, xout, bt, pd, ps, E);

    for (int l = 0; l < 2; ++l) {
        if (l > 0)
            proj_k<<<EB, 256, 0, stream>>>(xout, mw1 + (size_t)l * 192 * 64, pd, ps, E);
        layer_k<<<EB, 256, 0, stream>>>(
            xout, pd, ps, tt + (size_t)l * NTYPES * DDIM, bt, offs, srclist, cnt,
            mw2 + (size_t)l * DDIM * DDIM, mb2 + (size_t)l * DDIM,
            uw1 + (size_t)l * 128 * 64, ub1 + (size_t)l * DDIM,
            uw2 + (size_t)l * DDIM * DDIM, ub2 + (size_t)l * DDIM, E);
    }

    hipMemsetAsync(gfeat, 0, NGRAPHS * DDIM * sizeof(float), stream);
    dim3 pg(NGRAPHS, POOL_P);
    pool_partial_k<<<pg, 64, 0, stream>>>(xout, row, batch, gfeat, E);
    pool_final_k<<<NGRAPHS, 64, 0, stream>>>(row, batch, gfeat, E);
}

// Round 6
// 499.171 us; speedup vs baseline: 1.0084x; 1.0084x over previous
//
#include <hip/hip_runtime.h>
#include <cstdint>
#include <cstddef>

#define HDIM 128
#define DDIM 64
#define NTYPES 5
#define NGRAPHS 16
#define POOL_P 16
#define EPB 64   // edges (or atoms) per block, one per lane

static __device__ __forceinline__ float silu_f(float v) {
    return v / (1.0f + __expf(-v));
}

static __device__ __forceinline__ float4 ld4(const float* p) {
    return *reinterpret_cast<const float4*>(p);
}

static __device__ __forceinline__ void st4(float* p, float4 v) {
    *reinterpret_cast<float4*>(p) = v;
}

static __device__ __forceinline__ float4 add4(float4 a, float4 b) {
    return make_float4(a.x + b.x, a.y + b.y, a.z + b.z, a.w + b.w);
}

static __device__ __forceinline__ void silu_acc4(float4& s, float4 v) {
    s.x += silu_f(v.x);
    s.y += silu_f(v.y);
    s.z += silu_f(v.z);
    s.w += silu_f(v.w);
}

// XCD-affinity swizzle: launched grid is 8*chunk blocks; consecutive dispatch
// ids round-robin across the 8 XCDs (heuristic), so give XCD k the contiguous
// logical range [k*chunk, (k+1)*chunk) for L2 locality of graph-local gathers.
static __device__ __forceinline__ int xcd_logical_block() {
    int chunk = (int)(gridDim.x >> 3);
    return (int)(blockIdx.x & 7) * chunk + (int)(blockIdx.x >> 3);
}

// ---------------- CSR build ----------------
__global__ void __launch_bounds__(256) count_k(const int* __restrict__ bdst,
                                               int* __restrict__ cnt, int BE) {
    int i = blockIdx.x * 256 + threadIdx.x;
    if (i < BE)
        __hip_atomic_fetch_add(&cnt[bdst[i]], 1, __ATOMIC_RELAXED, __HIP_MEMORY_SCOPE_AGENT);
}

__global__ void __launch_bounds__(256) bsum_k(const int* __restrict__ cnt,
                                              int* __restrict__ bsum, int E) {
    __shared__ int red[256];
    int t = threadIdx.x;
    int i = blockIdx.x * 256 + t;
    red[t] = (i < E) ? cnt[i] : 0;
    __syncthreads();
    #pragma unroll
    for (int off = 128; off > 0; off >>= 1) {
        if (t < off) red[t] += red[t + off];
        __syncthreads();
    }
    if (t == 0) bsum[blockIdx.x] = red[0];
}

__global__ void __launch_bounds__(1024) bscan_k(const int* __restrict__ bsum,
                                                int* __restrict__ bpre, int NB) {
    __shared__ int sh[1024];
    int t = threadIdx.x;
    int v0 = (t < NB) ? bsum[t] : 0;
    sh[t] = v0;
    __syncthreads();
    for (int off = 1; off < 1024; off <<= 1) {
        int v = (t >= off) ? sh[t - off] : 0;
        __syncthreads();
        sh[t] += v;
        __syncthreads();
    }
    if (t < NB) bpre[t] = sh[t] - v0;
}

__global__ void __launch_bounds__(256) offs_k(const int* __restrict__ cnt,
                                              const int* __restrict__ bpre,
                                              int* __restrict__ offs,
                                              int* __restrict__ cursor, int E) {
    __shared__ int sh[256];
    int t = threadIdx.x;
    int i = blockIdx.x * 256 + t;
    int v0 = (i < E) ? cnt[i] : 0;
    sh[t] = v0;
    __syncthreads();
    for (int off = 1; off < 256; off <<= 1) {
        int v = (t >= off) ? sh[t - off] : 0;
        __syncthreads();
        sh[t] += v;
        __syncthreads();
    }
    int ex = sh[t] - v0 + bpre[blockIdx.x];
    if (i < E) { offs[i] = ex; cursor[i] = ex; }
    if (i == E - 1) offs[E] = ex + v0;
}

__global__ void __launch_bounds__(256) scatter_k(const int* __restrict__ bsrc,
                                                 const int* __restrict__ bdst,
                                                 int* __restrict__ cursor,
                                                 int* __restrict__ srclist, int BE) {
    int i = blockIdx.x * 256 + threadIdx.x;
    if (i < BE) {
        int d = bdst[i];
        int p = __hip_atomic_fetch_add(&cursor[d], 1, __ATOMIC_RELAXED,
                                       __HIP_MEMORY_SCOPE_AGENT);
        srclist[p] = bsrc[i];
    }
}

// tt for BOTH layers
__global__ void __launch_bounds__(64) tt2_k(const float* __restrict__ emb,
                                            const float* __restrict__ mw1,
                                            const float* __restrict__ mb1,
                                            float* __restrict__ tt) {
    int b = blockIdx.x;
    int l = b / NTYPES, t = b % NTYPES, j = threadIdx.x;
    const float* embl = emb + (size_t)l * NTYPES * DDIM + (size_t)t * DDIM;
    const float* w1 = mw1 + (size_t)l * 192 * DDIM;
    float s = mb1[l * DDIM + j];
    #pragma unroll 8
    for (int k = 0; k < DDIM; ++k)
        s = fmaf(embl[k], w1[(HDIM + k) * DDIM + j], s);
    tt[(size_t)b * DDIM + j] = s;
}

// ---------------- atom-side projection (LDS-staged) ----------------
// pa[a] = AF[a] @ iw1[0:128]; qa[a] = AF[a] @ iw1[128:256]; na[a] = ||AF[a]||
#define AFS (HDIM + 1)   // LDS row stride (129: 2-way bank alias = free)
__global__ void __launch_bounds__(256) atom_proj_k(
    const float* __restrict__ AF, const float* __restrict__ iw1,
    float* __restrict__ pa, float* __restrict__ qa, float* __restrict__ na, int N) {
    __shared__ float af[EPB * AFS];
    int t = threadIdx.x;
    int a0 = blockIdx.x * EPB;
    // coalesced cooperative load: up to 64 rows x 128 floats
    {
        int nrows = min(EPB, N - a0);
        int total4 = nrows * (HDIM / 4);
        for (int i = t; i < total4; i += 256) {
            int r = i >> 5;            // / (HDIM/4)
            int c4 = i & 31;
            float4 v = ld4(AF + (size_t)(a0 + r) * HDIM + c4 * 4);
            float* dst = af + r * AFS + c4 * 4;
            dst[0] = v.x; dst[1] = v.y; dst[2] = v.z; dst[3] = v.w;
        }
    }
    __syncthreads();

    int lane = t & 63;
    int w = __builtin_amdgcn_readfirstlane((int)(t >> 6));
    int a = a0 + lane;
    bool ok = a < N;
    const float* h = af + lane * AFS;
    int j0 = w * 16;

    float ap[16], aq[16];
    #pragma unroll
    for (int jj = 0; jj < 16; ++jj) { ap[jj] = 0.f; aq[jj] = 0.f; }
    float nrm = 0.f;
    #pragma unroll 4
    for (int c = 0; c < 16; ++c) {          // K = 128 in chunks of 8
        float xv[8];
        #pragma unroll
        for (int kk = 0; kk < 8; ++kk) xv[kk] = h[c * 8 + kk];
        if (w == 0) {
            #pragma unroll
            for (int kk = 0; kk < 8; ++kk) nrm = fmaf(xv[kk], xv[kk], nrm);
        }
        const float* wt = iw1 + (size_t)(c * 8) * DDIM + j0;
        const float* wb = iw1 + (size_t)(HDIM + c * 8) * DDIM + j0;
        #pragma unroll
        for (int kk = 0; kk < 8; ++kk) {
            const float* wtk = wt + (size_t)kk * DDIM;
            const float* wbk = wb + (size_t)kk * DDIM;
            #pragma unroll
            for (int jj = 0; jj < 16; ++jj) {
                ap[jj] = fmaf(xv[kk], wtk[jj], ap[jj]);
                aq[jj] = fmaf(xv[kk], wbk[jj], aq[jj]);
            }
        }
    }
    if (ok) {
        float* pr = pa + (size_t)a * DDIM + j0;
        float* qr = qa + (size_t)a * DDIM + j0;
        st4(pr + 0,  make_float4(ap[0],  ap[1],  ap[2],  ap[3]));
        st4(pr + 4,  make_float4(ap[4],  ap[5],  ap[6],  ap[7]));
        st4(pr + 8,  make_float4(ap[8],  ap[9],  ap[10], ap[11]));
        st4(pr + 12, make_float4(ap[12], ap[13], ap[14], ap[15]));
        st4(qr + 0,  make_float4(aq[0],  aq[1],  aq[2],  aq[3]));
        st4(qr + 4,  make_float4(aq[4],  aq[5],  aq[6],  aq[7]));
        st4(qr + 8,  make_float4(aq[8],  aq[9],  aq[10], aq[11]));
        st4(qr + 12, make_float4(aq[12], aq[13], aq[14], aq[15]));
        if (w == 0) na[a] = sqrtf(nrm);
    }
}

// ---------------- bond init (from atom projections) + layer-0 proj ----------------
__global__ void __launch_bounds__(256) bond_init2_k(
    const float* __restrict__ AF, const int* __restrict__ row, const int* __restrict__ col,
    const float* __restrict__ pa, const float* __restrict__ qa, const float* __restrict__ na,
    const float* __restrict__ b1, const float* __restrict__ w2, const float* __restrict__ b2,
    const float* __restrict__ w1p /*[192][64] layer0 mw1*/,
    float* __restrict__ x, int* __restrict__ bt,
    float* __restrict__ pd, float* __restrict__ ps, int E) {
    __shared__ float hbuf[EPB][DDIM + 1];
    __shared__ float dotb[EPB][5];
    int nEB = (E + EPB - 1) / EPB;
    int lb = xcd_logical_block();
    if (lb >= nEB) return;
    int lane = threadIdx.x & 63;
    int w = __builtin_amdgcn_readfirstlane((int)(threadIdx.x >> 6));
    int e = lb * EPB + lane;
    bool ok = e < E;
    int eidx = ok ? e : 0;
    int r = row[eidx], c = col[eidx];
    int j0 = w * 16;

    // partial dot over K-chunk [32w, 32w+32)
    {
        const float* hi = AF + (size_t)r * HDIM + w * 32;
        const float* hj = AF + (size_t)c * HDIM + w * 32;
        float d = 0.f;
        #pragma unroll
        for (int k = 0; k < 32; k += 4) {
            float4 a4 = ld4(hi + k), b4 = ld4(hj + k);
            d += a4.x * b4.x + a4.y * b4.y + a4.z * b4.z + a4.w * b4.w;
        }
        dotb[lane][w] = d;
    }

    // layer-1 hidden slice: silu(pa[r] + qa[c] + b1)
    {
        const float* pr = pa + (size_t)r * DDIM + j0;
        const float* qc = qa + (size_t)c * DDIM + j0;
        #pragma unroll
        for (int q = 0; q < 4; ++q) {
            float4 pv = ld4(pr + q * 4);
            float4 qv = ld4(qc + q * 4);
            hbuf[lane][j0 + q * 4 + 0] = silu_f(pv.x + qv.x + b1[j0 + q * 4 + 0]);
            hbuf[lane][j0 + q * 4 + 1] = silu_f(pv.y + qv.y + b1[j0 + q * 4 + 1]);
            hbuf[lane][j0 + q * 4 + 2] = silu_f(pv.z + qv.z + b1[j0 + q * 4 + 2]);
            hbuf[lane][j0 + q * 4 + 3] = silu_f(pv.w + qv.w + b1[j0 + q * 4 + 3]);
        }
    }
    __syncthreads();

    if (w == 0) {
        float dot = dotb[lane][0] + dotb[lane][1] + dotb[lane][2] + dotb[lane][3];
        float nr = fmaxf(na[r], 1e-8f), nc = fmaxf(na[c], 1e-8f);
        float sim = dot / (nr * nc);
        int t = 0;
        if (sim > 0.8f) t = 1;
        if (sim > 0.9f) t = 2;
        if (sim < 0.3f) t = 3;
        if (ok) bt[e] = t;
    }

    // layer-2: x = h @ w2 + b2 (K=64 from LDS)
    float o[16];
    #pragma unroll
    for (int jj = 0; jj < 16; ++jj) o[jj] = b2[j0 + jj];
    #pragma unroll 4
    for (int k = 0; k < DDIM; ++k) {
        float hk = hbuf[lane][k];
        const float* wk = w2 + (size_t)k * DDIM + j0;
        #pragma unroll
        for (int jj = 0; jj < 16; ++jj) o[jj] = fmaf(hk, wk[jj], o[jj]);
    }
    if (ok) {
        float* xr = x + (size_t)e * DDIM + j0;
        st4(xr + 0,  make_float4(o[0],  o[1],  o[2],  o[3]));
        st4(xr + 4,  make_float4(o[4],  o[5],  o[6],  o[7]));
        st4(xr + 8,  make_float4(o[8],  o[9],  o[10], o[11]));
        st4(xr + 12, make_float4(o[12], o[13], o[14], o[15]));
    }
    __syncthreads();
    #pragma unroll
    for (int jj = 0; jj < 16; ++jj) hbuf[lane][j0 + jj] = o[jj];   // x row
    __syncthreads();

    // proj (layer 0): pd = x@W1[0:64], ps = x@W1[64:128]
    float apd[16], aps[16];
    #pragma unroll
    for (int jj = 0; jj < 16; ++jj) { apd[jj] = 0.f; aps[jj] = 0.f; }
    #pragma unroll 4
    for (int k = 0; k < DDIM; ++k) {
        float xk = hbuf[lane][k];
        const float* wd = w1p + (size_t)k * DDIM + j0;
        const float* wsv = w1p + (size_t)(DDIM + k) * DDIM + j0;
        #pragma unroll
        for (int jj = 0; jj < 16; ++jj) {
            apd[jj] = fmaf(xk, wd[jj], apd[jj]);
            aps[jj] = fmaf(xk, wsv[jj], aps[jj]);
        }
    }
    if (ok) {
        float* pr = pd + (size_t)e * DDIM + j0;
        float* qr = ps + (size_t)e * DDIM + j0;
        st4(pr + 0,  make_float4(apd[0],  apd[1],  apd[2],  apd[3]));
        st4(pr + 4,  make_float4(apd[4],  apd[5],  apd[6],  apd[7]));
        st4(pr + 8,  make_float4(apd[8],  apd[9],  apd[10], apd[11]));
        st4(pr + 12, make_float4(apd[12], apd[13], apd[14], apd[15]));
        st4(qr + 0,  make_float4(aps[0],  aps[1],  aps[2],  aps[3]));
        st4(qr + 4,  make_float4(aps[4],  aps[5],  aps[6],  aps[7]));
        st4(qr + 8,  make_float4(aps[8],  aps[9],  aps[10], aps[11]));
        st4(qr + 12, make_float4(aps[12], aps[13], aps[14], aps[15]));
    }
}

// proj for layer 1 (x from global)
__global__ void __launch_bounds__(256) proj_k(const float* __restrict__ x,
                                              const float* __restrict__ w1 /*[192][64]*/,
                                              float* __restrict__ pd, float* __restrict__ ps,
                                              int E) {
    int lane = threadIdx.x & 63;
    int w = __builtin_amdgcn_readfirstlane((int)(threadIdx.x >> 6));
    int e = blockIdx.x * EPB + lane;
    bool ok = e < E;
    int eidx = ok ? e : 0;
    int j0 = w * 16;
    const float* xr = x + (size_t)eidx * DDIM;

    float apd[16], aps[16];
    #pragma unroll
    for (int jj = 0; jj < 16; ++jj) { apd[jj] = 0.f; aps[jj] = 0.f; }
    #pragma unroll 2
    for (int c = 0; c < 16; ++c) {
        float4 v = ld4(xr + c * 4);
        float xv[4] = {v.x, v.y, v.z, v.w};
        #pragma unroll
        for (int kk = 0; kk < 4; ++kk) {
            int k = c * 4 + kk;
            const float* wd = w1 + (size_t)k * DDIM + j0;
            const float* wsv = w1 + (size_t)(DDIM + k) * DDIM + j0;
            #pragma unroll
            for (int jj = 0; jj < 16; ++jj) {
                apd[jj] = fmaf(xv[kk], wd[jj], apd[jj]);
                aps[jj] = fmaf(xv[kk], wsv[jj], aps[jj]);
            }
        }
    }
    if (ok) {
        float* pr = pd + (size_t)e * DDIM + j0;
        float* qr = ps + (size_t)e * DDIM + j0;
        st4(pr + 0,  make_float4(apd[0],  apd[1],  apd[2],  apd[3]));
        st4(pr + 4,  make_float4(apd[4],  apd[5],  apd[6],  apd[7]));
        st4(pr + 8,  make_float4(apd[8],  apd[9],  apd[10], apd[11]));
        st4(pr + 12, make_float4(apd[12], apd[13], apd[14], apd[15]));
        st4(qr + 0,  make_float4(aps[0],  aps[1],  aps[2],  aps[3]));
        st4(qr + 4,  make_float4(aps[4],  aps[5],  aps[6],  aps[7]));
        st4(qr + 8,  make_float4(aps[8],  aps[9],  aps[10], aps[11]));
        st4(qr + 12, make_float4(aps[12], aps[13], aps[14], aps[15]));
    }
}

// ---------------- fused gather + mm + update ----------------
__global__ void __launch_bounds__(256) layer_k(
    float* __restrict__ x, const float* __restrict__ pd, const float* __restrict__ ps,
    const float* __restrict__ tt_l, const int* __restrict__ bt,
    const int* __restrict__ offs, const int* __restrict__ srclist,
    const int* __restrict__ cnt,
    const float* __restrict__ w2m, const float* __restrict__ b2m,
    const float* __restrict__ uw1 /*[128][64]*/, const float* __restrict__ ub1,
    const float* __restrict__ uw2 /*[64][64]*/, const float* __restrict__ ub2, int E) {
    __shared__ float sb[EPB][DDIM + 1];
    __shared__ float mb[EPB][DDIM + 1];
    int nEB = (E + EPB - 1) / EPB;
    int lb = xcd_logical_block();
    if (lb >= nEB) return;
    int lane = threadIdx.x & 63;
    int w = __builtin_amdgcn_readfirstlane((int)(threadIdx.x >> 6));
    int e = lb * EPB + lane;
    bool ok = e < E;
    int eidx = ok ? e : 0;
    int j0 = w * 16;

    // ---- P1: gather (thread = (d_local, q)), 2-way unrolled ----
    {
        int d_local = threadIdx.x >> 2, q = threadIdx.x & 3;
        int d = lb * EPB + d_local;
        if (d < E) {
            int jq = q * 16;
            const float* pr = pd + (size_t)d * DDIM + jq;
            const float* tp = tt_l + (size_t)bt[d] * DDIM + jq;
            float4 b0 = add4(ld4(pr + 0),  ld4(tp + 0));
            float4 b1 = add4(ld4(pr + 4),  ld4(tp + 4));
            float4 b2 = add4(ld4(pr + 8),  ld4(tp + 8));
            float4 b3 = add4(ld4(pr + 12), ld4(tp + 12));
            float4 s0 = make_float4(0, 0, 0, 0), s1 = s0, s2 = s0, s3 = s0;
            int p0 = offs[d], p1 = offs[d + 1];
            int p = p0;
            for (; p + 2 <= p1; p += 2) {
                const float* sa = ps + (size_t)srclist[p] * DDIM + jq;
                const float* sc = ps + (size_t)srclist[p + 1] * DDIM + jq;
                float4 u0 = ld4(sa + 0), u1 = ld4(sa + 4);
                float4 u2 = ld4(sa + 8), u3 = ld4(sa + 12);
                float4 v0 = ld4(sc + 0), v1 = ld4(sc + 4);
                float4 v2 = ld4(sc + 8), v3 = ld4(sc + 12);
                silu_acc4(s0, add4(b0, u0));
                silu_acc4(s1, add4(b1, u1));
                silu_acc4(s2, add4(b2, u2));
                silu_acc4(s3, add4(b3, u3));
                silu_acc4(s0, add4(b0, v0));
                silu_acc4(s1, add4(b1, v1));
                silu_acc4(s2, add4(b2, v2));
                silu_acc4(s3, add4(b3, v3));
            }
            if (p < p1) {
                const float* sa = ps + (size_t)srclist[p] * DDIM + jq;
                float4 u0 = ld4(sa + 0), u1 = ld4(sa + 4);
                float4 u2 = ld4(sa + 8), u3 = ld4(sa + 12);
                silu_acc4(s0, add4(b0, u0));
                silu_acc4(s1, add4(b1, u1));
                silu_acc4(s2, add4(b2, u2));
                silu_acc4(s3, add4(b3, u3));
            }
            st4(&sb[d_local][jq + 0],  s0);
            st4(&sb[d_local][jq + 4],  s1);
            st4(&sb[d_local][jq + 8],  s2);
            st4(&sb[d_local][jq + 12], s3);
        }
    }
    __syncthreads();

    // ---- P2: mm ----
    float degf = (float)cnt[eidx];
    float inv = 1.0f / fmaxf(degf, 1.0f);
    {
        float am[16];
        #pragma unroll
        for (int jj = 0; jj < 16; ++jj) am[jj] = degf * b2m[j0 + jj];
        #pragma unroll 4
        for (int k = 0; k < DDIM; ++k) {
            float sk = sb[lane][k];
            const float* wk = w2m + (size_t)k * DDIM + j0;
            #pragma unroll
            for (int jj = 0; jj < 16; ++jj) am[jj] = fmaf(sk, wk[jj], am[jj]);
        }
        #pragma unroll
        for (int jj = 0; jj < 16; ++jj) mb[lane][j0 + jj] = am[jj] * inv;
    }
    __syncthreads();

    // ---- P3: u-layer1 (mm from LDS, x from global) ----
    const float* xr = x + (size_t)eidx * DDIM;
    {
        float ah[16];
        #pragma unroll
        for (int jj = 0; jj < 16; ++jj) ah[jj] = ub1[j0 + jj];
        #pragma unroll 4
        for (int k = 0; k < DDIM; ++k) {
            float mk = mb[lane][k];
            const float* wk = uw1 + (size_t)k * DDIM + j0;
            #pragma unroll
            for (int jj = 0; jj < 16; ++jj) ah[jj] = fmaf(mk, wk[jj], ah[jj]);
        }
        #pragma unroll 2
        for (int c = 0; c < 16; ++c) {
            float4 v = ld4(xr + c * 4);
            float xv[4] = {v.x, v.y, v.z, v.w};
            #pragma unroll
            for (int kk = 0; kk < 4; ++kk) {
                const float* wk = uw1 + (size_t)(DDIM + c * 4 + kk) * DDIM + j0;
                #pragma unroll
                for (int jj = 0; jj < 16; ++jj) ah[jj] = fmaf(xv[kk], wk[jj], ah[jj]);
            }
        }
        #pragma unroll
        for (int jj = 0; jj < 16; ++jj) sb[lane][j0 + jj] = silu_f(ah[jj]);
    }
    __syncthreads();

    // ---- P4: u-layer2 + residual ----
    {
        float o[16];
        #pragma unroll
        for (int jj = 0; jj < 16; ++jj) o[jj] = ub2[j0 + jj];
        #pragma unroll 4
        for (int k = 0; k < DDIM; ++k) {
            float hk = sb[lane][k];
            const float* wk = uw2 + (size_t)k * DDIM + j0;
            #pragma unroll
            for (int jj = 0; jj < 16; ++jj) o[jj] = fmaf(hk, wk[jj], o[jj]);
        }
        if (ok) {
            float* xw = x + (size_t)e * DDIM + j0;
            #pragma unroll
            for (int q = 0; q < 4; ++q) {
                float4 xo = ld4(xw + q * 4);
                xo.x += o[q * 4 + 0];
                xo.y += o[q * 4 + 1];
                xo.z += o[q * 4 + 2];
                xo.w += o[q * 4 + 3];
                st4(xw + q * 4, xo);
            }
        }
    }
}

// ---------------- pooling ----------------
static __device__ __forceinline__ int lower_bound_bb(const int* __restrict__ row,
                                                     const int* __restrict__ batch,
                                                     int E, int g) {
    int lo = 0, hi = E;
    while (lo < hi) {
        int m = (lo + hi) >> 1;
        if (batch[row[m]] < g) lo = m + 1; else hi = m;
    }
    return lo;
}

__global__ void __launch_bounds__(64) pool_partial_k(
    const float* __restrict__ x, const int* __restrict__ row, const int* __restrict__ batch,
    float* __restrict__ gfeat, int E) {
    int g = blockIdx.x, p = blockIdx.y, j = threadIdx.x;
    int s = lower_bound_bb(row, batch, E, g);
    int t = lower_bound_bb(row, batch, E, g + 1);
    int cnt = t - s;
    int chunk = (cnt + POOL_P - 1) / POOL_P;
    int e0 = s + p * chunk;
    int e1 = min(e0 + chunk, t);
    float sum = 0.f;
    for (int e = e0; e < e1; ++e) sum += x[(size_t)e * DDIM + j];
    if (e0 < e1)
        __hip_atomic_fetch_add(&gfeat[g * DDIM + j], sum, __ATOMIC_RELAXED,
                               __HIP_MEMORY_SCOPE_AGENT);
}

__global__ void __launch_bounds__(64) pool_final_k(
    const int* __restrict__ row, const int* __restrict__ batch,
    float* __restrict__ gfeat, int E) {
    int g = blockIdx.x, j = threadIdx.x;
    int s = lower_bound_bb(row, batch, E, g);
    int t = lower_bound_bb(row, batch, E, g + 1);
    float cnt = fmaxf((float)(t - s), 1.0f);
    gfeat[g * DDIM + j] /= cnt;
}

extern "C" void kernel_launch(void* const* d_in, const int* in_sizes, int n_in,
                              void* d_out, int out_size, void* d_ws, size_t ws_size,
                              hipStream_t stream) {
    (void)n_in; (void)out_size; (void)ws_size;
    const float* AF    = (const float*)d_in[0];
    const int*   batch = (const int*)d_in[3];
    const int*   edge_index      = (const int*)d_in[4];
    const int*   bond_edge_index = (const int*)d_in[5];
    const float* iw1 = (const float*)d_in[6];
    const float* ib1 = (const float*)d_in[7];
    const float* iw2 = (const float*)d_in[8];
    const float* ib2 = (const float*)d_in[9];
    const float* emb = (const float*)d_in[10];
    const float* mw1 = (const float*)d_in[11];
    const float* mb1 = (const float*)d_in[12];
    const float* mw2 = (const float*)d_in[13];
    const float* mb2 = (const float*)d_in[14];
    const float* uw1 = (const float*)d_in[15];
    const float* ub1 = (const float*)d_in[16];
    const float* uw2 = (const float*)d_in[17];
    const float* ub2 = (const float*)d_in[18];

    const int N  = in_sizes[0] / HDIM;
    const int E  = in_sizes[4] / 2;
    const int BE = in_sizes[5] / 2;
    const int NB = (E + 255) / 256;
    const int EB = (E + EPB - 1) / EPB;
    const int AB = (N + EPB - 1) / EPB;
    const int EBS = ((EB + 7) / 8) * 8;   // swizzled grid (multiple of 8)

    float* xout  = (float*)d_out;                 // [E,64]
    float* gfeat = xout + (size_t)E * DDIM;       // [16,64]

    // workspace layout
    char* w = (char*)d_ws;
    float* tt       = (float*)w;  w += sizeof(float) * 2 * NTYPES * DDIM;
    int*   cnt      = (int*)w;    w += sizeof(int) * E;
    int*   offs     = (int*)w;    w += sizeof(int) * (E + 1);
    int*   cursor   = (int*)w;    w += sizeof(int) * E;
    int*   bt       = (int*)w;    w += sizeof(int) * E;
    int*   bsum     = (int*)w;    w += sizeof(int) * 1024;
    int*   bpre     = (int*)w;    w += sizeof(int) * 1024;
    int*   srclist  = (int*)w;    w += sizeof(int) * BE;
    w = (char*)(((uintptr_t)w + 15) & ~(uintptr_t)15);
    float* pd       = (float*)w;  w += sizeof(float) * (size_t)E * DDIM;
    float* ps       = (float*)w;  w += sizeof(float) * (size_t)E * DDIM;
    float* pa       = (float*)w;  w += sizeof(float) * (size_t)N * DDIM;
    float* qa       = (float*)w;  w += sizeof(float) * (size_t)N * DDIM;
    float* na       = (float*)w;  w += sizeof(float) * (size_t)N;

    const int* row  = edge_index;
    const int* col  = edge_index + E;
    const int* bsrc = bond_edge_index;
    const int* bdst = bond_edge_index + BE;

    // CSR build
    hipMemsetAsync(cnt, 0, (size_t)E * sizeof(int), stream);
    count_k<<<(BE + 255) / 256, 256, 0, stream>>>(bdst, cnt, BE);
    bsum_k<<<NB, 256, 0, stream>>>(cnt, bsum, E);
    bscan_k<<<1, 1024, 0, stream>>>(bsum, bpre, NB);
    offs_k<<<NB, 256, 0, stream>>>(cnt, bpre, offs, cursor, E);
    scatter_k<<<(BE + 255) / 256, 256, 0, stream>>>(bsrc, bdst, cursor, srclist, BE);

    // bond-type embeddings for both layers
    tt2_k<<<2 * NTYPES, 64, 0, stream>>>(emb, mw1, mb1, tt);

    // atom projections, then bond init + layer-0 proj
    atom_proj_k<<<AB, 256, 0, stream>>>(AF, iw1, pa, qa, na, N);
    bond_init2_k<<<EBS, 256, 0, stream>>>(AF, row, col, pa, qa, na, ib1, iw2, ib2,
                                          mw1 /* layer 0 */, xout, bt, pd, ps, E);

    for (int l = 0; l < 2; ++l) {
        if (l > 0)
            proj_k<<<EB, 256, 0, stream>>>(xout, mw1 + (size_t)l * 192 * 64, pd, ps, E);
        layer_k<<<EBS, 256, 0, stream>>>(
            xout, pd, ps, tt + (size_t)l * NTYPES * DDIM, bt, offs, srclist, cnt,
            mw2 + (size_t)l * DDIM * DDIM, mb2 + (size_t)l * DDIM,
            uw1 + (size_t)l * 128 * 64, ub1 + (size_t)l * DDIM,
            uw2 + (size_t)l * DDIM * DDIM, ub2 + (size_t)l * DDIM, E);
    }

    hipMemsetAsync(gfeat, 0, NGRAPHS * DDIM * sizeof(float), stream);
    dim3 pg(NGRAPHS, POOL_P);
    pool_partial_k<<<pg, 64, 0, stream>>>(xout, row, batch, gfeat, E);
    pool_final_k<<<NGRAPHS, 64, 0, stream>>>(row, batch, gfeat, E);
}

// Round 7
// 465.395 us; speedup vs baseline: 1.0816x; 1.0726x over previous
//
#include <hip/hip_runtime.h>
#include <cstdint>
#include <cstddef>

#define HDIM 128
#define DDIM 64
#define NTYPES 5
#define NGRAPHS 16
#define POOL_P 16
#define EPB 64   // edges per block (one per lane)
#define APW 8    // atoms per wave in atom_proj

static __device__ __forceinline__ float silu_f(float v) {
    return v / (1.0f + __expf(-v));
}

static __device__ __forceinline__ float4 ld4(const float* p) {
    return *reinterpret_cast<const float4*>(p);
}

static __device__ __forceinline__ void st4(float* p, float4 v) {
    *reinterpret_cast<float4*>(p) = v;
}

static __device__ __forceinline__ float4 add4(float4 a, float4 b) {
    return make_float4(a.x + b.x, a.y + b.y, a.z + b.z, a.w + b.w);
}

static __device__ __forceinline__ void silu_acc4(float4& s, float4 v) {
    s.x += silu_f(v.x);
    s.y += silu_f(v.y);
    s.z += silu_f(v.z);
    s.w += silu_f(v.w);
}

// XCD-affinity swizzle (heuristic blk%8 -> XCD round-robin).
static __device__ __forceinline__ int xcd_logical_block() {
    int chunk = (int)(gridDim.x >> 3);
    return (int)(blockIdx.x & 7) * chunk + (int)(blockIdx.x >> 3);
}

// ---------------- CSR build ----------------
__global__ void __launch_bounds__(256) count_k(const int* __restrict__ bdst,
                                               int* __restrict__ cnt, int BE) {
    int i = blockIdx.x * 256 + threadIdx.x;
    if (i < BE)
        __hip_atomic_fetch_add(&cnt[bdst[i]], 1, __ATOMIC_RELAXED, __HIP_MEMORY_SCOPE_AGENT);
}

__global__ void __launch_bounds__(256) bsum_k(const int* __restrict__ cnt,
                                              int* __restrict__ bsum, int E) {
    __shared__ int red[256];
    int t = threadIdx.x;
    int i = blockIdx.x * 256 + t;
    red[t] = (i < E) ? cnt[i] : 0;
    __syncthreads();
    #pragma unroll
    for (int off = 128; off > 0; off >>= 1) {
        if (t < off) red[t] += red[t + off];
        __syncthreads();
    }
    if (t == 0) bsum[blockIdx.x] = red[0];
}

__global__ void __launch_bounds__(1024) bscan_k(const int* __restrict__ bsum,
                                                int* __restrict__ bpre, int NB) {
    __shared__ int sh[1024];
    int t = threadIdx.x;
    int v0 = (t < NB) ? bsum[t] : 0;
    sh[t] = v0;
    __syncthreads();
    for (int off = 1; off < 1024; off <<= 1) {
        int v = (t >= off) ? sh[t - off] : 0;
        __syncthreads();
        sh[t] += v;
        __syncthreads();
    }
    if (t < NB) bpre[t] = sh[t] - v0;
}

__global__ void __launch_bounds__(256) offs_k(const int* __restrict__ cnt,
                                              const int* __restrict__ bpre,
                                              int* __restrict__ offs,
                                              int* __restrict__ cursor, int E) {
    __shared__ int sh[256];
    int t = threadIdx.x;
    int i = blockIdx.x * 256 + t;
    int v0 = (i < E) ? cnt[i] : 0;
    sh[t] = v0;
    __syncthreads();
    for (int off = 1; off < 256; off <<= 1) {
        int v = (t >= off) ? sh[t - off] : 0;
        __syncthreads();
        sh[t] += v;
        __syncthreads();
    }
    int ex = sh[t] - v0 + bpre[blockIdx.x];
    if (i < E) { offs[i] = ex; cursor[i] = ex; }
    if (i == E - 1) offs[E] = ex + v0;
}

__global__ void __launch_bounds__(256) scatter_k(const int* __restrict__ bsrc,
                                                 const int* __restrict__ bdst,
                                                 int* __restrict__ cursor,
                                                 int* __restrict__ srclist, int BE) {
    int i = blockIdx.x * 256 + threadIdx.x;
    if (i < BE) {
        int d = bdst[i];
        int p = __hip_atomic_fetch_add(&cursor[d], 1, __ATOMIC_RELAXED,
                                       __HIP_MEMORY_SCOPE_AGENT);
        srclist[p] = bsrc[i];
    }
}

// tt for BOTH layers
__global__ void __launch_bounds__(64) tt2_k(const float* __restrict__ emb,
                                            const float* __restrict__ mw1,
                                            const float* __restrict__ mb1,
                                            float* __restrict__ tt) {
    int b = blockIdx.x;
    int l = b / NTYPES, t = b % NTYPES, j = threadIdx.x;
    const float* embl = emb + (size_t)l * NTYPES * DDIM + (size_t)t * DDIM;
    const float* w1 = mw1 + (size_t)l * 192 * DDIM;
    float s = mb1[l * DDIM + j];
    #pragma unroll 8
    for (int k = 0; k < DDIM; ++k)
        s = fmaf(embl[k], w1[(HDIM + k) * DDIM + j], s);
    tt[(size_t)b * DDIM + j] = s;
}

// ---------------- atom-side projection: wave-per-8-atoms, lane = feature ----------------
// pa[a][j] = sum_k AF[a][k] * iw1[k][j]; qa[a][j] = sum_k AF[a][k] * iw1[128+k][j];
// na[a] = ||AF[a]||. AF row addresses are wave-uniform -> scalar loads;
// weight loads are lane-coalesced (lane = j). No LDS, no barriers.
__global__ void __launch_bounds__(256) atom_proj_k(
    const float* __restrict__ AF, const float* __restrict__ iw1,
    float* __restrict__ pa, float* __restrict__ qa, float* __restrict__ na, int N) {
    int lane = threadIdx.x & 63;
    int w = __builtin_amdgcn_readfirstlane((int)(threadIdx.x >> 6));
    int abase = blockIdx.x * (4 * APW) + w * APW;
    if (abase >= N) return;

    float accp[APW], accq[APW], nrm[APW];
    #pragma unroll
    for (int a = 0; a < APW; ++a) { accp[a] = 0.f; accq[a] = 0.f; nrm[a] = 0.f; }

    #pragma unroll 4
    for (int k = 0; k < HDIM; k += 4) {
        float wt[4], wb[4];
        #pragma unroll
        for (int kk = 0; kk < 4; ++kk) {
            wt[kk] = iw1[(size_t)(k + kk) * DDIM + lane];
            wb[kk] = iw1[(size_t)(HDIM + k + kk) * DDIM + lane];
        }
        #pragma unroll
        for (int a = 0; a < APW; ++a) {
            int aa = min(abase + a, N - 1);           // wave-uniform
            float4 hv = ld4(AF + (size_t)aa * HDIM + k);
            accp[a] = fmaf(hv.x, wt[0], accp[a]);
            accp[a] = fmaf(hv.y, wt[1], accp[a]);
            accp[a] = fmaf(hv.z, wt[2], accp[a]);
            accp[a] = fmaf(hv.w, wt[3], accp[a]);
            accq[a] = fmaf(hv.x, wb[0], accq[a]);
            accq[a] = fmaf(hv.y, wb[1], accq[a]);
            accq[a] = fmaf(hv.z, wb[2], accq[a]);
            accq[a] = fmaf(hv.w, wb[3], accq[a]);
            nrm[a] = fmaf(hv.x, hv.x, nrm[a]);
            nrm[a] = fmaf(hv.y, hv.y, nrm[a]);
            nrm[a] = fmaf(hv.z, hv.z, nrm[a]);
            nrm[a] = fmaf(hv.w, hv.w, nrm[a]);
        }
    }
    #pragma unroll
    for (int a = 0; a < APW; ++a) {
        int atom = abase + a;
        if (atom < N) {
            pa[(size_t)atom * DDIM + lane] = accp[a];
            qa[(size_t)atom * DDIM + lane] = accq[a];
            if (lane == 0) na[atom] = sqrtf(nrm[a]);
        }
    }
}

// ---------------- bond init (from atom projections) + layer-0 proj ----------------
__global__ void __launch_bounds__(256) bond_init2_k(
    const float* __restrict__ AF, const int* __restrict__ row, const int* __restrict__ col,
    const float* __restrict__ pa, const float* __restrict__ qa, const float* __restrict__ na,
    const float* __restrict__ b1, const float* __restrict__ w2, const float* __restrict__ b2,
    const float* __restrict__ w1p /*[192][64] layer0 mw1*/,
    float* __restrict__ x, int* __restrict__ bt,
    float* __restrict__ pd, float* __restrict__ ps, int E) {
    __shared__ float hbuf[EPB][DDIM + 1];
    __shared__ float dotb[EPB][5];
    int nEB = (E + EPB - 1) / EPB;
    int lb = xcd_logical_block();
    if (lb >= nEB) return;
    int lane = threadIdx.x & 63;
    int w = __builtin_amdgcn_readfirstlane((int)(threadIdx.x >> 6));
    int e = lb * EPB + lane;
    bool ok = e < E;
    int eidx = ok ? e : 0;
    int r = row[eidx], c = col[eidx];
    int j0 = w * 16;

    // partial dot over K-chunk [32w, 32w+32)
    {
        const float* hi = AF + (size_t)r * HDIM + w * 32;
        const float* hj = AF + (size_t)c * HDIM + w * 32;
        float d = 0.f;
        #pragma unroll
        for (int k = 0; k < 32; k += 4) {
            float4 a4 = ld4(hi + k), b4 = ld4(hj + k);
            d += a4.x * b4.x + a4.y * b4.y + a4.z * b4.z + a4.w * b4.w;
        }
        dotb[lane][w] = d;
    }

    // layer-1 hidden slice: silu(pa[r] + qa[c] + b1)
    {
        const float* pr = pa + (size_t)r * DDIM + j0;
        const float* qc = qa + (size_t)c * DDIM + j0;
        #pragma unroll
        for (int q = 0; q < 4; ++q) {
            float4 pv = ld4(pr + q * 4);
            float4 qv = ld4(qc + q * 4);
            hbuf[lane][j0 + q * 4 + 0] = silu_f(pv.x + qv.x + b1[j0 + q * 4 + 0]);
            hbuf[lane][j0 + q * 4 + 1] = silu_f(pv.y + qv.y + b1[j0 + q * 4 + 1]);
            hbuf[lane][j0 + q * 4 + 2] = silu_f(pv.z + qv.z + b1[j0 + q * 4 + 2]);
            hbuf[lane][j0 + q * 4 + 3] = silu_f(pv.w + qv.w + b1[j0 + q * 4 + 3]);
        }
    }
    __syncthreads();

    if (w == 0) {
        float dot = dotb[lane][0] + dotb[lane][1] + dotb[lane][2] + dotb[lane][3];
        float nr = fmaxf(na[r], 1e-8f), nc = fmaxf(na[c], 1e-8f);
        float sim = dot / (nr * nc);
        int t = 0;
        if (sim > 0.8f) t = 1;
        if (sim > 0.9f) t = 2;
        if (sim < 0.3f) t = 3;
        if (ok) bt[e] = t;
    }

    // layer-2: x = h @ w2 + b2 (K=64 from LDS)
    float o[16];
    #pragma unroll
    for (int jj = 0; jj < 16; ++jj) o[jj] = b2[j0 + jj];
    #pragma unroll 4
    for (int k = 0; k < DDIM; ++k) {
        float hk = hbuf[lane][k];
        const float* wk = w2 + (size_t)k * DDIM + j0;
        #pragma unroll
        for (int jj = 0; jj < 16; ++jj) o[jj] = fmaf(hk, wk[jj], o[jj]);
    }
    if (ok) {
        float* xr = x + (size_t)e * DDIM + j0;
        st4(xr + 0,  make_float4(o[0],  o[1],  o[2],  o[3]));
        st4(xr + 4,  make_float4(o[4],  o[5],  o[6],  o[7]));
        st4(xr + 8,  make_float4(o[8],  o[9],  o[10], o[11]));
        st4(xr + 12, make_float4(o[12], o[13], o[14], o[15]));
    }
    __syncthreads();
    #pragma unroll
    for (int jj = 0; jj < 16; ++jj) hbuf[lane][j0 + jj] = o[jj];   // x row
    __syncthreads();

    // proj (layer 0): pd = x@W1[0:64], ps = x@W1[64:128]
    float apd[16], aps[16];
    #pragma unroll
    for (int jj = 0; jj < 16; ++jj) { apd[jj] = 0.f; aps[jj] = 0.f; }
    #pragma unroll 4
    for (int k = 0; k < DDIM; ++k) {
        float xk = hbuf[lane][k];
        const float* wd = w1p + (size_t)k * DDIM + j0;
        const float* wsv = w1p + (size_t)(DDIM + k) * DDIM + j0;
        #pragma unroll
        for (int jj = 0; jj < 16; ++jj) {
            apd[jj] = fmaf(xk, wd[jj], apd[jj]);
            aps[jj] = fmaf(xk, wsv[jj], aps[jj]);
        }
    }
    if (ok) {
        float* pr = pd + (size_t)e * DDIM + j0;
        float* qr = ps + (size_t)e * DDIM + j0;
        st4(pr + 0,  make_float4(apd[0],  apd[1],  apd[2],  apd[3]));
        st4(pr + 4,  make_float4(apd[4],  apd[5],  apd[6],  apd[7]));
        st4(pr + 8,  make_float4(apd[8],  apd[9],  apd[10], apd[11]));
        st4(pr + 12, make_float4(apd[12], apd[13], apd[14], apd[15]));
        st4(qr + 0,  make_float4(aps[0],  aps[1],  aps[2],  aps[3]));
        st4(qr + 4,  make_float4(aps[4],  aps[5],  aps[6],  aps[7]));
        st4(qr + 8,  make_float4(aps[8],  aps[9],  aps[10], aps[11]));
        st4(qr + 12, make_float4(aps[12], aps[13], aps[14], aps[15]));
    }
}

// proj for layer 1 (x from global)
__global__ void __launch_bounds__(256) proj_k(const float* __restrict__ x,
                                              const float* __restrict__ w1 /*[192][64]*/,
                                              float* __restrict__ pd, float* __restrict__ ps,
                                              int E) {
    int lane = threadIdx.x & 63;
    int w = __builtin_amdgcn_readfirstlane((int)(threadIdx.x >> 6));
    int e = blockIdx.x * EPB + lane;
    bool ok = e < E;
    int eidx = ok ? e : 0;
    int j0 = w * 16;
    const float* xr = x + (size_t)eidx * DDIM;

    float apd[16], aps[16];
    #pragma unroll
    for (int jj = 0; jj < 16; ++jj) { apd[jj] = 0.f; aps[jj] = 0.f; }
    #pragma unroll 2
    for (int c = 0; c < 16; ++c) {
        float4 v = ld4(xr + c * 4);
        float xv[4] = {v.x, v.y, v.z, v.w};
        #pragma unroll
        for (int kk = 0; kk < 4; ++kk) {
            int k = c * 4 + kk;
            const float* wd = w1 + (size_t)k * DDIM + j0;
            const float* wsv = w1 + (size_t)(DDIM + k) * DDIM + j0;
            #pragma unroll
            for (int jj = 0; jj < 16; ++jj) {
                apd[jj] = fmaf(xv[kk], wd[jj], apd[jj]);
                aps[jj] = fmaf(xv[kk], wsv[jj], aps[jj]);
            }
        }
    }
    if (ok) {
        float* pr = pd + (size_t)e * DDIM + j0;
        float* qr = ps + (size_t)e * DDIM + j0;
        st4(pr + 0,  make_float4(apd[0],  apd[1],  apd[2],  apd[3]));
        st4(pr + 4,  make_float4(apd[4],  apd[5],  apd[6],  apd[7]));
        st4(pr + 8,  make_float4(apd[8],  apd[9],  apd[10], apd[11]));
        st4(pr + 12, make_float4(apd[12], apd[13], apd[14], apd[15]));
        st4(qr + 0,  make_float4(aps[0],  aps[1],  aps[2],  aps[3]));
        st4(qr + 4,  make_float4(aps[4],  aps[5],  aps[6],  aps[7]));
        st4(qr + 8,  make_float4(aps[8],  aps[9],  aps[10], aps[11]));
        st4(qr + 12, make_float4(aps[12], aps[13], aps[14], aps[15]));
    }
}

// ---------------- fused gather + mm + update ----------------
__global__ void __launch_bounds__(256) layer_k(
    float* __restrict__ x, const float* __restrict__ pd, const float* __restrict__ ps,
    const float* __restrict__ tt_l, const int* __restrict__ bt,
    const int* __restrict__ offs, const int* __restrict__ srclist,
    const int* __restrict__ cnt,
    const float* __restrict__ w2m, const float* __restrict__ b2m,
    const float* __restrict__ uw1 /*[128][64]*/, const float* __restrict__ ub1,
    const float* __restrict__ uw2 /*[64][64]*/, const float* __restrict__ ub2, int E) {
    __shared__ float sb[EPB][DDIM + 1];
    __shared__ float mb[EPB][DDIM + 1];
    int nEB = (E + EPB - 1) / EPB;
    int lb = xcd_logical_block();
    if (lb >= nEB) return;
    int lane = threadIdx.x & 63;
    int w = __builtin_amdgcn_readfirstlane((int)(threadIdx.x >> 6));
    int e = lb * EPB + lane;
    bool ok = e < E;
    int eidx = ok ? e : 0;
    int j0 = w * 16;

    // ---- P1: gather (thread = (d_local, q)), 2-way unrolled ----
    {
        int d_local = threadIdx.x >> 2, q = threadIdx.x & 3;
        int d = lb * EPB + d_local;
        if (d < E) {
            int jq = q * 16;
            const float* pr = pd + (size_t)d * DDIM + jq;
            const float* tp = tt_l + (size_t)bt[d] * DDIM + jq;
            float4 b0 = add4(ld4(pr + 0),  ld4(tp + 0));
            float4 b1 = add4(ld4(pr + 4),  ld4(tp + 4));
            float4 b2 = add4(ld4(pr + 8),  ld4(tp + 8));
            float4 b3 = add4(ld4(pr + 12), ld4(tp + 12));
            float4 s0 = make_float4(0, 0, 0, 0), s1 = s0, s2 = s0, s3 = s0;
            int p0 = offs[d], p1 = offs[d + 1];
            int p = p0;
            for (; p + 2 <= p1; p += 2) {
                const float* sa = ps + (size_t)srclist[p] * DDIM + jq;
                const float* sc = ps + (size_t)srclist[p + 1] * DDIM + jq;
                float4 u0 = ld4(sa + 0), u1 = ld4(sa + 4);
                float4 u2 = ld4(sa + 8), u3 = ld4(sa + 12);
                float4 v0 = ld4(sc + 0), v1 = ld4(sc + 4);
                float4 v2 = ld4(sc + 8), v3 = ld4(sc + 12);
                silu_acc4(s0, add4(b0, u0));
                silu_acc4(s1, add4(b1, u1));
                silu_acc4(s2, add4(b2, u2));
                silu_acc4(s3, add4(b3, u3));
                silu_acc4(s0, add4(b0, v0));
                silu_acc4(s1, add4(b1, v1));
                silu_acc4(s2, add4(b2, v2));
                silu_acc4(s3, add4(b3, v3));
            }
            if (p < p1) {
                const float* sa = ps + (size_t)srclist[p] * DDIM + jq;
                float4 u0 = ld4(sa + 0), u1 = ld4(sa + 4);
                float4 u2 = ld4(sa + 8), u3 = ld4(sa + 12);
                silu_acc4(s0, add4(b0, u0));
                silu_acc4(s1, add4(b1, u1));
                silu_acc4(s2, add4(b2, u2));
                silu_acc4(s3, add4(b3, u3));
            }
            st4(&sb[d_local][jq + 0],  s0);
            st4(&sb[d_local][jq + 4],  s1);
            st4(&sb[d_local][jq + 8],  s2);
            st4(&sb[d_local][jq + 12], s3);
        }
    }
    __syncthreads();

    // ---- P2: mm ----
    float degf = (float)cnt[eidx];
    float inv = 1.0f / fmaxf(degf, 1.0f);
    {
        float am[16];
        #pragma unroll
        for (int jj = 0; jj < 16; ++jj) am[jj] = degf * b2m[j0 + jj];
        #pragma unroll 4
        for (int k = 0; k < DDIM; ++k) {
            float sk = sb[lane][k];
            const float* wk = w2m + (size_t)k * DDIM + j0;
            #pragma unroll
            for (int jj = 0; jj < 16; ++jj) am[jj] = fmaf(sk, wk[jj], am[jj]);
        }
        #pragma unroll
        for (int jj = 0; jj < 16; ++jj) mb[lane][j0 + jj] = am[jj] * inv;
    }
    __syncthreads();

    // ---- P3: u-layer1 (mm from LDS, x from global) ----
    const float* xr = x + (size_t)eidx * DDIM;
    {
        float ah[16];
        #pragma unroll
        for (int jj = 0; jj < 16; ++jj) ah[jj] = ub1[j0 + jj];
        #pragma unroll 4
        for (int k = 0; k < DDIM; ++k) {
            float mk = mb[lane][k];
            const float* wk = uw1 + (size_t)k * DDIM + j0;
            #pragma unroll
            for (int jj = 0; jj < 16; ++jj) ah[jj] = fmaf(mk, wk[jj], ah[jj]);
        }
        #pragma unroll 2
        for (int c = 0; c < 16; ++c) {
            float4 v = ld4(xr + c * 4);
            float xv[4] = {v.x, v.y, v.z, v.w};
            #pragma unroll
            for (int kk = 0; kk < 4; ++kk) {
                const float* wk = uw1 + (size_t)(DDIM + c * 4 + kk) * DDIM + j0;
                #pragma unroll
                for (int jj = 0; jj < 16; ++jj) ah[jj] = fmaf(xv[kk], wk[jj], ah[jj]);
            }
        }
        #pragma unroll
        for (int jj = 0; jj < 16; ++jj) sb[lane][j0 + jj] = silu_f(ah[jj]);
    }
    __syncthreads();

    // ---- P4: u-layer2 + residual ----
    {
        float o[16];
        #pragma unroll
        for (int jj = 0; jj < 16; ++jj) o[jj] = ub2[j0 + jj];
        #pragma unroll 4
        for (int k = 0; k < DDIM; ++k) {
            float hk = sb[lane][k];
            const float* wk = uw2 + (size_t)k * DDIM + j0;
            #pragma unroll
            for (int jj = 0; jj < 16; ++jj) o[jj] = fmaf(hk, wk[jj], o[jj]);
        }
        if (ok) {
            float* xw = x + (size_t)e * DDIM + j0;
            #pragma unroll
            for (int q = 0; q < 4; ++q) {
                float4 xo = ld4(xw + q * 4);
                xo.x += o[q * 4 + 0];
                xo.y += o[q * 4 + 1];
                xo.z += o[q * 4 + 2];
                xo.w += o[q * 4 + 3];
                st4(xw + q * 4, xo);
            }
        }
    }
}

// ---------------- pooling ----------------
static __device__ __forceinline__ int lower_bound_bb(const int* __restrict__ row,
                                                     const int* __restrict__ batch,
                                                     int E, int g) {
    int lo = 0, hi = E;
    while (lo < hi) {
        int m = (lo + hi) >> 1;
        if (batch[row[m]] < g) lo = m + 1; else hi = m;
    }
    return lo;
}

__global__ void __launch_bounds__(64) pool_partial_k(
    const float* __restrict__ x, const int* __restrict__ row, const int* __restrict__ batch,
    float* __restrict__ gfeat, int E) {
    int g = blockIdx.x, p = blockIdx.y, j = threadIdx.x;
    int s = lower_bound_bb(row, batch, E, g);
    int t = lower_bound_bb(row, batch, E, g + 1);
    int cnt = t - s;
    int chunk = (cnt + POOL_P - 1) / POOL_P;
    int e0 = s + p * chunk;
    int e1 = min(e0 + chunk, t);
    float sum = 0.f;
    for (int e = e0; e < e1; ++e) sum += x[(size_t)e * DDIM + j];
    if (e0 < e1)
        __hip_atomic_fetch_add(&gfeat[g * DDIM + j], sum, __ATOMIC_RELAXED,
                               __HIP_MEMORY_SCOPE_AGENT);
}

__global__ void __launch_bounds__(64) pool_final_k(
    const int* __restrict__ row, const int* __restrict__ batch,
    float* __restrict__ gfeat, int E) {
    int g = blockIdx.x, j = threadIdx.x;
    int s = lower_bound_bb(row, batch, E, g);
    int t = lower_bound_bb(row, batch, E, g + 1);
    float cnt = fmaxf((float)(t - s), 1.0f);
    gfeat[g * DDIM + j] /= cnt;
}

extern "C" void kernel_launch(void* const* d_in, const int* in_sizes, int n_in,
                              void* d_out, int out_size, void* d_ws, size_t ws_size,
                              hipStream_t stream) {
    (void)n_in; (void)out_size; (void)ws_size;
    const float* AF    = (const float*)d_in[0];
    const int*   batch = (const int*)d_in[3];
    const int*   edge_index      = (const int*)d_in[4];
    const int*   bond_edge_index = (const int*)d_in[5];
    const float* iw1 = (const float*)d_in[6];
    const float* ib1 = (const float*)d_in[7];
    const float* iw2 = (const float*)d_in[8];
    const float* ib2 = (const float*)d_in[9];
    const float* emb = (const float*)d_in[10];
    const float* mw1 = (const float*)d_in[11];
    const float* mb1 = (const float*)d_in[12];
    const float* mw2 = (const float*)d_in[13];
    const float* mb2 = (const float*)d_in[14];
    const float* uw1 = (const float*)d_in[15];
    const float* ub1 = (const float*)d_in[16];
    const float* uw2 = (const float*)d_in[17];
    const float* ub2 = (const float*)d_in[18];

    const int N  = in_sizes[0] / HDIM;
    const int E  = in_sizes[4] / 2;
    const int BE = in_sizes[5] / 2;
    const int NB = (E + 255) / 256;
    const int EB = (E + EPB - 1) / EPB;
    const int AB = (N + 4 * APW - 1) / (4 * APW);   // atom blocks (32 atoms/block)
    const int EBS = ((EB + 7) / 8) * 8;             // swizzled grid (multiple of 8)

    float* xout  = (float*)d_out;                 // [E,64]
    float* gfeat = xout + (size_t)E * DDIM;       // [16,64]

    // workspace layout
    char* w = (char*)d_ws;
    float* tt       = (float*)w;  w += sizeof(float) * 2 * NTYPES * DDIM;
    int*   cnt      = (int*)w;    w += sizeof(int) * E;
    int*   offs     = (int*)w;    w += sizeof(int) * (E + 1);
    int*   cursor   = (int*)w;    w += sizeof(int) * E;
    int*   bt       = (int*)w;    w += sizeof(int) * E;
    int*   bsum     = (int*)w;    w += sizeof(int) * 1024;
    int*   bpre     = (int*)w;    w += sizeof(int) * 1024;
    int*   srclist  = (int*)w;    w += sizeof(int) * BE;
    w = (char*)(((uintptr_t)w + 15) & ~(uintptr_t)15);
    float* pd       = (float*)w;  w += sizeof(float) * (size_t)E * DDIM;
    float* ps       = (float*)w;  w += sizeof(float) * (size_t)E * DDIM;
    float* pa       = (float*)w;  w += sizeof(float) * (size_t)N * DDIM;
    float* qa       = (float*)w;  w += sizeof(float) * (size_t)N * DDIM;
    float* na       = (float*)w;  w += sizeof(float) * (size_t)N;

    const int* row  = edge_index;
    const int* col  = edge_index + E;
    const int* bsrc = bond_edge_index;
    const int* bdst = bond_edge_index + BE;

    // CSR build
    hipMemsetAsync(cnt, 0, (size_t)E * sizeof(int), stream);
    count_k<<<(BE + 255) / 256, 256, 0, stream>>>(bdst, cnt, BE);
    bsum_k<<<NB, 256, 0, stream>>>(cnt, bsum, E);
    bscan_k<<<1, 1024, 0, stream>>>(bsum, bpre, NB);
    offs_k<<<NB, 256, 0, stream>>>(cnt, bpre, offs, cursor, E);
    scatter_k<<<(BE + 255) / 256, 256, 0, stream>>>(bsrc, bdst, cursor, srclist, BE);

    // bond-type embeddings for both layers
    tt2_k<<<2 * NTYPES, 64, 0, stream>>>(emb, mw1, mb1, tt);

    // atom projections, then bond init + layer-0 proj
    atom_proj_k<<<AB, 256, 0, stream>>>(AF, iw1, pa, qa, na, N);
    bond_init2_k<<<EBS, 256, 0, stream>>>(AF, row, col, pa, qa, na, ib1, iw2, ib2,
                                          mw1 /* layer 0 */, xout, bt, pd, ps, E);

    for (int l = 0; l < 2; ++l) {
        if (l > 0)
            proj_k<<<EB, 256, 0, stream>>>(xout, mw1 + (size_t)l * 192 * 64, pd, ps, E);
        layer_k<<<EBS, 256, 0, stream>>>(
            xout, pd, ps, tt + (size_t)l * NTYPES * DDIM, bt, offs, srclist, cnt,
            mw2 + (size_t)l * DDIM * DDIM, mb2 + (size_t)l * DDIM,
            uw1 + (size_t)l * 128 * 64, ub1 + (size_t)l * DDIM,
            uw2 + (size_t)l * DDIM * DDIM, ub2 + (size_t)l * DDIM, E);
    }

    hipMemsetAsync(gfeat, 0, NGRAPHS * DDIM * sizeof(float), stream);
    dim3 pg(NGRAPHS, POOL_P);
    pool_partial_k<<<pg, 64, 0, stream>>>(xout, row, batch, gfeat, E);
    pool_final_k<<<NGRAPHS, 64, 0, stream>>>(row, batch, gfeat, E);
}

// Round 8
// 461.730 us; speedup vs baseline: 1.0902x; 1.0079x over previous
//
#include <hip/hip_runtime.h>
#include <cstdint>
#include <cstddef>

#define HDIM 128
#define DDIM 64
#define NTYPES 5
#define NGRAPHS 16
#define POOL_P 16
#define EPB 64   // edges per block (one per lane)
#define APW 8    // atoms per wave in atom_proj

static __device__ __forceinline__ float silu_f(float v) {
    return v / (1.0f + __expf(-v));
}

static __device__ __forceinline__ float4 ld4(const float* p) {
    return *reinterpret_cast<const float4*>(p);
}

static __device__ __forceinline__ void st4(float* p, float4 v) {
    *reinterpret_cast<float4*>(p) = v;
}

static __device__ __forceinline__ float4 add4(float4 a, float4 b) {
    return make_float4(a.x + b.x, a.y + b.y, a.z + b.z, a.w + b.w);
}

static __device__ __forceinline__ void silu_acc4(float4& s, float4 v) {
    s.x += silu_f(v.x);
    s.y += silu_f(v.y);
    s.z += silu_f(v.z);
    s.w += silu_f(v.w);
}

// XCD-affinity swizzle (heuristic blk%8 -> XCD round-robin; validated r7:
// layer_k FETCH 82 -> 25.7 MB).
static __device__ __forceinline__ int xcd_logical_block() {
    int chunk = (int)(gridDim.x >> 3);
    return (int)(blockIdx.x & 7) * chunk + (int)(blockIdx.x >> 3);
}

// ---------------- CSR build ----------------
__global__ void __launch_bounds__(256) count_k(const int* __restrict__ bdst,
                                               int* __restrict__ cnt, int BE) {
    int i = blockIdx.x * 256 + threadIdx.x;
    if (i < BE)
        __hip_atomic_fetch_add(&cnt[bdst[i]], 1, __ATOMIC_RELAXED, __HIP_MEMORY_SCOPE_AGENT);
}

__global__ void __launch_bounds__(256) bsum_k(const int* __restrict__ cnt,
                                              int* __restrict__ bsum, int E) {
    __shared__ int red[256];
    int t = threadIdx.x;
    int i = blockIdx.x * 256 + t;
    red[t] = (i < E) ? cnt[i] : 0;
    __syncthreads();
    #pragma unroll
    for (int off = 128; off > 0; off >>= 1) {
        if (t < off) red[t] += red[t + off];
        __syncthreads();
    }
    if (t == 0) bsum[blockIdx.x] = red[0];
}

__global__ void __launch_bounds__(1024) bscan_k(const int* __restrict__ bsum,
                                                int* __restrict__ bpre, int NB) {
    __shared__ int sh[1024];
    int t = threadIdx.x;
    int v0 = (t < NB) ? bsum[t] : 0;
    sh[t] = v0;
    __syncthreads();
    for (int off = 1; off < 1024; off <<= 1) {
        int v = (t >= off) ? sh[t - off] : 0;
        __syncthreads();
        sh[t] += v;
        __syncthreads();
    }
    if (t < NB) bpre[t] = sh[t] - v0;
}

__global__ void __launch_bounds__(256) offs_k(const int* __restrict__ cnt,
                                              const int* __restrict__ bpre,
                                              int* __restrict__ offs,
                                              int* __restrict__ cursor, int E) {
    __shared__ int sh[256];
    int t = threadIdx.x;
    int i = blockIdx.x * 256 + t;
    int v0 = (i < E) ? cnt[i] : 0;
    sh[t] = v0;
    __syncthreads();
    for (int off = 1; off < 256; off <<= 1) {
        int v = (t >= off) ? sh[t - off] : 0;
        __syncthreads();
        sh[t] += v;
        __syncthreads();
    }
    int ex = sh[t] - v0 + bpre[blockIdx.x];
    if (i < E) { offs[i] = ex; cursor[i] = ex; }
    if (i == E - 1) offs[E] = ex + v0;
}

__global__ void __launch_bounds__(256) scatter_k(const int* __restrict__ bsrc,
                                                 const int* __restrict__ bdst,
                                                 int* __restrict__ cursor,
                                                 int* __restrict__ srclist, int BE) {
    int i = blockIdx.x * 256 + threadIdx.x;
    if (i < BE) {
        int d = bdst[i];
        int p = __hip_atomic_fetch_add(&cursor[d], 1, __ATOMIC_RELAXED,
                                       __HIP_MEMORY_SCOPE_AGENT);
        srclist[p] = bsrc[i];
    }
}

// tt for BOTH layers
__global__ void __launch_bounds__(64) tt2_k(const float* __restrict__ emb,
                                            const float* __restrict__ mw1,
                                            const float* __restrict__ mb1,
                                            float* __restrict__ tt) {
    int b = blockIdx.x;
    int l = b / NTYPES, t = b % NTYPES, j = threadIdx.x;
    const float* embl = emb + (size_t)l * NTYPES * DDIM + (size_t)t * DDIM;
    const float* w1 = mw1 + (size_t)l * 192 * DDIM;
    float s = mb1[l * DDIM + j];
    #pragma unroll 8
    for (int k = 0; k < DDIM; ++k)
        s = fmaf(embl[k], w1[(HDIM + k) * DDIM + j], s);
    tt[(size_t)b * DDIM + j] = s;
}

// Fused weights: W2u[l] = mw2[l] @ uw1[l][0:64]; b2u[l] = mb2[l] @ uw1[l][0:64].
// grid = 2*64 blocks (l,k), 64 threads (j).
__global__ void __launch_bounds__(64) fuse_k(const float* __restrict__ mw2,
                                             const float* __restrict__ mb2,
                                             const float* __restrict__ uw1,
                                             float* __restrict__ w2u,
                                             float* __restrict__ b2u) {
    int l = blockIdx.x >> 6, k = blockIdx.x & 63, j = threadIdx.x;
    const float* w2 = mw2 + (size_t)l * DDIM * DDIM;
    const float* u1 = uw1 + (size_t)l * 128 * DDIM;   // rows 0..63 = mm part
    float s = 0.f;
    #pragma unroll 8
    for (int t = 0; t < DDIM; ++t)
        s = fmaf(w2[k * DDIM + t], u1[(size_t)t * DDIM + j], s);
    w2u[(size_t)l * DDIM * DDIM + (size_t)k * DDIM + j] = s;
    if (k == 0) {
        float b = 0.f;
        #pragma unroll 8
        for (int t = 0; t < DDIM; ++t)
            b = fmaf(mb2[l * DDIM + t], u1[(size_t)t * DDIM + j], b);
        b2u[l * DDIM + j] = b;
    }
}

// ---------------- atom-side projection: wave-per-8-atoms, lane = feature ----------------
__global__ void __launch_bounds__(256) atom_proj_k(
    const float* __restrict__ AF, const float* __restrict__ iw1,
    float* __restrict__ pa, float* __restrict__ qa, float* __restrict__ na, int N) {
    int lane = threadIdx.x & 63;
    int w = __builtin_amdgcn_readfirstlane((int)(threadIdx.x >> 6));
    int abase = blockIdx.x * (4 * APW) + w * APW;
    if (abase >= N) return;

    float accp[APW], accq[APW], nrm[APW];
    #pragma unroll
    for (int a = 0; a < APW; ++a) { accp[a] = 0.f; accq[a] = 0.f; nrm[a] = 0.f; }

    #pragma unroll 4
    for (int k = 0; k < HDIM; k += 4) {
        float wt[4], wb[4];
        #pragma unroll
        for (int kk = 0; kk < 4; ++kk) {
            wt[kk] = iw1[(size_t)(k + kk) * DDIM + lane];
            wb[kk] = iw1[(size_t)(HDIM + k + kk) * DDIM + lane];
        }
        #pragma unroll
        for (int a = 0; a < APW; ++a) {
            int aa = min(abase + a, N - 1);           // wave-uniform
            float4 hv = ld4(AF + (size_t)aa * HDIM + k);
            accp[a] = fmaf(hv.x, wt[0], accp[a]);
            accp[a] = fmaf(hv.y, wt[1], accp[a]);
            accp[a] = fmaf(hv.z, wt[2], accp[a]);
            accp[a] = fmaf(hv.w, wt[3], accp[a]);
            accq[a] = fmaf(hv.x, wb[0], accq[a]);
            accq[a] = fmaf(hv.y, wb[1], accq[a]);
            accq[a] = fmaf(hv.z, wb[2], accq[a]);
            accq[a] = fmaf(hv.w, wb[3], accq[a]);
            nrm[a] = fmaf(hv.x, hv.x, nrm[a]);
            nrm[a] = fmaf(hv.y, hv.y, nrm[a]);
            nrm[a] = fmaf(hv.z, hv.z, nrm[a]);
            nrm[a] = fmaf(hv.w, hv.w, nrm[a]);
        }
    }
    #pragma unroll
    for (int a = 0; a < APW; ++a) {
        int atom = abase + a;
        if (atom < N) {
            pa[(size_t)atom * DDIM + lane] = accp[a];
            qa[(size_t)atom * DDIM + lane] = accq[a];
            if (lane == 0) na[atom] = sqrtf(nrm[a]);
        }
    }
}

// ---------------- bond init (from atom projections) + layer-0 proj ----------------
__global__ void __launch_bounds__(256) bond_init2_k(
    const float* __restrict__ AF, const int* __restrict__ row, const int* __restrict__ col,
    const float* __restrict__ pa, const float* __restrict__ qa, const float* __restrict__ na,
    const float* __restrict__ b1, const float* __restrict__ w2, const float* __restrict__ b2,
    const float* __restrict__ w1p /*[192][64] layer0 mw1*/,
    float* __restrict__ x, int* __restrict__ bt,
    float* __restrict__ pd, float* __restrict__ ps, int E) {
    __shared__ float hbuf[EPB][DDIM + 1];
    __shared__ float dotb[EPB][5];
    int nEB = (E + EPB - 1) / EPB;
    int lb = xcd_logical_block();
    if (lb >= nEB) return;
    int lane = threadIdx.x & 63;
    int w = __builtin_amdgcn_readfirstlane((int)(threadIdx.x >> 6));
    int e = lb * EPB + lane;
    bool ok = e < E;
    int eidx = ok ? e : 0;
    int r = row[eidx], c = col[eidx];
    int j0 = w * 16;

    // partial dot over K-chunk [32w, 32w+32)
    {
        const float* hi = AF + (size_t)r * HDIM + w * 32;
        const float* hj = AF + (size_t)c * HDIM + w * 32;
        float d = 0.f;
        #pragma unroll
        for (int k = 0; k < 32; k += 4) {
            float4 a4 = ld4(hi + k), b4 = ld4(hj + k);
            d += a4.x * b4.x + a4.y * b4.y + a4.z * b4.z + a4.w * b4.w;
        }
        dotb[lane][w] = d;
    }

    // layer-1 hidden slice: silu(pa[r] + qa[c] + b1)
    {
        const float* pr = pa + (size_t)r * DDIM + j0;
        const float* qc = qa + (size_t)c * DDIM + j0;
        #pragma unroll
        for (int q = 0; q < 4; ++q) {
            float4 pv = ld4(pr + q * 4);
            float4 qv = ld4(qc + q * 4);
            hbuf[lane][j0 + q * 4 + 0] = silu_f(pv.x + qv.x + b1[j0 + q * 4 + 0]);
            hbuf[lane][j0 + q * 4 + 1] = silu_f(pv.y + qv.y + b1[j0 + q * 4 + 1]);
            hbuf[lane][j0 + q * 4 + 2] = silu_f(pv.z + qv.z + b1[j0 + q * 4 + 2]);
            hbuf[lane][j0 + q * 4 + 3] = silu_f(pv.w + qv.w + b1[j0 + q * 4 + 3]);
        }
    }
    __syncthreads();

    if (w == 0) {
        float dot = dotb[lane][0] + dotb[lane][1] + dotb[lane][2] + dotb[lane][3];
        float nr = fmaxf(na[r], 1e-8f), nc = fmaxf(na[c], 1e-8f);
        float sim = dot / (nr * nc);
        int t = 0;
        if (sim > 0.8f) t = 1;
        if (sim > 0.9f) t = 2;
        if (sim < 0.3f) t = 3;
        if (ok) bt[e] = t;
    }

    // layer-2: x = h @ w2 + b2 (K=64 from LDS)
    float o[16];
    #pragma unroll
    for (int jj = 0; jj < 16; ++jj) o[jj] = b2[j0 + jj];
    #pragma unroll 4
    for (int k = 0; k < DDIM; ++k) {
        float hk = hbuf[lane][k];
        const float* wk = w2 + (size_t)k * DDIM + j0;
        #pragma unroll
        for (int jj = 0; jj < 16; ++jj) o[jj] = fmaf(hk, wk[jj], o[jj]);
    }
    if (ok) {
        float* xr = x + (size_t)e * DDIM + j0;
        st4(xr + 0,  make_float4(o[0],  o[1],  o[2],  o[3]));
        st4(xr + 4,  make_float4(o[4],  o[5],  o[6],  o[7]));
        st4(xr + 8,  make_float4(o[8],  o[9],  o[10], o[11]));
        st4(xr + 12, make_float4(o[12], o[13], o[14], o[15]));
    }
    __syncthreads();
    #pragma unroll
    for (int jj = 0; jj < 16; ++jj) hbuf[lane][j0 + jj] = o[jj];   // x row
    __syncthreads();

    // proj (layer 0): pd = x@W1[0:64], ps = x@W1[64:128]
    float apd[16], aps[16];
    #pragma unroll
    for (int jj = 0; jj < 16; ++jj) { apd[jj] = 0.f; aps[jj] = 0.f; }
    #pragma unroll 4
    for (int k = 0; k < DDIM; ++k) {
        float xk = hbuf[lane][k];
        const float* wd = w1p + (size_t)k * DDIM + j0;
        const float* wsv = w1p + (size_t)(DDIM + k) * DDIM + j0;
        #pragma unroll
        for (int jj = 0; jj < 16; ++jj) {
            apd[jj] = fmaf(xk, wd[jj], apd[jj]);
            aps[jj] = fmaf(xk, wsv[jj], aps[jj]);
        }
    }
    if (ok) {
        float* pr = pd + (size_t)e * DDIM + j0;
        float* qr = ps + (size_t)e * DDIM + j0;
        st4(pr + 0,  make_float4(apd[0],  apd[1],  apd[2],  apd[3]));
        st4(pr + 4,  make_float4(apd[4],  apd[5],  apd[6],  apd[7]));
        st4(pr + 8,  make_float4(apd[8],  apd[9],  apd[10], apd[11]));
        st4(pr + 12, make_float4(apd[12], apd[13], apd[14], apd[15]));
        st4(qr + 0,  make_float4(aps[0],  aps[1],  aps[2],  aps[3]));
        st4(qr + 4,  make_float4(aps[4],  aps[5],  aps[6],  aps[7]));
        st4(qr + 8,  make_float4(aps[8],  aps[9],  aps[10], aps[11]));
        st4(qr + 12, make_float4(aps[12], aps[13], aps[14], aps[15]));
    }
}

// proj for layer 1 (x from global)
__global__ void __launch_bounds__(256) proj_k(const float* __restrict__ x,
                                              const float* __restrict__ w1 /*[192][64]*/,
                                              float* __restrict__ pd, float* __restrict__ ps,
                                              int E) {
    int lane = threadIdx.x & 63;
    int w = __builtin_amdgcn_readfirstlane((int)(threadIdx.x >> 6));
    int e = blockIdx.x * EPB + lane;
    bool ok = e < E;
    int eidx = ok ? e : 0;
    int j0 = w * 16;
    const float* xr = x + (size_t)eidx * DDIM;

    float apd[16], aps[16];
    #pragma unroll
    for (int jj = 0; jj < 16; ++jj) { apd[jj] = 0.f; aps[jj] = 0.f; }
    #pragma unroll 2
    for (int c = 0; c < 16; ++c) {
        float4 v = ld4(xr + c * 4);
        float xv[4] = {v.x, v.y, v.z, v.w};
        #pragma unroll
        for (int kk = 0; kk < 4; ++kk) {
            int k = c * 4 + kk;
            const float* wd = w1 + (size_t)k * DDIM + j0;
            const float* wsv = w1 + (size_t)(DDIM + k) * DDIM + j0;
            #pragma unroll
            for (int jj = 0; jj < 16; ++jj) {
                apd[jj] = fmaf(xv[kk], wd[jj], apd[jj]);
                aps[jj] = fmaf(xv[kk], wsv[jj], aps[jj]);
            }
        }
    }
    if (ok) {
        float* pr = pd + (size_t)e * DDIM + j0;
        float* qr = ps + (size_t)e * DDIM + j0;
        st4(pr + 0,  make_float4(apd[0],  apd[1],  apd[2],  apd[3]));
        st4(pr + 4,  make_float4(apd[4],  apd[5],  apd[6],  apd[7]));
        st4(pr + 8,  make_float4(apd[8],  apd[9],  apd[10], apd[11]));
        st4(pr + 12, make_float4(apd[12], apd[13], apd[14], apd[15]));
        st4(qr + 0,  make_float4(aps[0],  aps[1],  aps[2],  aps[3]));
        st4(qr + 4,  make_float4(aps[4],  aps[5],  aps[6],  aps[7]));
        st4(qr + 8,  make_float4(aps[8],  aps[9],  aps[10], aps[11]));
        st4(qr + 12, make_float4(aps[12], aps[13], aps[14], aps[15]));
    }
}

// ---------------- fused gather + update (mm folded into W2u) ----------------
// P1: gather s -> sb.  P3': h = silu(inv*(s@W2u) + inv*deg*b2u + x@Wu1[64:] + ub1).
// sb overwritten with h.  P4: x += h@Wu2 + ub2.  Single LDS buffer.
__global__ void __launch_bounds__(256) layer_k(
    float* __restrict__ x, const float* __restrict__ pd, const float* __restrict__ ps,
    const float* __restrict__ tt_l, const int* __restrict__ bt,
    const int* __restrict__ offs, const int* __restrict__ srclist,
    const int* __restrict__ cnt,
    const float* __restrict__ w2u, const float* __restrict__ b2u,
    const float* __restrict__ uw1 /*[128][64], rows 64..127 used*/,
    const float* __restrict__ ub1,
    const float* __restrict__ uw2 /*[64][64]*/, const float* __restrict__ ub2, int E) {
    __shared__ float sb[EPB][DDIM + 1];
    int nEB = (E + EPB - 1) / EPB;
    int lb = xcd_logical_block();
    if (lb >= nEB) return;
    int lane = threadIdx.x & 63;
    int w = __builtin_amdgcn_readfirstlane((int)(threadIdx.x >> 6));
    int e = lb * EPB + lane;
    bool ok = e < E;
    int eidx = ok ? e : 0;
    int j0 = w * 16;

    // ---- P1: gather (thread = (d_local, q)), 2-way unrolled ----
    {
        int d_local = threadIdx.x >> 2, q = threadIdx.x & 3;
        int d = lb * EPB + d_local;
        if (d < E) {
            int jq = q * 16;
            const float* pr = pd + (size_t)d * DDIM + jq;
            const float* tp = tt_l + (size_t)bt[d] * DDIM + jq;
            float4 b0 = add4(ld4(pr + 0),  ld4(tp + 0));
            float4 b1 = add4(ld4(pr + 4),  ld4(tp + 4));
            float4 b2 = add4(ld4(pr + 8),  ld4(tp + 8));
            float4 b3 = add4(ld4(pr + 12), ld4(tp + 12));
            float4 s0 = make_float4(0, 0, 0, 0), s1 = s0, s2 = s0, s3 = s0;
            int p0 = offs[d], p1 = offs[d + 1];
            int p = p0;
            for (; p + 2 <= p1; p += 2) {
                const float* sa = ps + (size_t)srclist[p] * DDIM + jq;
                const float* sc = ps + (size_t)srclist[p + 1] * DDIM + jq;
                float4 u0 = ld4(sa + 0), u1 = ld4(sa + 4);
                float4 u2 = ld4(sa + 8), u3 = ld4(sa + 12);
                float4 v0 = ld4(sc + 0), v1 = ld4(sc + 4);
                float4 v2 = ld4(sc + 8), v3 = ld4(sc + 12);
                silu_acc4(s0, add4(b0, u0));
                silu_acc4(s1, add4(b1, u1));
                silu_acc4(s2, add4(b2, u2));
                silu_acc4(s3, add4(b3, u3));
                silu_acc4(s0, add4(b0, v0));
                silu_acc4(s1, add4(b1, v1));
                silu_acc4(s2, add4(b2, v2));
                silu_acc4(s3, add4(b3, v3));
            }
            if (p < p1) {
                const float* sa = ps + (size_t)srclist[p] * DDIM + jq;
                float4 u0 = ld4(sa + 0), u1 = ld4(sa + 4);
                float4 u2 = ld4(sa + 8), u3 = ld4(sa + 12);
                silu_acc4(s0, add4(b0, u0));
                silu_acc4(s1, add4(b1, u1));
                silu_acc4(s2, add4(b2, u2));
                silu_acc4(s3, add4(b3, u3));
            }
            st4(&sb[d_local][jq + 0],  s0);
            st4(&sb[d_local][jq + 4],  s1);
            st4(&sb[d_local][jq + 8],  s2);
            st4(&sb[d_local][jq + 12], s3);
        }
    }
    __syncthreads();

    // ---- P3': h = silu(inv*(s@W2u) + inv*deg*b2u + x@Wu1[64:] + ub1) ----
    float degf = (float)cnt[eidx];
    float inv = 1.0f / fmaxf(degf, 1.0f);
    const float* xr = x + (size_t)eidx * DDIM;
    float h[16];
    {
        float sm[16];
        #pragma unroll
        for (int jj = 0; jj < 16; ++jj) sm[jj] = 0.f;
        #pragma unroll 4
        for (int k = 0; k < DDIM; ++k) {
            float sk = sb[lane][k];
            const float* wk = w2u + (size_t)k * DDIM + j0;
            #pragma unroll
            for (int jj = 0; jj < 16; ++jj) sm[jj] = fmaf(sk, wk[jj], sm[jj]);
        }
        float ah[16];
        float dib = degf * inv;
        #pragma unroll
        for (int jj = 0; jj < 16; ++jj)
            ah[jj] = fmaf(inv, sm[jj], fmaf(dib, b2u[j0 + jj], ub1[j0 + jj]));
        #pragma unroll 2
        for (int c = 0; c < 16; ++c) {
            float4 v = ld4(xr + c * 4);
            float xv[4] = {v.x, v.y, v.z, v.w};
            #pragma unroll
            for (int kk = 0; kk < 4; ++kk) {
                const float* wk = uw1 + (size_t)(DDIM + c * 4 + kk) * DDIM + j0;
                #pragma unroll
                for (int jj = 0; jj < 16; ++jj) ah[jj] = fmaf(xv[kk], wk[jj], ah[jj]);
            }
        }
        #pragma unroll
        for (int jj = 0; jj < 16; ++jj) h[jj] = silu_f(ah[jj]);
    }
    __syncthreads();     // all reads of sb (s) done
    #pragma unroll
    for (int jj = 0; jj < 16; ++jj) sb[lane][j0 + jj] = h[jj];
    __syncthreads();

    // ---- P4: u-layer2 + residual ----
    {
        float o[16];
        #pragma unroll
        for (int jj = 0; jj < 16; ++jj) o[jj] = ub2[j0 + jj];
        #pragma unroll 4
        for (int k = 0; k < DDIM; ++k) {
            float hk = sb[lane][k];
            const float* wk = uw2 + (size_t)k * DDIM + j0;
            #pragma unroll
            for (int jj = 0; jj < 16; ++jj) o[jj] = fmaf(hk, wk[jj], o[jj]);
        }
        if (ok) {
            float* xw = x + (size_t)e * DDIM + j0;
            #pragma unroll
            for (int q = 0; q < 4; ++q) {
                float4 xo = ld4(xw + q * 4);
                xo.x += o[q * 4 + 0];
                xo.y += o[q * 4 + 1];
                xo.z += o[q * 4 + 2];
                xo.w += o[q * 4 + 3];
                st4(xw + q * 4, xo);
            }
        }
    }
}

// ---------------- pooling ----------------
static __device__ __forceinline__ int lower_bound_bb(const int* __restrict__ row,
                                                     const int* __restrict__ batch,
                                                     int E, int g) {
    int lo = 0, hi = E;
    while (lo < hi) {
        int m = (lo + hi) >> 1;
        if (batch[row[m]] < g) lo = m + 1; else hi = m;
    }
    return lo;
}

__global__ void __launch_bounds__(64) pool_partial_k(
    const float* __restrict__ x, const int* __restrict__ row, const int* __restrict__ batch,
    float* __restrict__ gfeat, int E) {
    int g = blockIdx.x, p = blockIdx.y, j = threadIdx.x;
    int s = lower_bound_bb(row, batch, E, g);
    int t = lower_bound_bb(row, batch, E, g + 1);
    int cnt = t - s;
    int chunk = (cnt + POOL_P - 1) / POOL_P;
    int e0 = s + p * chunk;
    int e1 = min(e0 + chunk, t);
    float sum = 0.f;
    for (int e = e0; e < e1; ++e) sum += x[(size_t)e * DDIM + j];
    if (e0 < e1)
        __hip_atomic_fetch_add(&gfeat[g * DDIM + j], sum, __ATOMIC_RELAXED,
                               __HIP_MEMORY_SCOPE_AGENT);
}

__global__ void __launch_bounds__(64) pool_final_k(
    const int* __restrict__ row, const int* __restrict__ batch,
    float* __restrict__ gfeat, int E) {
    int g = blockIdx.x, j = threadIdx.x;
    int s = lower_bound_bb(row, batch, E, g);
    int t = lower_bound_bb(row, batch, E, g + 1);
    float cnt = fmaxf((float)(t - s), 1.0f);
    gfeat[g * DDIM + j] /= cnt;
}

extern "C" void kernel_launch(void* const* d_in, const int* in_sizes, int n_in,
                              void* d_out, int out_size, void* d_ws, size_t ws_size,
                              hipStream_t stream) {
    (void)n_in; (void)out_size; (void)ws_size;
    const float* AF    = (const float*)d_in[0];
    const int*   batch = (const int*)d_in[3];
    const int*   edge_index      = (const int*)d_in[4];
    const int*   bond_edge_index = (const int*)d_in[5];
    const float* iw1 = (const float*)d_in[6];
    const float* ib1 = (const float*)d_in[7];
    const float* iw2 = (const float*)d_in[8];
    const float* ib2 = (const float*)d_in[9];
    const float* emb = (const float*)d_in[10];
    const float* mw1 = (const float*)d_in[11];
    const float* mb1 = (const float*)d_in[12];
    const float* mw2 = (const float*)d_in[13];
    const float* mb2 = (const float*)d_in[14];
    const float* uw1 = (const float*)d_in[15];
    const float* ub1 = (const float*)d_in[16];
    const float* uw2 = (const float*)d_in[17];
    const float* ub2 = (const float*)d_in[18];

    const int N  = in_sizes[0] / HDIM;
    const int E  = in_sizes[4] / 2;
    const int BE = in_sizes[5] / 2;
    const int NB = (E + 255) / 256;
    const int EB = (E + EPB - 1) / EPB;
    const int AB = (N + 4 * APW - 1) / (4 * APW);   // atom blocks (32 atoms/block)
    const int EBS = ((EB + 7) / 8) * 8;             // swizzled grid (multiple of 8)

    float* xout  = (float*)d_out;                 // [E,64]
    float* gfeat = xout + (size_t)E * DDIM;       // [16,64]

    // workspace layout
    char* w = (char*)d_ws;
    float* tt       = (float*)w;  w += sizeof(float) * 2 * NTYPES * DDIM;
    float* w2u      = (float*)w;  w += sizeof(float) * 2 * DDIM * DDIM;
    float* b2u      = (float*)w;  w += sizeof(float) * 2 * DDIM;
    int*   cnt      = (int*)w;    w += sizeof(int) * E;
    int*   offs     = (int*)w;    w += sizeof(int) * (E + 1);
    int*   cursor   = (int*)w;    w += sizeof(int) * E;
    int*   bt       = (int*)w;    w += sizeof(int) * E;
    int*   bsum     = (int*)w;    w += sizeof(int) * 1024;
    int*   bpre     = (int*)w;    w += sizeof(int) * 1024;
    int*   srclist  = (int*)w;    w += sizeof(int) * BE;
    w = (char*)(((uintptr_t)w + 15) & ~(uintptr_t)15);
    float* pd       = (float*)w;  w += sizeof(float) * (size_t)E * DDIM;
    float* ps       = (float*)w;  w += sizeof(float) * (size_t)E * DDIM;
    float* pa       = (float*)w;  w += sizeof(float) * (size_t)N * DDIM;
    float* qa       = (float*)w;  w += sizeof(float) * (size_t)N * DDIM;
    float* na       = (float*)w;  w += sizeof(float) * (size_t)N;

    const int* row  = edge_index;
    const int* col  = edge_index + E;
    const int* bsrc = bond_edge_index;
    const int* bdst = bond_edge_index + BE;

    // CSR build
    hipMemsetAsync(cnt, 0, (size_t)E * sizeof(int), stream);
    count_k<<<(BE + 255) / 256, 256, 0, stream>>>(bdst, cnt, BE);
    bsum_k<<<NB, 256, 0, stream>>>(cnt, bsum, E);
    bscan_k<<<1, 1024, 0, stream>>>(bsum, bpre, NB);
    offs_k<<<NB, 256, 0, stream>>>(cnt, bpre, offs, cursor, E);
    scatter_k<<<(BE + 255) / 256, 256, 0, stream>>>(bsrc, bdst, cursor, srclist, BE);

    // constants: bond-type embeddings + fused mm weights
    tt2_k<<<2 * NTYPES, 64, 0, stream>>>(emb, mw1, mb1, tt);
    fuse_k<<<2 * 64, 64, 0, stream>>>(mw2, mb2, uw1, w2u, b2u);

    // atom projections, then bond init + layer-0 proj
    atom_proj_k<<<AB, 256, 0, stream>>>(AF, iw1, pa, qa, na, N);
    bond_init2_k<<<EBS, 256, 0, stream>>>(AF, row, col, pa, qa, na, ib1, iw2, ib2,
                                          mw1 /* layer 0 */, xout, bt, pd, ps, E);

    for (int l = 0; l < 2; ++l) {
        if (l > 0)
            proj_k<<<EB, 256, 0, stream>>>(xout, mw1 + (size_t)l * 192 * 64, pd, ps, E);
        layer_k<<<EBS, 256, 0, stream>>>(
            xout, pd, ps, tt + (size_t)l * NTYPES * DDIM, bt, offs, srclist, cnt,
            w2u + (size_t)l * DDIM * DDIM, b2u + (size_t)l * DDIM,
            uw1 + (size_t)l * 128 * 64, ub1 + (size_t)l * DDIM,
            uw2 + (size_t)l * DDIM * DDIM, ub2 + (size_t)l * DDIM, E);
    }

    hipMemsetAsync(gfeat, 0, NGRAPHS * DDIM * sizeof(float), stream);
    dim3 pg(NGRAPHS, POOL_P);
    pool_partial_k<<<pg, 64, 0, stream>>>(xout, row, batch, gfeat, E);
    pool_final_k<<<NGRAPHS, 64, 0, stream>>>(row, batch, gfeat, E);
}

// Round 9
// 417.302 us; speedup vs baseline: 1.2063x; 1.1065x over previous
//
#include <hip/hip_runtime.h>
#include <cstdint>
#include <cstddef>

#define HDIM 128
#define DDIM 64
#define NTYPES 5
#define NGRAPHS 16
#define PCHUNK 128   // edges per pooling block
#define EPB 64       // edges per block (one per lane)
#define APW 8        // atoms per wave in atom_proj

static __device__ __forceinline__ float silu_f(float v) {
    return v / (1.0f + __expf(-v));
}

static __device__ __forceinline__ float4 ld4(const float* p) {
    return *reinterpret_cast<const float4*>(p);
}

static __device__ __forceinline__ void st4(float* p, float4 v) {
    *reinterpret_cast<float4*>(p) = v;
}

static __device__ __forceinline__ float4 add4(float4 a, float4 b) {
    return make_float4(a.x + b.x, a.y + b.y, a.z + b.z, a.w + b.w);
}

static __device__ __forceinline__ void silu_acc4(float4& s, float4 v) {
    s.x += silu_f(v.x);
    s.y += silu_f(v.y);
    s.z += silu_f(v.z);
    s.w += silu_f(v.w);
}

// XCD-affinity swizzle (heuristic blk%8 -> XCD round-robin; validated r7:
// layer_k FETCH 82 -> 25.7 MB).
static __device__ __forceinline__ int xcd_logical_block() {
    int chunk = (int)(gridDim.x >> 3);
    return (int)(blockIdx.x & 7) * chunk + (int)(blockIdx.x >> 3);
}

// ---------------- CSR build ----------------
__global__ void __launch_bounds__(256) count_k(const int* __restrict__ bdst,
                                               int* __restrict__ cnt, int BE) {
    int i = blockIdx.x * 256 + threadIdx.x;
    if (i < BE)
        __hip_atomic_fetch_add(&cnt[bdst[i]], 1, __ATOMIC_RELAXED, __HIP_MEMORY_SCOPE_AGENT);
}

__global__ void __launch_bounds__(256) bsum_k(const int* __restrict__ cnt,
                                              int* __restrict__ bsum, int E) {
    __shared__ int red[256];
    int t = threadIdx.x;
    int i = blockIdx.x * 256 + t;
    red[t] = (i < E) ? cnt[i] : 0;
    __syncthreads();
    #pragma unroll
    for (int off = 128; off > 0; off >>= 1) {
        if (t < off) red[t] += red[t + off];
        __syncthreads();
    }
    if (t == 0) bsum[blockIdx.x] = red[0];
}

__global__ void __launch_bounds__(1024) bscan_k(const int* __restrict__ bsum,
                                                int* __restrict__ bpre, int NB) {
    __shared__ int sh[1024];
    int t = threadIdx.x;
    int v0 = (t < NB) ? bsum[t] : 0;
    sh[t] = v0;
    __syncthreads();
    for (int off = 1; off < 1024; off <<= 1) {
        int v = (t >= off) ? sh[t - off] : 0;
        __syncthreads();
        sh[t] += v;
        __syncthreads();
    }
    if (t < NB) bpre[t] = sh[t] - v0;
}

__global__ void __launch_bounds__(256) offs_k(const int* __restrict__ cnt,
                                              const int* __restrict__ bpre,
                                              int* __restrict__ offs,
                                              int* __restrict__ cursor, int E) {
    __shared__ int sh[256];
    int t = threadIdx.x;
    int i = blockIdx.x * 256 + t;
    int v0 = (i < E) ? cnt[i] : 0;
    sh[t] = v0;
    __syncthreads();
    for (int off = 1; off < 256; off <<= 1) {
        int v = (t >= off) ? sh[t - off] : 0;
        __syncthreads();
        sh[t] += v;
        __syncthreads();
    }
    int ex = sh[t] - v0 + bpre[blockIdx.x];
    if (i < E) { offs[i] = ex; cursor[i] = ex; }
    if (i == E - 1) offs[E] = ex + v0;
}

__global__ void __launch_bounds__(256) scatter_k(const int* __restrict__ bsrc,
                                                 const int* __restrict__ bdst,
                                                 int* __restrict__ cursor,
                                                 int* __restrict__ srclist, int BE) {
    int i = blockIdx.x * 256 + threadIdx.x;
    if (i < BE) {
        int d = bdst[i];
        int p = __hip_atomic_fetch_add(&cursor[d], 1, __ATOMIC_RELAXED,
                                       __HIP_MEMORY_SCOPE_AGENT);
        srclist[p] = bsrc[i];
    }
}

// tt for BOTH layers
__global__ void __launch_bounds__(64) tt2_k(const float* __restrict__ emb,
                                            const float* __restrict__ mw1,
                                            const float* __restrict__ mb1,
                                            float* __restrict__ tt) {
    int b = blockIdx.x;
    int l = b / NTYPES, t = b % NTYPES, j = threadIdx.x;
    const float* embl = emb + (size_t)l * NTYPES * DDIM + (size_t)t * DDIM;
    const float* w1 = mw1 + (size_t)l * 192 * DDIM;
    float s = mb1[l * DDIM + j];
    #pragma unroll 8
    for (int k = 0; k < DDIM; ++k)
        s = fmaf(embl[k], w1[(HDIM + k) * DDIM + j], s);
    tt[(size_t)b * DDIM + j] = s;
}

// Fused weights: W2u[l] = mw2[l] @ uw1[l][0:64]; b2u[l] = mb2[l] @ uw1[l][0:64].
__global__ void __launch_bounds__(64) fuse_k(const float* __restrict__ mw2,
                                             const float* __restrict__ mb2,
                                             const float* __restrict__ uw1,
                                             float* __restrict__ w2u,
                                             float* __restrict__ b2u) {
    int l = blockIdx.x >> 6, k = blockIdx.x & 63, j = threadIdx.x;
    const float* w2 = mw2 + (size_t)l * DDIM * DDIM;
    const float* u1 = uw1 + (size_t)l * 128 * DDIM;   // rows 0..63 = mm part
    float s = 0.f;
    #pragma unroll 8
    for (int t = 0; t < DDIM; ++t)
        s = fmaf(w2[k * DDIM + t], u1[(size_t)t * DDIM + j], s);
    w2u[(size_t)l * DDIM * DDIM + (size_t)k * DDIM + j] = s;
    if (k == 0) {
        float b = 0.f;
        #pragma unroll 8
        for (int t = 0; t < DDIM; ++t)
            b = fmaf(mb2[l * DDIM + t], u1[(size_t)t * DDIM + j], b);
        b2u[l * DDIM + j] = b;
    }
}

// ---------------- atom-side projection: wave-per-8-atoms, lane = feature ----------------
__global__ void __launch_bounds__(256) atom_proj_k(
    const float* __restrict__ AF, const float* __restrict__ iw1,
    float* __restrict__ pa, float* __restrict__ qa, float* __restrict__ na, int N) {
    int lane = threadIdx.x & 63;
    int w = __builtin_amdgcn_readfirstlane((int)(threadIdx.x >> 6));
    int abase = blockIdx.x * (4 * APW) + w * APW;
    if (abase >= N) return;

    float accp[APW], accq[APW], nrm[APW];
    #pragma unroll
    for (int a = 0; a < APW; ++a) { accp[a] = 0.f; accq[a] = 0.f; nrm[a] = 0.f; }

    #pragma unroll 4
    for (int k = 0; k < HDIM; k += 4) {
        float wt[4], wb[4];
        #pragma unroll
        for (int kk = 0; kk < 4; ++kk) {
            wt[kk] = iw1[(size_t)(k + kk) * DDIM + lane];
            wb[kk] = iw1[(size_t)(HDIM + k + kk) * DDIM + lane];
        }
        #pragma unroll
        for (int a = 0; a < APW; ++a) {
            int aa = min(abase + a, N - 1);           // wave-uniform
            float4 hv = ld4(AF + (size_t)aa * HDIM + k);
            accp[a] = fmaf(hv.x, wt[0], accp[a]);
            accp[a] = fmaf(hv.y, wt[1], accp[a]);
            accp[a] = fmaf(hv.z, wt[2], accp[a]);
            accp[a] = fmaf(hv.w, wt[3], accp[a]);
            accq[a] = fmaf(hv.x, wb[0], accq[a]);
            accq[a] = fmaf(hv.y, wb[1], accq[a]);
            accq[a] = fmaf(hv.z, wb[2], accq[a]);
            accq[a] = fmaf(hv.w, wb[3], accq[a]);
            nrm[a] = fmaf(hv.x, hv.x, nrm[a]);
            nrm[a] = fmaf(hv.y, hv.y, nrm[a]);
            nrm[a] = fmaf(hv.z, hv.z, nrm[a]);
            nrm[a] = fmaf(hv.w, hv.w, nrm[a]);
        }
    }
    #pragma unroll
    for (int a = 0; a < APW; ++a) {
        int atom = abase + a;
        if (atom < N) {
            pa[(size_t)atom * DDIM + lane] = accp[a];
            qa[(size_t)atom * DDIM + lane] = accq[a];
            if (lane == 0) na[atom] = sqrtf(nrm[a]);
        }
    }
}

// ---------------- bond init (from atom projections) + layer-0 proj ----------------
__global__ void __launch_bounds__(256) bond_init2_k(
    const float* __restrict__ AF, const int* __restrict__ row, const int* __restrict__ col,
    const float* __restrict__ pa, const float* __restrict__ qa, const float* __restrict__ na,
    const float* __restrict__ b1, const float* __restrict__ w2, const float* __restrict__ b2,
    const float* __restrict__ w1p /*[192][64] layer0 mw1*/,
    float* __restrict__ x, int* __restrict__ bt,
    float* __restrict__ pd, float* __restrict__ ps, int E) {
    __shared__ float hbuf[EPB][DDIM + 1];
    __shared__ float dotb[EPB][5];
    int nEB = (E + EPB - 1) / EPB;
    int lb = xcd_logical_block();
    if (lb >= nEB) return;
    int lane = threadIdx.x & 63;
    int w = __builtin_amdgcn_readfirstlane((int)(threadIdx.x >> 6));
    int e = lb * EPB + lane;
    bool ok = e < E;
    int eidx = ok ? e : 0;
    int r = row[eidx], c = col[eidx];
    int j0 = w * 16;

    // partial dot over K-chunk [32w, 32w+32)
    {
        const float* hi = AF + (size_t)r * HDIM + w * 32;
        const float* hj = AF + (size_t)c * HDIM + w * 32;
        float d = 0.f;
        #pragma unroll
        for (int k = 0; k < 32; k += 4) {
            float4 a4 = ld4(hi + k), b4 = ld4(hj + k);
            d += a4.x * b4.x + a4.y * b4.y + a4.z * b4.z + a4.w * b4.w;
        }
        dotb[lane][w] = d;
    }

    // layer-1 hidden slice: silu(pa[r] + qa[c] + b1)
    {
        const float* pr = pa + (size_t)r * DDIM + j0;
        const float* qc = qa + (size_t)c * DDIM + j0;
        #pragma unroll
        for (int q = 0; q < 4; ++q) {
            float4 pv = ld4(pr + q * 4);
            float4 qv = ld4(qc + q * 4);
            hbuf[lane][j0 + q * 4 + 0] = silu_f(pv.x + qv.x + b1[j0 + q * 4 + 0]);
            hbuf[lane][j0 + q * 4 + 1] = silu_f(pv.y + qv.y + b1[j0 + q * 4 + 1]);
            hbuf[lane][j0 + q * 4 + 2] = silu_f(pv.z + qv.z + b1[j0 + q * 4 + 2]);
            hbuf[lane][j0 + q * 4 + 3] = silu_f(pv.w + qv.w + b1[j0 + q * 4 + 3]);
        }
    }
    __syncthreads();

    if (w == 0) {
        float dot = dotb[lane][0] + dotb[lane][1] + dotb[lane][2] + dotb[lane][3];
        float nr = fmaxf(na[r], 1e-8f), nc = fmaxf(na[c], 1e-8f);
        float sim = dot / (nr * nc);
        int t = 0;
        if (sim > 0.8f) t = 1;
        if (sim > 0.9f) t = 2;
        if (sim < 0.3f) t = 3;
        if (ok) bt[e] = t;
    }

    // layer-2: x = h @ w2 + b2 (K=64 from LDS)
    float o[16];
    #pragma unroll
    for (int jj = 0; jj < 16; ++jj) o[jj] = b2[j0 + jj];
    #pragma unroll 4
    for (int k = 0; k < DDIM; ++k) {
        float hk = hbuf[lane][k];
        const float* wk = w2 + (size_t)k * DDIM + j0;
        #pragma unroll
        for (int jj = 0; jj < 16; ++jj) o[jj] = fmaf(hk, wk[jj], o[jj]);
    }
    if (ok) {
        float* xr = x + (size_t)e * DDIM + j0;
        st4(xr + 0,  make_float4(o[0],  o[1],  o[2],  o[3]));
        st4(xr + 4,  make_float4(o[4],  o[5],  o[6],  o[7]));
        st4(xr + 8,  make_float4(o[8],  o[9],  o[10], o[11]));
        st4(xr + 12, make_float4(o[12], o[13], o[14], o[15]));
    }
    __syncthreads();
    #pragma unroll
    for (int jj = 0; jj < 16; ++jj) hbuf[lane][j0 + jj] = o[jj];   // x row
    __syncthreads();

    // proj (layer 0): pd = x@W1[0:64], ps = x@W1[64:128]
    float apd[16], aps[16];
    #pragma unroll
    for (int jj = 0; jj < 16; ++jj) { apd[jj] = 0.f; aps[jj] = 0.f; }
    #pragma unroll 4
    for (int k = 0; k < DDIM; ++k) {
        float xk = hbuf[lane][k];
        const float* wd = w1p + (size_t)k * DDIM + j0;
        const float* wsv = w1p + (size_t)(DDIM + k) * DDIM + j0;
        #pragma unroll
        for (int jj = 0; jj < 16; ++jj) {
            apd[jj] = fmaf(xk, wd[jj], apd[jj]);
            aps[jj] = fmaf(xk, wsv[jj], aps[jj]);
        }
    }
    if (ok) {
        float* pr = pd + (size_t)e * DDIM + j0;
        float* qr = ps + (size_t)e * DDIM + j0;
        st4(pr + 0,  make_float4(apd[0],  apd[1],  apd[2],  apd[3]));
        st4(pr + 4,  make_float4(apd[4],  apd[5],  apd[6],  apd[7]));
        st4(pr + 8,  make_float4(apd[8],  apd[9],  apd[10], apd[11]));
        st4(pr + 12, make_float4(apd[12], apd[13], apd[14], apd[15]));
        st4(qr + 0,  make_float4(aps[0],  aps[1],  aps[2],  aps[3]));
        st4(qr + 4,  make_float4(aps[4],  aps[5],  aps[6],  aps[7]));
        st4(qr + 8,  make_float4(aps[8],  aps[9],  aps[10], aps[11]));
        st4(qr + 12, make_float4(aps[12], aps[13], aps[14], aps[15]));
    }
}

// proj for layer 1 (x from global)
__global__ void __launch_bounds__(256) proj_k(const float* __restrict__ x,
                                              const float* __restrict__ w1 /*[192][64]*/,
                                              float* __restrict__ pd, float* __restrict__ ps,
                                              int E) {
    int lane = threadIdx.x & 63;
    int w = __builtin_amdgcn_readfirstlane((int)(threadIdx.x >> 6));
    int e = blockIdx.x * EPB + lane;
    bool ok = e < E;
    int eidx = ok ? e : 0;
    int j0 = w * 16;
    const float* xr = x + (size_t)eidx * DDIM;

    float apd[16], aps[16];
    #pragma unroll
    for (int jj = 0; jj < 16; ++jj) { apd[jj] = 0.f; aps[jj] = 0.f; }
    #pragma unroll 2
    for (int c = 0; c < 16; ++c) {
        float4 v = ld4(xr + c * 4);
        float xv[4] = {v.x, v.y, v.z, v.w};
        #pragma unroll
        for (int kk = 0; kk < 4; ++kk) {
            int k = c * 4 + kk;
            const float* wd = w1 + (size_t)k * DDIM + j0;
            const float* wsv = w1 + (size_t)(DDIM + k) * DDIM + j0;
            #pragma unroll
            for (int jj = 0; jj < 16; ++jj) {
                apd[jj] = fmaf(xv[kk], wd[jj], apd[jj]);
                aps[jj] = fmaf(xv[kk], wsv[jj], aps[jj]);
            }
        }
    }
    if (ok) {
        float* pr = pd + (size_t)e * DDIM + j0;
        float* qr = ps + (size_t)e * DDIM + j0;
        st4(pr + 0,  make_float4(apd[0],  apd[1],  apd[2],  apd[3]));
        st4(pr + 4,  make_float4(apd[4],  apd[5],  apd[6],  apd[7]));
        st4(pr + 8,  make_float4(apd[8],  apd[9],  apd[10], apd[11]));
        st4(pr + 12, make_float4(apd[12], apd[13], apd[14], apd[15]));
        st4(qr + 0,  make_float4(aps[0],  aps[1],  aps[2],  aps[3]));
        st4(qr + 4,  make_float4(aps[4],  aps[5],  aps[6],  aps[7]));
        st4(qr + 8,  make_float4(aps[8],  aps[9],  aps[10], aps[11]));
        st4(qr + 12, make_float4(aps[12], aps[13], aps[14], aps[15]));
    }
}

// ---------------- fused gather + update (mm folded into W2u) ----------------
__global__ void __launch_bounds__(256) layer_k(
    float* __restrict__ x, const float* __restrict__ pd, const float* __restrict__ ps,
    const float* __restrict__ tt_l, const int* __restrict__ bt,
    const int* __restrict__ offs, const int* __restrict__ srclist,
    const int* __restrict__ cnt,
    const float* __restrict__ w2u, const float* __restrict__ b2u,
    const float* __restrict__ uw1 /*[128][64], rows 64..127 used*/,
    const float* __restrict__ ub1,
    const float* __restrict__ uw2 /*[64][64]*/, const float* __restrict__ ub2, int E) {
    __shared__ float sb[EPB][DDIM + 1];
    int nEB = (E + EPB - 1) / EPB;
    int lb = xcd_logical_block();
    if (lb >= nEB) return;
    int lane = threadIdx.x & 63;
    int w = __builtin_amdgcn_readfirstlane((int)(threadIdx.x >> 6));
    int e = lb * EPB + lane;
    bool ok = e < E;
    int eidx = ok ? e : 0;
    int j0 = w * 16;

    // ---- P1: gather (thread = (d_local, q)), 2-way unrolled ----
    {
        int d_local = threadIdx.x >> 2, q = threadIdx.x & 3;
        int d = lb * EPB + d_local;
        if (d < E) {
            int jq = q * 16;
            const float* pr = pd + (size_t)d * DDIM + jq;
            const float* tp = tt_l + (size_t)bt[d] * DDIM + jq;
            float4 b0 = add4(ld4(pr + 0),  ld4(tp + 0));
            float4 b1 = add4(ld4(pr + 4),  ld4(tp + 4));
            float4 b2 = add4(ld4(pr + 8),  ld4(tp + 8));
            float4 b3 = add4(ld4(pr + 12), ld4(tp + 12));
            float4 s0 = make_float4(0, 0, 0, 0), s1 = s0, s2 = s0, s3 = s0;
            int p0 = offs[d], p1 = offs[d + 1];
            int p = p0;
            for (; p + 2 <= p1; p += 2) {
                const float* sa = ps + (size_t)srclist[p] * DDIM + jq;
                const float* sc = ps + (size_t)srclist[p + 1] * DDIM + jq;
                float4 u0 = ld4(sa + 0), u1 = ld4(sa + 4);
                float4 u2 = ld4(sa + 8), u3 = ld4(sa + 12);
                float4 v0 = ld4(sc + 0), v1 = ld4(sc + 4);
                float4 v2 = ld4(sc + 8), v3 = ld4(sc + 12);
                silu_acc4(s0, add4(b0, u0));
                silu_acc4(s1, add4(b1, u1));
                silu_acc4(s2, add4(b2, u2));
                silu_acc4(s3, add4(b3, u3));
                silu_acc4(s0, add4(b0, v0));
                silu_acc4(s1, add4(b1, v1));
                silu_acc4(s2, add4(b2, v2));
                silu_acc4(s3, add4(b3, v3));
            }
            if (p < p1) {
                const float* sa = ps + (size_t)srclist[p] * DDIM + jq;
                float4 u0 = ld4(sa + 0), u1 = ld4(sa + 4);
                float4 u2 = ld4(sa + 8), u3 = ld4(sa + 12);
                silu_acc4(s0, add4(b0, u0));
                silu_acc4(s1, add4(b1, u1));
                silu_acc4(s2, add4(b2, u2));
                silu_acc4(s3, add4(b3, u3));
            }
            st4(&sb[d_local][jq + 0],  s0);
            st4(&sb[d_local][jq + 4],  s1);
            st4(&sb[d_local][jq + 8],  s2);
            st4(&sb[d_local][jq + 12], s3);
        }
    }
    __syncthreads();

    // ---- P3': h = silu(inv*(s@W2u) + inv*deg*b2u + x@Wu1[64:] + ub1) ----
    float degf = (float)cnt[eidx];
    float inv = 1.0f / fmaxf(degf, 1.0f);
    const float* xr = x + (size_t)eidx * DDIM;
    float h[16];
    {
        float sm[16];
        #pragma unroll
        for (int jj = 0; jj < 16; ++jj) sm[jj] = 0.f;
        #pragma unroll 4
        for (int k = 0; k < DDIM; ++k) {
            float sk = sb[lane][k];
            const float* wk = w2u + (size_t)k * DDIM + j0;
            #pragma unroll
            for (int jj = 0; jj < 16; ++jj) sm[jj] = fmaf(sk, wk[jj], sm[jj]);
        }
        float ah[16];
        float dib = degf * inv;
        #pragma unroll
        for (int jj = 0; jj < 16; ++jj)
            ah[jj] = fmaf(inv, sm[jj], fmaf(dib, b2u[j0 + jj], ub1[j0 + jj]));
        #pragma unroll 2
        for (int c = 0; c < 16; ++c) {
            float4 v = ld4(xr + c * 4);
            float xv[4] = {v.x, v.y, v.z, v.w};
            #pragma unroll
            for (int kk = 0; kk < 4; ++kk) {
                const float* wk = uw1 + (size_t)(DDIM + c * 4 + kk) * DDIM + j0;
                #pragma unroll
                for (int jj = 0; jj < 16; ++jj) ah[jj] = fmaf(xv[kk], wk[jj], ah[jj]);
            }
        }
        #pragma unroll
        for (int jj = 0; jj < 16; ++jj) h[jj] = silu_f(ah[jj]);
    }
    __syncthreads();     // all reads of sb (s) done
    #pragma unroll
    for (int jj = 0; jj < 16; ++jj) sb[lane][j0 + jj] = h[jj];
    __syncthreads();

    // ---- P4: u-layer2 + residual ----
    {
        float o[16];
        #pragma unroll
        for (int jj = 0; jj < 16; ++jj) o[jj] = ub2[j0 + jj];
        #pragma unroll 4
        for (int k = 0; k < DDIM; ++k) {
            float hk = sb[lane][k];
            const float* wk = uw2 + (size_t)k * DDIM + j0;
            #pragma unroll
            for (int jj = 0; jj < 16; ++jj) o[jj] = fmaf(hk, wk[jj], o[jj]);
        }
        if (ok) {
            float* xw = x + (size_t)e * DDIM + j0;
            #pragma unroll
            for (int q = 0; q < 4; ++q) {
                float4 xo = ld4(xw + q * 4);
                xo.x += o[q * 4 + 0];
                xo.y += o[q * 4 + 1];
                xo.z += o[q * 4 + 2];
                xo.w += o[q * 4 + 3];
                st4(xw + q * 4, xo);
            }
        }
    }
}

// ---------------- pooling ----------------
// Grid-saturating sum: block covers PCHUNK contiguous edges; thread =
// (wave -> edge offset, lane -> feature). Edges sorted by graph id, so each
// thread flushes its register sum via one atomic per graph transition.
__global__ void __launch_bounds__(256) pool_k(
    const float* __restrict__ x, const int* __restrict__ row,
    const int* __restrict__ batch, float* __restrict__ gfeat, int E) {
    int lane = threadIdx.x & 63;
    int esub = threadIdx.x >> 6;       // 0..3
    int e0 = blockIdx.x * PCHUNK;
    int e1 = min(e0 + PCHUNK, E);
    float sum = 0.f;
    int cur = -1;
    for (int e = e0 + esub; e < e1; e += 4) {
        int g = batch[row[e]];         // wave-uniform -> scalar load
        if (g != cur) {
            if (cur >= 0)
                __hip_atomic_fetch_add(&gfeat[cur * DDIM + lane], sum,
                                       __ATOMIC_RELAXED, __HIP_MEMORY_SCOPE_AGENT);
            cur = g;
            sum = 0.f;
        }
        sum += x[(size_t)e * DDIM + lane];
    }
    if (cur >= 0)
        __hip_atomic_fetch_add(&gfeat[cur * DDIM + lane], sum,
                               __ATOMIC_RELAXED, __HIP_MEMORY_SCOPE_AGENT);
}

static __device__ __forceinline__ int lower_bound_bb(const int* __restrict__ row,
                                                     const int* __restrict__ batch,
                                                     int E, int g) {
    int lo = 0, hi = E;
    while (lo < hi) {
        int m = (lo + hi) >> 1;
        if (batch[row[m]] < g) lo = m + 1; else hi = m;
    }
    return lo;
}

__global__ void __launch_bounds__(64) pool_final_k(
    const int* __restrict__ row, const int* __restrict__ batch,
    float* __restrict__ gfeat, int E) {
    int g = blockIdx.x, j = threadIdx.x;
    int s = lower_bound_bb(row, batch, E, g);
    int t = lower_bound_bb(row, batch, E, g + 1);
    float cnt = fmaxf((float)(t - s), 1.0f);
    gfeat[g * DDIM + j] /= cnt;
}

extern "C" void kernel_launch(void* const* d_in, const int* in_sizes, int n_in,
                              void* d_out, int out_size, void* d_ws, size_t ws_size,
                              hipStream_t stream) {
    (void)n_in; (void)out_size; (void)ws_size;
    const float* AF    = (const float*)d_in[0];
    const int*   batch = (const int*)d_in[3];
    const int*   edge_index      = (const int*)d_in[4];
    const int*   bond_edge_index = (const int*)d_in[5];
    const float* iw1 = (const float*)d_in[6];
    const float* ib1 = (const float*)d_in[7];
    const float* iw2 = (const float*)d_in[8];
    const float* ib2 = (const float*)d_in[9];
    const float* emb = (const float*)d_in[10];
    const float* mw1 = (const float*)d_in[11];
    const float* mb1 = (const float*)d_in[12];
    const float* mw2 = (const float*)d_in[13];
    const float* mb2 = (const float*)d_in[14];
    const float* uw1 = (const float*)d_in[15];
    const float* ub1 = (const float*)d_in[16];
    const float* uw2 = (const float*)d_in[17];
    const float* ub2 = (const float*)d_in[18];

    const int N  = in_sizes[0] / HDIM;
    const int E  = in_sizes[4] / 2;
    const int BE = in_sizes[5] / 2;
    const int NB = (E + 255) / 256;
    const int EB = (E + EPB - 1) / EPB;
    const int AB = (N + 4 * APW - 1) / (4 * APW);   // atom blocks (32 atoms/block)
    const int EBS = ((EB + 7) / 8) * 8;             // swizzled grid (multiple of 8)
    const int PB = (E + PCHUNK - 1) / PCHUNK;       // pooling blocks

    float* xout  = (float*)d_out;                 // [E,64]
    float* gfeat = xout + (size_t)E * DDIM;       // [16,64]

    // workspace layout
    char* w = (char*)d_ws;
    float* tt       = (float*)w;  w += sizeof(float) * 2 * NTYPES * DDIM;
    float* w2u      = (float*)w;  w += sizeof(float) * 2 * DDIM * DDIM;
    float* b2u      = (float*)w;  w += sizeof(float) * 2 * DDIM;
    int*   cnt      = (int*)w;    w += sizeof(int) * E;
    int*   offs     = (int*)w;    w += sizeof(int) * (E + 1);
    int*   cursor   = (int*)w;    w += sizeof(int) * E;
    int*   bt       = (int*)w;    w += sizeof(int) * E;
    int*   bsum     = (int*)w;    w += sizeof(int) * 1024;
    int*   bpre     = (int*)w;    w += sizeof(int) * 1024;
    int*   srclist  = (int*)w;    w += sizeof(int) * BE;
    w = (char*)(((uintptr_t)w + 15) & ~(uintptr_t)15);
    float* pd       = (float*)w;  w += sizeof(float) * (size_t)E * DDIM;
    float* ps       = (float*)w;  w += sizeof(float) * (size_t)E * DDIM;
    float* pa       = (float*)w;  w += sizeof(float) * (size_t)N * DDIM;
    float* qa       = (float*)w;  w += sizeof(float) * (size_t)N * DDIM;
    float* na       = (float*)w;  w += sizeof(float) * (size_t)N;

    const int* row  = edge_index;
    const int* col  = edge_index + E;
    const int* bsrc = bond_edge_index;
    const int* bdst = bond_edge_index + BE;

    // CSR build
    hipMemsetAsync(cnt, 0, (size_t)E * sizeof(int), stream);
    count_k<<<(BE + 255) / 256, 256, 0, stream>>>(bdst, cnt, BE);
    bsum_k<<<NB, 256, 0, stream>>>(cnt, bsum, E);
    bscan_k<<<1, 1024, 0, stream>>>(bsum, bpre, NB);
    offs_k<<<NB, 256, 0, stream>>>(cnt, bpre, offs, cursor, E);
    scatter_k<<<(BE + 255) / 256, 256, 0, stream>>>(bsrc, bdst, cursor, srclist, BE);

    // constants: bond-type embeddings + fused mm weights
    tt2_k<<<2 * NTYPES, 64, 0, stream>>>(emb, mw1, mb1, tt);
    fuse_k<<<2 * 64, 64, 0, stream>>>(mw2, mb2, uw1, w2u, b2u);

    // atom projections, then bond init + layer-0 proj
    atom_proj_k<<<AB, 256, 0, stream>>>(AF, iw1, pa, qa, na, N);
    bond_init2_k<<<EBS, 256, 0, stream>>>(AF, row, col, pa, qa, na, ib1, iw2, ib2,
                                          mw1 /* layer 0 */, xout, bt, pd, ps, E);

    for (int l = 0; l < 2; ++l) {
        if (l > 0)
            proj_k<<<EB, 256, 0, stream>>>(xout, mw1 + (size_t)l * 192 * 64, pd, ps, E);
        layer_k<<<EBS, 256, 0, stream>>>(
            xout, pd, ps, tt + (size_t)l * NTYPES * DDIM, bt, offs, srclist, cnt,
            w2u + (size_t)l * DDIM * DDIM, b2u + (size_t)l * DDIM,
            uw1 + (size_t)l * 128 * 64, ub1 + (size_t)l * DDIM,
            uw2 + (size_t)l * DDIM * DDIM, ub2 + (size_t)l * DDIM, E);
    }

    hipMemsetAsync(gfeat, 0, NGRAPHS * DDIM * sizeof(float), stream);
    pool_k<<<PB, 256, 0, stream>>>(xout, row, batch, gfeat, E);
    pool_final_k<<<NGRAPHS, 64, 0, stream>>>(row, batch, gfeat, E);
}

// Round 10
// 401.264 us; speedup vs baseline: 1.2545x; 1.0400x over previous
//
#include <hip/hip_runtime.h>
#include <cstdint>
#include <cstddef>

#define HDIM 128
#define DDIM 64
#define NTYPES 5
#define NGRAPHS 16
#define PCHUNK 128   // edges per pooling block
#define EPB 64       // edges per block (one per lane)
#define APW 8        // atoms per wave in atom_proj

static __device__ __forceinline__ float silu_f(float v) {
    return v / (1.0f + __expf(-v));
}

static __device__ __forceinline__ float4 ld4(const float* p) {
    return *reinterpret_cast<const float4*>(p);
}

static __device__ __forceinline__ void st4(float* p, float4 v) {
    *reinterpret_cast<float4*>(p) = v;
}

static __device__ __forceinline__ float4 add4(float4 a, float4 b) {
    return make_float4(a.x + b.x, a.y + b.y, a.z + b.z, a.w + b.w);
}

static __device__ __forceinline__ void silu_acc4(float4& s, float4 v) {
    s.x += silu_f(v.x);
    s.y += silu_f(v.y);
    s.z += silu_f(v.z);
    s.w += silu_f(v.w);
}

// XCD-affinity swizzle (heuristic blk%8 -> XCD round-robin; validated r7:
// layer_k FETCH 82 -> 25.7 MB).
static __device__ __forceinline__ int xcd_logical_block() {
    int chunk = (int)(gridDim.x >> 3);
    return (int)(blockIdx.x & 7) * chunk + (int)(blockIdx.x >> 3);
}

// ---------------- CSR build ----------------
__global__ void __launch_bounds__(256) count_k(const int* __restrict__ bdst,
                                               int* __restrict__ cnt, int BE) {
    int i = blockIdx.x * 256 + threadIdx.x;
    if (i < BE)
        __hip_atomic_fetch_add(&cnt[bdst[i]], 1, __ATOMIC_RELAXED, __HIP_MEMORY_SCOPE_AGENT);
}

__global__ void __launch_bounds__(256) bsum_k(const int* __restrict__ cnt,
                                              int* __restrict__ bsum, int E) {
    __shared__ int red[256];
    int t = threadIdx.x;
    int i = blockIdx.x * 256 + t;
    red[t] = (i < E) ? cnt[i] : 0;
    __syncthreads();
    #pragma unroll
    for (int off = 128; off > 0; off >>= 1) {
        if (t < off) red[t] += red[t + off];
        __syncthreads();
    }
    if (t == 0) bsum[blockIdx.x] = red[0];
}

__global__ void __launch_bounds__(1024) bscan_k(const int* __restrict__ bsum,
                                                int* __restrict__ bpre, int NB) {
    __shared__ int sh[1024];
    int t = threadIdx.x;
    int v0 = (t < NB) ? bsum[t] : 0;
    sh[t] = v0;
    __syncthreads();
    for (int off = 1; off < 1024; off <<= 1) {
        int v = (t >= off) ? sh[t - off] : 0;
        __syncthreads();
        sh[t] += v;
        __syncthreads();
    }
    if (t < NB) bpre[t] = sh[t] - v0;
}

__global__ void __launch_bounds__(256) offs_k(const int* __restrict__ cnt,
                                              const int* __restrict__ bpre,
                                              int* __restrict__ offs,
                                              int* __restrict__ cursor, int E) {
    __shared__ int sh[256];
    int t = threadIdx.x;
    int i = blockIdx.x * 256 + t;
    int v0 = (i < E) ? cnt[i] : 0;
    sh[t] = v0;
    __syncthreads();
    for (int off = 1; off < 256; off <<= 1) {
        int v = (t >= off) ? sh[t - off] : 0;
        __syncthreads();
        sh[t] += v;
        __syncthreads();
    }
    int ex = sh[t] - v0 + bpre[blockIdx.x];
    if (i < E) { offs[i] = ex; cursor[i] = ex; }
    if (i == E - 1) offs[E] = ex + v0;
}

__global__ void __launch_bounds__(256) scatter_k(const int* __restrict__ bsrc,
                                                 const int* __restrict__ bdst,
                                                 int* __restrict__ cursor,
                                                 int* __restrict__ srclist, int BE) {
    int i = blockIdx.x * 256 + threadIdx.x;
    if (i < BE) {
        int d = bdst[i];
        int p = __hip_atomic_fetch_add(&cursor[d], 1, __ATOMIC_RELAXED,
                                       __HIP_MEMORY_SCOPE_AGENT);
        srclist[p] = bsrc[i];
    }
}

// tt for BOTH layers
__global__ void __launch_bounds__(64) tt2_k(const float* __restrict__ emb,
                                            const float* __restrict__ mw1,
                                            const float* __restrict__ mb1,
                                            float* __restrict__ tt) {
    int b = blockIdx.x;
    int l = b / NTYPES, t = b % NTYPES, j = threadIdx.x;
    const float* embl = emb + (size_t)l * NTYPES * DDIM + (size_t)t * DDIM;
    const float* w1 = mw1 + (size_t)l * 192 * DDIM;
    float s = mb1[l * DDIM + j];
    #pragma unroll 8
    for (int k = 0; k < DDIM; ++k)
        s = fmaf(embl[k], w1[(HDIM + k) * DDIM + j], s);
    tt[(size_t)b * DDIM + j] = s;
}

// Fused weights: W2u[l] = mw2[l] @ uw1[l][0:64]; b2u[l] = mb2[l] @ uw1[l][0:64].
__global__ void __launch_bounds__(64) fuse_k(const float* __restrict__ mw2,
                                             const float* __restrict__ mb2,
                                             const float* __restrict__ uw1,
                                             float* __restrict__ w2u,
                                             float* __restrict__ b2u) {
    int l = blockIdx.x >> 6, k = blockIdx.x & 63, j = threadIdx.x;
    const float* w2 = mw2 + (size_t)l * DDIM * DDIM;
    const float* u1 = uw1 + (size_t)l * 128 * DDIM;   // rows 0..63 = mm part
    float s = 0.f;
    #pragma unroll 8
    for (int t = 0; t < DDIM; ++t)
        s = fmaf(w2[k * DDIM + t], u1[(size_t)t * DDIM + j], s);
    w2u[(size_t)l * DDIM * DDIM + (size_t)k * DDIM + j] = s;
    if (k == 0) {
        float b = 0.f;
        #pragma unroll 8
        for (int t = 0; t < DDIM; ++t)
            b = fmaf(mb2[l * DDIM + t], u1[(size_t)t * DDIM + j], b);
        b2u[l * DDIM + j] = b;
    }
}

// ---------------- atom-side projection: wave-per-8-atoms, lane = feature ----------------
__global__ void __launch_bounds__(256) atom_proj_k(
    const float* __restrict__ AF, const float* __restrict__ iw1,
    float* __restrict__ pa, float* __restrict__ qa, float* __restrict__ na, int N) {
    int lane = threadIdx.x & 63;
    int w = __builtin_amdgcn_readfirstlane((int)(threadIdx.x >> 6));
    int abase = blockIdx.x * (4 * APW) + w * APW;
    if (abase >= N) return;

    float accp[APW], accq[APW], nrm[APW];
    #pragma unroll
    for (int a = 0; a < APW; ++a) { accp[a] = 0.f; accq[a] = 0.f; nrm[a] = 0.f; }

    #pragma unroll 4
    for (int k = 0; k < HDIM; k += 4) {
        float wt[4], wb[4];
        #pragma unroll
        for (int kk = 0; kk < 4; ++kk) {
            wt[kk] = iw1[(size_t)(k + kk) * DDIM + lane];
            wb[kk] = iw1[(size_t)(HDIM + k + kk) * DDIM + lane];
        }
        #pragma unroll
        for (int a = 0; a < APW; ++a) {
            int aa = min(abase + a, N - 1);           // wave-uniform
            float4 hv = ld4(AF + (size_t)aa * HDIM + k);
            accp[a] = fmaf(hv.x, wt[0], accp[a]);
            accp[a] = fmaf(hv.y, wt[1], accp[a]);
            accp[a] = fmaf(hv.z, wt[2], accp[a]);
            accp[a] = fmaf(hv.w, wt[3], accp[a]);
            accq[a] = fmaf(hv.x, wb[0], accq[a]);
            accq[a] = fmaf(hv.y, wb[1], accq[a]);
            accq[a] = fmaf(hv.z, wb[2], accq[a]);
            accq[a] = fmaf(hv.w, wb[3], accq[a]);
            nrm[a] = fmaf(hv.x, hv.x, nrm[a]);
            nrm[a] = fmaf(hv.y, hv.y, nrm[a]);
            nrm[a] = fmaf(hv.z, hv.z, nrm[a]);
            nrm[a] = fmaf(hv.w, hv.w, nrm[a]);
        }
    }
    #pragma unroll
    for (int a = 0; a < APW; ++a) {
        int atom = abase + a;
        if (atom < N) {
            pa[(size_t)atom * DDIM + lane] = accp[a];
            qa[(size_t)atom * DDIM + lane] = accq[a];
            if (lane == 0) na[atom] = sqrtf(nrm[a]);
        }
    }
}

// ---------------- bond init (from atom projections) + layer-0 proj ----------------
__global__ void __launch_bounds__(256) bond_init2_k(
    const float* __restrict__ AF, const int* __restrict__ row, const int* __restrict__ col,
    const float* __restrict__ pa, const float* __restrict__ qa, const float* __restrict__ na,
    const float* __restrict__ b1, const float* __restrict__ w2, const float* __restrict__ b2,
    const float* __restrict__ w1p /*[192][64] layer0 mw1*/,
    float* __restrict__ x, int* __restrict__ bt,
    float* __restrict__ pd, float* __restrict__ ps, int E) {
    __shared__ float hbuf[EPB][DDIM + 1];
    __shared__ float dotb[EPB][5];
    int nEB = (E + EPB - 1) / EPB;
    int lb = xcd_logical_block();
    if (lb >= nEB) return;
    int lane = threadIdx.x & 63;
    int w = __builtin_amdgcn_readfirstlane((int)(threadIdx.x >> 6));
    int e = lb * EPB + lane;
    bool ok = e < E;
    int eidx = ok ? e : 0;
    int r = row[eidx], c = col[eidx];
    int j0 = w * 16;

    // partial dot over K-chunk [32w, 32w+32)
    {
        const float* hi = AF + (size_t)r * HDIM + w * 32;
        const float* hj = AF + (size_t)c * HDIM + w * 32;
        float d = 0.f;
        #pragma unroll
        for (int k = 0; k < 32; k += 4) {
            float4 a4 = ld4(hi + k), b4 = ld4(hj + k);
            d += a4.x * b4.x + a4.y * b4.y + a4.z * b4.z + a4.w * b4.w;
        }
        dotb[lane][w] = d;
    }

    // layer-1 hidden slice: silu(pa[r] + qa[c] + b1)
    {
        const float* pr = pa + (size_t)r * DDIM + j0;
        const float* qc = qa + (size_t)c * DDIM + j0;
        #pragma unroll
        for (int q = 0; q < 4; ++q) {
            float4 pv = ld4(pr + q * 4);
            float4 qv = ld4(qc + q * 4);
            hbuf[lane][j0 + q * 4 + 0] = silu_f(pv.x + qv.x + b1[j0 + q * 4 + 0]);
            hbuf[lane][j0 + q * 4 + 1] = silu_f(pv.y + qv.y + b1[j0 + q * 4 + 1]);
            hbuf[lane][j0 + q * 4 + 2] = silu_f(pv.z + qv.z + b1[j0 + q * 4 + 2]);
            hbuf[lane][j0 + q * 4 + 3] = silu_f(pv.w + qv.w + b1[j0 + q * 4 + 3]);
        }
    }
    __syncthreads();

    if (w == 0) {
        float dot = dotb[lane][0] + dotb[lane][1] + dotb[lane][2] + dotb[lane][3];
        float nr = fmaxf(na[r], 1e-8f), nc = fmaxf(na[c], 1e-8f);
        float sim = dot / (nr * nc);
        int t = 0;
        if (sim > 0.8f) t = 1;
        if (sim > 0.9f) t = 2;
        if (sim < 0.3f) t = 3;
        if (ok) bt[e] = t;
    }

    // layer-2: x = h @ w2 + b2 (K=64 from LDS)
    float o[16];
    #pragma unroll
    for (int jj = 0; jj < 16; ++jj) o[jj] = b2[j0 + jj];
    #pragma unroll 4
    for (int k = 0; k < DDIM; ++k) {
        float hk = hbuf[lane][k];
        const float* wk = w2 + (size_t)k * DDIM + j0;
        #pragma unroll
        for (int jj = 0; jj < 16; ++jj) o[jj] = fmaf(hk, wk[jj], o[jj]);
    }
    if (ok) {
        float* xr = x + (size_t)e * DDIM + j0;
        st4(xr + 0,  make_float4(o[0],  o[1],  o[2],  o[3]));
        st4(xr + 4,  make_float4(o[4],  o[5],  o[6],  o[7]));
        st4(xr + 8,  make_float4(o[8],  o[9],  o[10], o[11]));
        st4(xr + 12, make_float4(o[12], o[13], o[14], o[15]));
    }
    __syncthreads();
    #pragma unroll
    for (int jj = 0; jj < 16; ++jj) hbuf[lane][j0 + jj] = o[jj];   // x row
    __syncthreads();

    // proj (layer 0): pd = x@W1[0:64], ps = x@W1[64:128]
    float apd[16], aps[16];
    #pragma unroll
    for (int jj = 0; jj < 16; ++jj) { apd[jj] = 0.f; aps[jj] = 0.f; }
    #pragma unroll 4
    for (int k = 0; k < DDIM; ++k) {
        float xk = hbuf[lane][k];
        const float* wd = w1p + (size_t)k * DDIM + j0;
        const float* wsv = w1p + (size_t)(DDIM + k) * DDIM + j0;
        #pragma unroll
        for (int jj = 0; jj < 16; ++jj) {
            apd[jj] = fmaf(xk, wd[jj], apd[jj]);
            aps[jj] = fmaf(xk, wsv[jj], aps[jj]);
        }
    }
    if (ok) {
        float* pr = pd + (size_t)e * DDIM + j0;
        float* qr = ps + (size_t)e * DDIM + j0;
        st4(pr + 0,  make_float4(apd[0],  apd[1],  apd[2],  apd[3]));
        st4(pr + 4,  make_float4(apd[4],  apd[5],  apd[6],  apd[7]));
        st4(pr + 8,  make_float4(apd[8],  apd[9],  apd[10], apd[11]));
        st4(pr + 12, make_float4(apd[12], apd[13], apd[14], apd[15]));
        st4(qr + 0,  make_float4(aps[0],  aps[1],  aps[2],  aps[3]));
        st4(qr + 4,  make_float4(aps[4],  aps[5],  aps[6],  aps[7]));
        st4(qr + 8,  make_float4(aps[8],  aps[9],  aps[10], aps[11]));
        st4(qr + 12, make_float4(aps[12], aps[13], aps[14], aps[15]));
    }
}

// proj (x from global) — fallback path only (used if ws too small for pd2/ps2)
__global__ void __launch_bounds__(256) proj_k(const float* __restrict__ x,
                                              const float* __restrict__ w1 /*[192][64]*/,
                                              float* __restrict__ pd, float* __restrict__ ps,
                                              int E) {
    int lane = threadIdx.x & 63;
    int w = __builtin_amdgcn_readfirstlane((int)(threadIdx.x >> 6));
    int e = blockIdx.x * EPB + lane;
    bool ok = e < E;
    int eidx = ok ? e : 0;
    int j0 = w * 16;
    const float* xr = x + (size_t)eidx * DDIM;

    float apd[16], aps[16];
    #pragma unroll
    for (int jj = 0; jj < 16; ++jj) { apd[jj] = 0.f; aps[jj] = 0.f; }
    #pragma unroll 2
    for (int c = 0; c < 16; ++c) {
        float4 v = ld4(xr + c * 4);
        float xv[4] = {v.x, v.y, v.z, v.w};
        #pragma unroll
        for (int kk = 0; kk < 4; ++kk) {
            int k = c * 4 + kk;
            const float* wd = w1 + (size_t)k * DDIM + j0;
            const float* wsv = w1 + (size_t)(DDIM + k) * DDIM + j0;
            #pragma unroll
            for (int jj = 0; jj < 16; ++jj) {
                apd[jj] = fmaf(xv[kk], wd[jj], apd[jj]);
                aps[jj] = fmaf(xv[kk], wsv[jj], aps[jj]);
            }
        }
    }
    if (ok) {
        float* pr = pd + (size_t)e * DDIM + j0;
        float* qr = ps + (size_t)e * DDIM + j0;
        st4(pr + 0,  make_float4(apd[0],  apd[1],  apd[2],  apd[3]));
        st4(pr + 4,  make_float4(apd[4],  apd[5],  apd[6],  apd[7]));
        st4(pr + 8,  make_float4(apd[8],  apd[9],  apd[10], apd[11]));
        st4(pr + 12, make_float4(apd[12], apd[13], apd[14], apd[15]));
        st4(qr + 0,  make_float4(aps[0],  aps[1],  aps[2],  aps[3]));
        st4(qr + 4,  make_float4(aps[4],  aps[5],  aps[6],  aps[7]));
        st4(qr + 8,  make_float4(aps[8],  aps[9],  aps[10], aps[11]));
        st4(qr + 12, make_float4(aps[12], aps[13], aps[14], aps[15]));
    }
}

// ---------------- fused gather + update (+ optional next-layer proj) ----------------
// 512 threads = 8 waves. P1: 8 thr/bond gather s -> sb. P3': h = silu(...) (8-feature
// wave slices). P4: x += h@Wu2 + ub2. P5 (if w1n): pdn/psn = x_new @ w1n from LDS.
__global__ void __launch_bounds__(512) layer_k(
    float* __restrict__ x, const float* __restrict__ pd, const float* __restrict__ ps,
    const float* __restrict__ tt_l, const int* __restrict__ bt,
    const int* __restrict__ offs, const int* __restrict__ srclist,
    const int* __restrict__ cnt,
    const float* __restrict__ w2u, const float* __restrict__ b2u,
    const float* __restrict__ uw1 /*[128][64], rows 64..127 used*/,
    const float* __restrict__ ub1,
    const float* __restrict__ uw2 /*[64][64]*/, const float* __restrict__ ub2,
    const float* __restrict__ w1n /* next-layer mw1 or nullptr */,
    float* __restrict__ pdn, float* __restrict__ psn, int E) {
    __shared__ float sb[EPB][DDIM + 1];
    int nEB = (E + EPB - 1) / EPB;
    int lb = xcd_logical_block();
    if (lb >= nEB) return;
    int tid = threadIdx.x;
    int lane = tid & 63;
    int w = __builtin_amdgcn_readfirstlane((int)(tid >> 6));   // 0..7
    int e = lb * EPB + lane;
    bool ok = e < E;
    int eidx = ok ? e : 0;
    int j0 = w * 8;

    // ---- P1: gather (8 threads per bond, 8 features each), 2-way unrolled ----
    {
        int d_local = tid >> 3, q = tid & 7;
        int d = lb * EPB + d_local;
        if (d < E) {
            int jq = q * 8;
            const float* pr = pd + (size_t)d * DDIM + jq;
            const float* tp = tt_l + (size_t)bt[d] * DDIM + jq;
            float4 b0 = add4(ld4(pr + 0), ld4(tp + 0));
            float4 b1 = add4(ld4(pr + 4), ld4(tp + 4));
            float4 s0 = make_float4(0, 0, 0, 0), s1 = s0;
            int p0 = offs[d], p1 = offs[d + 1];
            int p = p0;
            for (; p + 2 <= p1; p += 2) {
                const float* sa = ps + (size_t)srclist[p] * DDIM + jq;
                const float* sc = ps + (size_t)srclist[p + 1] * DDIM + jq;
                float4 u0 = ld4(sa + 0), u1 = ld4(sa + 4);
                float4 v0 = ld4(sc + 0), v1 = ld4(sc + 4);
                silu_acc4(s0, add4(b0, u0));
                silu_acc4(s1, add4(b1, u1));
                silu_acc4(s0, add4(b0, v0));
                silu_acc4(s1, add4(b1, v1));
            }
            if (p < p1) {
                const float* sa = ps + (size_t)srclist[p] * DDIM + jq;
                float4 u0 = ld4(sa + 0), u1 = ld4(sa + 4);
                silu_acc4(s0, add4(b0, u0));
                silu_acc4(s1, add4(b1, u1));
            }
            st4(&sb[d_local][jq + 0], s0);
            st4(&sb[d_local][jq + 4], s1);
        }
    }
    __syncthreads();

    // ---- P3': h = silu(inv*(s@W2u) + inv*deg*b2u + x@Wu1[64:] + ub1) ----
    float degf = (float)cnt[eidx];
    float inv = 1.0f / fmaxf(degf, 1.0f);
    const float* xr = x + (size_t)eidx * DDIM;
    float h[8];
    {
        float sm[8];
        #pragma unroll
        for (int jj = 0; jj < 8; ++jj) sm[jj] = 0.f;
        #pragma unroll 4
        for (int k = 0; k < DDIM; ++k) {
            float sk = sb[lane][k];
            const float* wk = w2u + (size_t)k * DDIM + j0;
            #pragma unroll
            for (int jj = 0; jj < 8; ++jj) sm[jj] = fmaf(sk, wk[jj], sm[jj]);
        }
        float ah[8];
        float dib = degf * inv;
        #pragma unroll
        for (int jj = 0; jj < 8; ++jj)
            ah[jj] = fmaf(inv, sm[jj], fmaf(dib, b2u[j0 + jj], ub1[j0 + jj]));
        #pragma unroll 2
        for (int c = 0; c < 16; ++c) {
            float4 v = ld4(xr + c * 4);
            float xv[4] = {v.x, v.y, v.z, v.w};
            #pragma unroll
            for (int kk = 0; kk < 4; ++kk) {
                const float* wk = uw1 + (size_t)(DDIM + c * 4 + kk) * DDIM + j0;
                #pragma unroll
                for (int jj = 0; jj < 8; ++jj) ah[jj] = fmaf(xv[kk], wk[jj], ah[jj]);
            }
        }
        #pragma unroll
        for (int jj = 0; jj < 8; ++jj) h[jj] = silu_f(ah[jj]);
    }
    __syncthreads();     // all reads of sb (s) done
    #pragma unroll
    for (int jj = 0; jj < 8; ++jj) sb[lane][j0 + jj] = h[jj];
    __syncthreads();

    // ---- P4: u-layer2 + residual ----
    float xn[8];
    {
        float o[8];
        #pragma unroll
        for (int jj = 0; jj < 8; ++jj) o[jj] = ub2[j0 + jj];
        #pragma unroll 4
        for (int k = 0; k < DDIM; ++k) {
            float hk = sb[lane][k];
            const float* wk = uw2 + (size_t)k * DDIM + j0;
            #pragma unroll
            for (int jj = 0; jj < 8; ++jj) o[jj] = fmaf(hk, wk[jj], o[jj]);
        }
        float4 x0 = ld4(xr + j0), x1 = ld4(xr + j0 + 4);
        xn[0] = x0.x + o[0]; xn[1] = x0.y + o[1];
        xn[2] = x0.z + o[2]; xn[3] = x0.w + o[3];
        xn[4] = x1.x + o[4]; xn[5] = x1.y + o[5];
        xn[6] = x1.z + o[6]; xn[7] = x1.w + o[7];
        if (ok) {
            float* xw = x + (size_t)e * DDIM + j0;
            st4(xw + 0, make_float4(xn[0], xn[1], xn[2], xn[3]));
            st4(xw + 4, make_float4(xn[4], xn[5], xn[6], xn[7]));
        }
    }

    // ---- P5 (optional): next-layer proj from x_new in LDS ----
    if (w1n != nullptr) {
        __syncthreads();     // all reads of sb (h) done
        #pragma unroll
        for (int jj = 0; jj < 8; ++jj) sb[lane][j0 + jj] = xn[jj];
        __syncthreads();
        float apd[8], aps[8];
        #pragma unroll
        for (int jj = 0; jj < 8; ++jj) { apd[jj] = 0.f; aps[jj] = 0.f; }
        #pragma unroll 4
        for (int k = 0; k < DDIM; ++k) {
            float xk = sb[lane][k];
            const float* wd = w1n + (size_t)k * DDIM + j0;
            const float* wsv = w1n + (size_t)(DDIM + k) * DDIM + j0;
            #pragma unroll
            for (int jj = 0; jj < 8; ++jj) {
                apd[jj] = fmaf(xk, wd[jj], apd[jj]);
                aps[jj] = fmaf(xk, wsv[jj], aps[jj]);
            }
        }
        if (ok) {
            float* pr = pdn + (size_t)e * DDIM + j0;
            float* qr = psn + (size_t)e * DDIM + j0;
            st4(pr + 0, make_float4(apd[0], apd[1], apd[2], apd[3]));
            st4(pr + 4, make_float4(apd[4], apd[5], apd[6], apd[7]));
            st4(qr + 0, make_float4(aps[0], aps[1], aps[2], aps[3]));
            st4(qr + 4, make_float4(aps[4], aps[5], aps[6], aps[7]));
        }
    }
}

// ---------------- pooling ----------------
__global__ void __launch_bounds__(256) pool_k(
    const float* __restrict__ x, const int* __restrict__ row,
    const int* __restrict__ batch, float* __restrict__ gfeat, int E) {
    int lane = threadIdx.x & 63;
    int esub = threadIdx.x >> 6;       // 0..3
    int e0 = blockIdx.x * PCHUNK;
    int e1 = min(e0 + PCHUNK, E);
    float sum = 0.f;
    int cur = -1;
    for (int e = e0 + esub; e < e1; e += 4) {
        int g = batch[row[e]];         // wave-uniform -> scalar load
        if (g != cur) {
            if (cur >= 0)
                __hip_atomic_fetch_add(&gfeat[cur * DDIM + lane], sum,
                                       __ATOMIC_RELAXED, __HIP_MEMORY_SCOPE_AGENT);
            cur = g;
            sum = 0.f;
        }
        sum += x[(size_t)e * DDIM + lane];
    }
    if (cur >= 0)
        __hip_atomic_fetch_add(&gfeat[cur * DDIM + lane], sum,
                               __ATOMIC_RELAXED, __HIP_MEMORY_SCOPE_AGENT);
}

static __device__ __forceinline__ int lower_bound_bb(const int* __restrict__ row,
                                                     const int* __restrict__ batch,
                                                     int E, int g) {
    int lo = 0, hi = E;
    while (lo < hi) {
        int m = (lo + hi) >> 1;
        if (batch[row[m]] < g) lo = m + 1; else hi = m;
    }
    return lo;
}

__global__ void __launch_bounds__(64) pool_final_k(
    const int* __restrict__ row, const int* __restrict__ batch,
    float* __restrict__ gfeat, int E) {
    int g = blockIdx.x, j = threadIdx.x;
    int s = lower_bound_bb(row, batch, E, g);
    int t = lower_bound_bb(row, batch, E, g + 1);
    float cnt = fmaxf((float)(t - s), 1.0f);
    gfeat[g * DDIM + j] /= cnt;
}

extern "C" void kernel_launch(void* const* d_in, const int* in_sizes, int n_in,
                              void* d_out, int out_size, void* d_ws, size_t ws_size,
                              hipStream_t stream) {
    (void)n_in; (void)out_size;
    const float* AF    = (const float*)d_in[0];
    const int*   batch = (const int*)d_in[3];
    const int*   edge_index      = (const int*)d_in[4];
    const int*   bond_edge_index = (const int*)d_in[5];
    const float* iw1 = (const float*)d_in[6];
    const float* ib1 = (const float*)d_in[7];
    const float* iw2 = (const float*)d_in[8];
    const float* ib2 = (const float*)d_in[9];
    const float* emb = (const float*)d_in[10];
    const float* mw1 = (const float*)d_in[11];
    const float* mb1 = (const float*)d_in[12];
    const float* mw2 = (const float*)d_in[13];
    const float* mb2 = (const float*)d_in[14];
    const float* uw1 = (const float*)d_in[15];
    const float* ub1 = (const float*)d_in[16];
    const float* uw2 = (const float*)d_in[17];
    const float* ub2 = (const float*)d_in[18];

    const int N  = in_sizes[0] / HDIM;
    const int E  = in_sizes[4] / 2;
    const int BE = in_sizes[5] / 2;
    const int NB = (E + 255) / 256;
    const int EB = (E + EPB - 1) / EPB;
    const int AB = (N + 4 * APW - 1) / (4 * APW);   // atom blocks (32 atoms/block)
    const int EBS = ((EB + 7) / 8) * 8;             // swizzled grid (multiple of 8)
    const int PB = (E + PCHUNK - 1) / PCHUNK;       // pooling blocks

    float* xout  = (float*)d_out;                 // [E,64]
    float* gfeat = xout + (size_t)E * DDIM;       // [16,64]

    // workspace layout
    char* w = (char*)d_ws;
    float* tt       = (float*)w;  w += sizeof(float) * 2 * NTYPES * DDIM;
    float* w2u      = (float*)w;  w += sizeof(float) * 2 * DDIM * DDIM;
    float* b2u      = (float*)w;  w += sizeof(float) * 2 * DDIM;
    int*   cnt      = (int*)w;    w += sizeof(int) * E;
    int*   offs     = (int*)w;    w += sizeof(int) * (E + 1);
    int*   cursor   = (int*)w;    w += sizeof(int) * E;
    int*   bt       = (int*)w;    w += sizeof(int) * E;
    int*   bsum     = (int*)w;    w += sizeof(int) * 1024;
    int*   bpre     = (int*)w;    w += sizeof(int) * 1024;
    int*   srclist  = (int*)w;    w += sizeof(int) * BE;
    w = (char*)(((uintptr_t)w + 15) & ~(uintptr_t)15);
    float* pd       = (float*)w;  w += sizeof(float) * (size_t)E * DDIM;
    float* ps       = (float*)w;  w += sizeof(float) * (size_t)E * DDIM;
    float* pa       = (float*)w;  w += sizeof(float) * (size_t)N * DDIM;
    float* qa       = (float*)w;  w += sizeof(float) * (size_t)N * DDIM;
    float* na       = (float*)w;  w += sizeof(float) * (size_t)N;
    // optional second proj buffers (fused-proj path)
    float* pd2      = (float*)w;  w += sizeof(float) * (size_t)E * DDIM;
    float* ps2      = (float*)w;  w += sizeof(float) * (size_t)E * DDIM;
    bool fuse_proj = ((size_t)(w - (char*)d_ws) <= ws_size);

    const int* row  = edge_index;
    const int* col  = edge_index + E;
    const int* bsrc = bond_edge_index;
    const int* bdst = bond_edge_index + BE;

    // CSR build
    hipMemsetAsync(cnt, 0, (size_t)E * sizeof(int), stream);
    count_k<<<(BE + 255) / 256, 256, 0, stream>>>(bdst, cnt, BE);
    bsum_k<<<NB, 256, 0, stream>>>(cnt, bsum, E);
    bscan_k<<<1, 1024, 0, stream>>>(bsum, bpre, NB);
    offs_k<<<NB, 256, 0, stream>>>(cnt, bpre, offs, cursor, E);
    scatter_k<<<(BE + 255) / 256, 256, 0, stream>>>(bsrc, bdst, cursor, srclist, BE);

    // constants: bond-type embeddings + fused mm weights
    tt2_k<<<2 * NTYPES, 64, 0, stream>>>(emb, mw1, mb1, tt);
    fuse_k<<<2 * 64, 64, 0, stream>>>(mw2, mb2, uw1, w2u, b2u);

    // atom projections, then bond init + layer-0 proj
    atom_proj_k<<<AB, 256, 0, stream>>>(AF, iw1, pa, qa, na, N);
    bond_init2_k<<<EBS, 256, 0, stream>>>(AF, row, col, pa, qa, na, ib1, iw2, ib2,
                                          mw1 /* layer 0 */, xout, bt, pd, ps, E);

    if (fuse_proj) {
        // layer 0: fused next-layer proj -> pd2/ps2
        layer_k<<<EBS, 512, 0, stream>>>(
            xout, pd, ps, tt, bt, offs, srclist, cnt,
            w2u, b2u, uw1, ub1, uw2, ub2,
            mw1 + (size_t)192 * 64, pd2, ps2, E);
        // layer 1: no proj
        layer_k<<<EBS, 512, 0, stream>>>(
            xout, pd2, ps2, tt + NTYPES * DDIM, bt, offs, srclist, cnt,
            w2u + DDIM * DDIM, b2u + DDIM,
            uw1 + (size_t)128 * 64, ub1 + DDIM,
            uw2 + (size_t)DDIM * DDIM, ub2 + DDIM,
            nullptr, nullptr, nullptr, E);
    } else {
        for (int l = 0; l < 2; ++l) {
            if (l > 0)
                proj_k<<<EB, 256, 0, stream>>>(xout, mw1 + (size_t)l * 192 * 64, pd, ps, E);
            layer_k<<<EBS, 512, 0, stream>>>(
                xout, pd, ps, tt + (size_t)l * NTYPES * DDIM, bt, offs, srclist, cnt,
                w2u + (size_t)l * DDIM * DDIM, b2u + (size_t)l * DDIM,
                uw1 + (size_t)l * 128 * 64, ub1 + (size_t)l * DDIM,
                uw2 + (size_t)l * DDIM * DDIM, ub2 + (size_t)l * DDIM,
                nullptr, nullptr, nullptr, E);
        }
    }

    hipMemsetAsync(gfeat, 0, NGRAPHS * DDIM * sizeof(float), stream);
    pool_k<<<PB, 256, 0, stream>>>(xout, row, batch, gfeat, E);
    pool_final_k<<<NGRAPHS, 64, 0, stream>>>(row, batch, gfeat, E);
}

// Round 11
// 384.515 us; speedup vs baseline: 1.3091x; 1.0436x over previous
//
#include <hip/hip_runtime.h>
#include <cstdint>
#include <cstddef>

#define HDIM 128
#define DDIM 64
#define NTYPES 5
#define NGRAPHS 16
#define PCHUNK 128   // edges per pooling block
#define EPB 64       // edges per block (one per lane)
#define APW 8        // atoms per wave in atom_proj

// fast silu: v_rcp_f32 (rel err ~1e-7) instead of precise-division sequence
static __device__ __forceinline__ float silu_f(float v) {
    return v * __builtin_amdgcn_rcpf(1.0f + __expf(-v));
}

static __device__ __forceinline__ float4 ld4(const float* p) {
    return *reinterpret_cast<const float4*>(p);
}

static __device__ __forceinline__ void st4(float* p, float4 v) {
    *reinterpret_cast<float4*>(p) = v;
}

static __device__ __forceinline__ float4 add4(float4 a, float4 b) {
    return make_float4(a.x + b.x, a.y + b.y, a.z + b.z, a.w + b.w);
}

static __device__ __forceinline__ void silu_acc4(float4& s, float4 v) {
    s.x += silu_f(v.x);
    s.y += silu_f(v.y);
    s.z += silu_f(v.z);
    s.w += silu_f(v.w);
}

// XCD-affinity swizzle (heuristic blk%8 -> XCD round-robin; validated r7:
// layer_k FETCH 82 -> 25.7 MB).
static __device__ __forceinline__ int xcd_logical_block() {
    int chunk = (int)(gridDim.x >> 3);
    return (int)(blockIdx.x & 7) * chunk + (int)(blockIdx.x >> 3);
}

// ---------------- CSR build ----------------
__global__ void __launch_bounds__(256) count_k(const int* __restrict__ bdst,
                                               int* __restrict__ cnt, int BE) {
    int i = blockIdx.x * 256 + threadIdx.x;
    if (i < BE)
        __hip_atomic_fetch_add(&cnt[bdst[i]], 1, __ATOMIC_RELAXED, __HIP_MEMORY_SCOPE_AGENT);
}

__global__ void __launch_bounds__(256) bsum_k(const int* __restrict__ cnt,
                                              int* __restrict__ bsum, int E) {
    __shared__ int red[256];
    int t = threadIdx.x;
    int i = blockIdx.x * 256 + t;
    red[t] = (i < E) ? cnt[i] : 0;
    __syncthreads();
    #pragma unroll
    for (int off = 128; off > 0; off >>= 1) {
        if (t < off) red[t] += red[t + off];
        __syncthreads();
    }
    if (t == 0) bsum[blockIdx.x] = red[0];
}

__global__ void __launch_bounds__(1024) bscan_k(const int* __restrict__ bsum,
                                                int* __restrict__ bpre, int NB) {
    __shared__ int sh[1024];
    int t = threadIdx.x;
    int v0 = (t < NB) ? bsum[t] : 0;
    sh[t] = v0;
    __syncthreads();
    for (int off = 1; off < 1024; off <<= 1) {
        int v = (t >= off) ? sh[t - off] : 0;
        __syncthreads();
        sh[t] += v;
        __syncthreads();
    }
    if (t < NB) bpre[t] = sh[t] - v0;
}

__global__ void __launch_bounds__(256) offs_k(const int* __restrict__ cnt,
                                              const int* __restrict__ bpre,
                                              int* __restrict__ offs,
                                              int* __restrict__ cursor, int E) {
    __shared__ int sh[256];
    int t = threadIdx.x;
    int i = blockIdx.x * 256 + t;
    int v0 = (i < E) ? cnt[i] : 0;
    sh[t] = v0;
    __syncthreads();
    for (int off = 1; off < 256; off <<= 1) {
        int v = (t >= off) ? sh[t - off] : 0;
        __syncthreads();
        sh[t] += v;
        __syncthreads();
    }
    int ex = sh[t] - v0 + bpre[blockIdx.x];
    if (i < E) { offs[i] = ex; cursor[i] = ex; }
    if (i == E - 1) offs[E] = ex + v0;
}

__global__ void __launch_bounds__(256) scatter_k(const int* __restrict__ bsrc,
                                                 const int* __restrict__ bdst,
                                                 int* __restrict__ cursor,
                                                 int* __restrict__ srclist, int BE) {
    int i = blockIdx.x * 256 + threadIdx.x;
    if (i < BE) {
        int d = bdst[i];
        int p = __hip_atomic_fetch_add(&cursor[d], 1, __ATOMIC_RELAXED,
                                       __HIP_MEMORY_SCOPE_AGENT);
        srclist[p] = bsrc[i];
    }
}

// tt for BOTH layers
__global__ void __launch_bounds__(64) tt2_k(const float* __restrict__ emb,
                                            const float* __restrict__ mw1,
                                            const float* __restrict__ mb1,
                                            float* __restrict__ tt) {
    int b = blockIdx.x;
    int l = b / NTYPES, t = b % NTYPES, j = threadIdx.x;
    const float* embl = emb + (size_t)l * NTYPES * DDIM + (size_t)t * DDIM;
    const float* w1 = mw1 + (size_t)l * 192 * DDIM;
    float s = mb1[l * DDIM + j];
    #pragma unroll 8
    for (int k = 0; k < DDIM; ++k)
        s = fmaf(embl[k], w1[(HDIM + k) * DDIM + j], s);
    tt[(size_t)b * DDIM + j] = s;
}

// Fused weights: W2u[l] = mw2[l] @ uw1[l][0:64]; b2u[l] = mb2[l] @ uw1[l][0:64].
__global__ void __launch_bounds__(64) fuse_k(const float* __restrict__ mw2,
                                             const float* __restrict__ mb2,
                                             const float* __restrict__ uw1,
                                             float* __restrict__ w2u,
                                             float* __restrict__ b2u) {
    int l = blockIdx.x >> 6, k = blockIdx.x & 63, j = threadIdx.x;
    const float* w2 = mw2 + (size_t)l * DDIM * DDIM;
    const float* u1 = uw1 + (size_t)l * 128 * DDIM;   // rows 0..63 = mm part
    float s = 0.f;
    #pragma unroll 8
    for (int t = 0; t < DDIM; ++t)
        s = fmaf(w2[k * DDIM + t], u1[(size_t)t * DDIM + j], s);
    w2u[(size_t)l * DDIM * DDIM + (size_t)k * DDIM + j] = s;
    if (k == 0) {
        float b = 0.f;
        #pragma unroll 8
        for (int t = 0; t < DDIM; ++t)
            b = fmaf(mb2[l * DDIM + t], u1[(size_t)t * DDIM + j], b);
        b2u[l * DDIM + j] = b;
    }
}

// ---------------- atom-side projection: wave-per-8-atoms, lane = feature ----------------
__global__ void __launch_bounds__(256) atom_proj_k(
    const float* __restrict__ AF, const float* __restrict__ iw1,
    float* __restrict__ pa, float* __restrict__ qa, float* __restrict__ na, int N) {
    int lane = threadIdx.x & 63;
    int w = __builtin_amdgcn_readfirstlane((int)(threadIdx.x >> 6));
    int abase = blockIdx.x * (4 * APW) + w * APW;
    if (abase >= N) return;

    float accp[APW], accq[APW], nrm[APW];
    #pragma unroll
    for (int a = 0; a < APW; ++a) { accp[a] = 0.f; accq[a] = 0.f; nrm[a] = 0.f; }

    #pragma unroll 4
    for (int k = 0; k < HDIM; k += 4) {
        float wt[4], wb[4];
        #pragma unroll
        for (int kk = 0; kk < 4; ++kk) {
            wt[kk] = iw1[(size_t)(k + kk) * DDIM + lane];
            wb[kk] = iw1[(size_t)(HDIM + k + kk) * DDIM + lane];
        }
        #pragma unroll
        for (int a = 0; a < APW; ++a) {
            int aa = min(abase + a, N - 1);           // wave-uniform
            float4 hv = ld4(AF + (size_t)aa * HDIM + k);
            accp[a] = fmaf(hv.x, wt[0], accp[a]);
            accp[a] = fmaf(hv.y, wt[1], accp[a]);
            accp[a] = fmaf(hv.z, wt[2], accp[a]);
            accp[a] = fmaf(hv.w, wt[3], accp[a]);
            accq[a] = fmaf(hv.x, wb[0], accq[a]);
            accq[a] = fmaf(hv.y, wb[1], accq[a]);
            accq[a] = fmaf(hv.z, wb[2], accq[a]);
            accq[a] = fmaf(hv.w, wb[3], accq[a]);
            nrm[a] = fmaf(hv.x, hv.x, nrm[a]);
            nrm[a] = fmaf(hv.y, hv.y, nrm[a]);
            nrm[a] = fmaf(hv.z, hv.z, nrm[a]);
            nrm[a] = fmaf(hv.w, hv.w, nrm[a]);
        }
    }
    #pragma unroll
    for (int a = 0; a < APW; ++a) {
        int atom = abase + a;
        if (atom < N) {
            pa[(size_t)atom * DDIM + lane] = accp[a];
            qa[(size_t)atom * DDIM + lane] = accq[a];
            if (lane == 0) na[atom] = sqrtf(nrm[a]);
        }
    }
}

// ---------------- bond init (from atom projections) + layer-0 proj ----------------
// 512 threads = 8 waves; lane = bond; wave w owns 8-feature slice [8w, 8w+8).
__global__ void __launch_bounds__(512) bond_init2_k(
    const float* __restrict__ AF, const int* __restrict__ row, const int* __restrict__ col,
    const float* __restrict__ pa, const float* __restrict__ qa, const float* __restrict__ na,
    const float* __restrict__ b1, const float* __restrict__ w2, const float* __restrict__ b2,
    const float* __restrict__ w1p /*[192][64] layer0 mw1*/,
    float* __restrict__ x, int* __restrict__ bt,
    float* __restrict__ pd, float* __restrict__ ps, int E) {
    __shared__ float hbuf[EPB][DDIM + 1];
    __shared__ float dotb[EPB][8];
    int nEB = (E + EPB - 1) / EPB;
    int lb = xcd_logical_block();
    if (lb >= nEB) return;
    int tid = threadIdx.x;
    int lane = tid & 63;
    int w = __builtin_amdgcn_readfirstlane((int)(tid >> 6));   // 0..7
    int e = lb * EPB + lane;
    bool ok = e < E;
    int eidx = ok ? e : 0;
    int r = row[eidx], c = col[eidx];
    int j0 = w * 8;

    // partial dot over K-chunk [16w, 16w+16)
    {
        const float* hi = AF + (size_t)r * HDIM + w * 16;
        const float* hj = AF + (size_t)c * HDIM + w * 16;
        float d = 0.f;
        #pragma unroll
        for (int k = 0; k < 16; k += 4) {
            float4 a4 = ld4(hi + k), b4 = ld4(hj + k);
            d += a4.x * b4.x + a4.y * b4.y + a4.z * b4.z + a4.w * b4.w;
        }
        dotb[lane][w] = d;
    }

    // layer-1 hidden slice: silu(pa[r] + qa[c] + b1)
    {
        const float* pr = pa + (size_t)r * DDIM + j0;
        const float* qc = qa + (size_t)c * DDIM + j0;
        float4 p0 = ld4(pr + 0), p1 = ld4(pr + 4);
        float4 q0 = ld4(qc + 0), q1 = ld4(qc + 4);
        hbuf[lane][j0 + 0] = silu_f(p0.x + q0.x + b1[j0 + 0]);
        hbuf[lane][j0 + 1] = silu_f(p0.y + q0.y + b1[j0 + 1]);
        hbuf[lane][j0 + 2] = silu_f(p0.z + q0.z + b1[j0 + 2]);
        hbuf[lane][j0 + 3] = silu_f(p0.w + q0.w + b1[j0 + 3]);
        hbuf[lane][j0 + 4] = silu_f(p1.x + q1.x + b1[j0 + 4]);
        hbuf[lane][j0 + 5] = silu_f(p1.y + q1.y + b1[j0 + 5]);
        hbuf[lane][j0 + 6] = silu_f(p1.z + q1.z + b1[j0 + 6]);
        hbuf[lane][j0 + 7] = silu_f(p1.w + q1.w + b1[j0 + 7]);
    }
    __syncthreads();

    if (w == 0) {
        float dot = dotb[lane][0] + dotb[lane][1] + dotb[lane][2] + dotb[lane][3]
                  + dotb[lane][4] + dotb[lane][5] + dotb[lane][6] + dotb[lane][7];
        float nr = fmaxf(na[r], 1e-8f), nc = fmaxf(na[c], 1e-8f);
        float sim = dot / (nr * nc);
        int t = 0;
        if (sim > 0.8f) t = 1;
        if (sim > 0.9f) t = 2;
        if (sim < 0.3f) t = 3;
        if (ok) bt[e] = t;
    }

    // layer-2: x = h @ w2 + b2 (K=64 from LDS)
    float o[8];
    #pragma unroll
    for (int jj = 0; jj < 8; ++jj) o[jj] = b2[j0 + jj];
    #pragma unroll 4
    for (int k = 0; k < DDIM; ++k) {
        float hk = hbuf[lane][k];
        const float* wk = w2 + (size_t)k * DDIM + j0;
        #pragma unroll
        for (int jj = 0; jj < 8; ++jj) o[jj] = fmaf(hk, wk[jj], o[jj]);
    }
    if (ok) {
        float* xr = x + (size_t)e * DDIM + j0;
        st4(xr + 0, make_float4(o[0], o[1], o[2], o[3]));
        st4(xr + 4, make_float4(o[4], o[5], o[6], o[7]));
    }
    __syncthreads();            // all reads of hbuf (h) done
    #pragma unroll
    for (int jj = 0; jj < 8; ++jj) hbuf[lane][j0 + jj] = o[jj];   // x row
    __syncthreads();

    // proj (layer 0): pd = x@W1[0:64], ps = x@W1[64:128]
    float apd[8], aps[8];
    #pragma unroll
    for (int jj = 0; jj < 8; ++jj) { apd[jj] = 0.f; aps[jj] = 0.f; }
    #pragma unroll 4
    for (int k = 0; k < DDIM; ++k) {
        float xk = hbuf[lane][k];
        const float* wd = w1p + (size_t)k * DDIM + j0;
        const float* wsv = w1p + (size_t)(DDIM + k) * DDIM + j0;
        #pragma unroll
        for (int jj = 0; jj < 8; ++jj) {
            apd[jj] = fmaf(xk, wd[jj], apd[jj]);
            aps[jj] = fmaf(xk, wsv[jj], aps[jj]);
        }
    }
    if (ok) {
        float* pr = pd + (size_t)e * DDIM + j0;
        float* qr = ps + (size_t)e * DDIM + j0;
        st4(pr + 0, make_float4(apd[0], apd[1], apd[2], apd[3]));
        st4(pr + 4, make_float4(apd[4], apd[5], apd[6], apd[7]));
        st4(qr + 0, make_float4(aps[0], aps[1], aps[2], aps[3]));
        st4(qr + 4, make_float4(aps[4], aps[5], aps[6], aps[7]));
    }
}

// proj (x from global) — fallback path only (used if ws too small for pd2/ps2)
__global__ void __launch_bounds__(256) proj_k(const float* __restrict__ x,
                                              const float* __restrict__ w1 /*[192][64]*/,
                                              float* __restrict__ pd, float* __restrict__ ps,
                                              int E) {
    int lane = threadIdx.x & 63;
    int w = __builtin_amdgcn_readfirstlane((int)(threadIdx.x >> 6));
    int e = blockIdx.x * EPB + lane;
    bool ok = e < E;
    int eidx = ok ? e : 0;
    int j0 = w * 16;
    const float* xr = x + (size_t)eidx * DDIM;

    float apd[16], aps[16];
    #pragma unroll
    for (int jj = 0; jj < 16; ++jj) { apd[jj] = 0.f; aps[jj] = 0.f; }
    #pragma unroll 2
    for (int c = 0; c < 16; ++c) {
        float4 v = ld4(xr + c * 4);
        float xv[4] = {v.x, v.y, v.z, v.w};
        #pragma unroll
        for (int kk = 0; kk < 4; ++kk) {
            int k = c * 4 + kk;
            const float* wd = w1 + (size_t)k * DDIM + j0;
            const float* wsv = w1 + (size_t)(DDIM + k) * DDIM + j0;
            #pragma unroll
            for (int jj = 0; jj < 16; ++jj) {
                apd[jj] = fmaf(xv[kk], wd[jj], apd[jj]);
                aps[jj] = fmaf(xv[kk], wsv[jj], aps[jj]);
            }
        }
    }
    if (ok) {
        float* pr = pd + (size_t)e * DDIM + j0;
        float* qr = ps + (size_t)e * DDIM + j0;
        st4(pr + 0,  make_float4(apd[0],  apd[1],  apd[2],  apd[3]));
        st4(pr + 4,  make_float4(apd[4],  apd[5],  apd[6],  apd[7]));
        st4(pr + 8,  make_float4(apd[8],  apd[9],  apd[10], apd[11]));
        st4(pr + 12, make_float4(apd[12], apd[13], apd[14], apd[15]));
        st4(qr + 0,  make_float4(aps[0],  aps[1],  aps[2],  aps[3]));
        st4(qr + 4,  make_float4(aps[4],  aps[5],  aps[6],  aps[7]));
        st4(qr + 8,  make_float4(aps[8],  aps[9],  aps[10], aps[11]));
        st4(qr + 12, make_float4(aps[12], aps[13], aps[14], aps[15]));
    }
}

// ---------------- fused gather + update (+ optional next-layer proj) ----------------
// 512 threads = 8 waves. P1: 8 thr/bond gather s -> sb. P3': h = silu(...) (8-feature
// wave slices). P4: x += h@Wu2 + ub2. P5 (if w1n): pdn/psn = x_new @ w1n from LDS.
__global__ void __launch_bounds__(512) layer_k(
    float* __restrict__ x, const float* __restrict__ pd, const float* __restrict__ ps,
    const float* __restrict__ tt_l, const int* __restrict__ bt,
    const int* __restrict__ offs, const int* __restrict__ srclist,
    const int* __restrict__ cnt,
    const float* __restrict__ w2u, const float* __restrict__ b2u,
    const float* __restrict__ uw1 /*[128][64], rows 64..127 used*/,
    const float* __restrict__ ub1,
    const float* __restrict__ uw2 /*[64][64]*/, const float* __restrict__ ub2,
    const float* __restrict__ w1n /* next-layer mw1 or nullptr */,
    float* __restrict__ pdn, float* __restrict__ psn, int E) {
    __shared__ float sb[EPB][DDIM + 1];
    int nEB = (E + EPB - 1) / EPB;
    int lb = xcd_logical_block();
    if (lb >= nEB) return;
    int tid = threadIdx.x;
    int lane = tid & 63;
    int w = __builtin_amdgcn_readfirstlane((int)(tid >> 6));   // 0..7
    int e = lb * EPB + lane;
    bool ok = e < E;
    int eidx = ok ? e : 0;
    int j0 = w * 8;

    // ---- P1: gather (8 threads per bond, 8 features each), 2-way unrolled ----
    {
        int d_local = tid >> 3, q = tid & 7;
        int d = lb * EPB + d_local;
        if (d < E) {
            int jq = q * 8;
            const float* pr = pd + (size_t)d * DDIM + jq;
            const float* tp = tt_l + (size_t)bt[d] * DDIM + jq;
            float4 b0 = add4(ld4(pr + 0), ld4(tp + 0));
            float4 b1 = add4(ld4(pr + 4), ld4(tp + 4));
            float4 s0 = make_float4(0, 0, 0, 0), s1 = s0;
            int p0 = offs[d], p1 = offs[d + 1];
            int p = p0;
            for (; p + 2 <= p1; p += 2) {
                const float* sa = ps + (size_t)srclist[p] * DDIM + jq;
                const float* sc = ps + (size_t)srclist[p + 1] * DDIM + jq;
                float4 u0 = ld4(sa + 0), u1 = ld4(sa + 4);
                float4 v0 = ld4(sc + 0), v1 = ld4(sc + 4);
                silu_acc4(s0, add4(b0, u0));
                silu_acc4(s1, add4(b1, u1));
                silu_acc4(s0, add4(b0, v0));
                silu_acc4(s1, add4(b1, v1));
            }
            if (p < p1) {
                const float* sa = ps + (size_t)srclist[p] * DDIM + jq;
                float4 u0 = ld4(sa + 0), u1 = ld4(sa + 4);
                silu_acc4(s0, add4(b0, u0));
                silu_acc4(s1, add4(b1, u1));
            }
            st4(&sb[d_local][jq + 0], s0);
            st4(&sb[d_local][jq + 4], s1);
        }
    }
    __syncthreads();

    // ---- P3': h = silu(inv*(s@W2u) + inv*deg*b2u + x@Wu1[64:] + ub1) ----
    float degf = (float)cnt[eidx];
    float inv = 1.0f / fmaxf(degf, 1.0f);
    const float* xr = x + (size_t)eidx * DDIM;
    float h[8];
    {
        float sm[8];
        #pragma unroll
        for (int jj = 0; jj < 8; ++jj) sm[jj] = 0.f;
        #pragma unroll 4
        for (int k = 0; k < DDIM; ++k) {
            float sk = sb[lane][k];
            const float* wk = w2u + (size_t)k * DDIM + j0;
            #pragma unroll
            for (int jj = 0; jj < 8; ++jj) sm[jj] = fmaf(sk, wk[jj], sm[jj]);
        }
        float ah[8];
        float dib = degf * inv;
        #pragma unroll
        for (int jj = 0; jj < 8; ++jj)
            ah[jj] = fmaf(inv, sm[jj], fmaf(dib, b2u[j0 + jj], ub1[j0 + jj]));
        #pragma unroll 2
        for (int c = 0; c < 16; ++c) {
            float4 v = ld4(xr + c * 4);
            float xv[4] = {v.x, v.y, v.z, v.w};
            #pragma unroll
            for (int kk = 0; kk < 4; ++kk) {
                const float* wk = uw1 + (size_t)(DDIM + c * 4 + kk) * DDIM + j0;
                #pragma unroll
                for (int jj = 0; jj < 8; ++jj) ah[jj] = fmaf(xv[kk], wk[jj], ah[jj]);
            }
        }
        #pragma unroll
        for (int jj = 0; jj < 8; ++jj) h[jj] = silu_f(ah[jj]);
    }
    __syncthreads();     // all reads of sb (s) done
    #pragma unroll
    for (int jj = 0; jj < 8; ++jj) sb[lane][j0 + jj] = h[jj];
    __syncthreads();

    // ---- P4: u-layer2 + residual ----
    float xn[8];
    {
        float o[8];
        #pragma unroll
        for (int jj = 0; jj < 8; ++jj) o[jj] = ub2[j0 + jj];
        #pragma unroll 4
        for (int k = 0; k < DDIM; ++k) {
            float hk = sb[lane][k];
            const float* wk = uw2 + (size_t)k * DDIM + j0;
            #pragma unroll
            for (int jj = 0; jj < 8; ++jj) o[jj] = fmaf(hk, wk[jj], o[jj]);
        }
        float4 x0 = ld4(xr + j0), x1 = ld4(xr + j0 + 4);
        xn[0] = x0.x + o[0]; xn[1] = x0.y + o[1];
        xn[2] = x0.z + o[2]; xn[3] = x0.w + o[3];
        xn[4] = x1.x + o[4]; xn[5] = x1.y + o[5];
        xn[6] = x1.z + o[6]; xn[7] = x1.w + o[7];
        if (ok) {
            float* xw = x + (size_t)e * DDIM + j0;
            st4(xw + 0, make_float4(xn[0], xn[1], xn[2], xn[3]));
            st4(xw + 4, make_float4(xn[4], xn[5], xn[6], xn[7]));
        }
    }

    // ---- P5 (optional): next-layer proj from x_new in LDS ----
    if (w1n != nullptr) {
        __syncthreads();     // all reads of sb (h) done
        #pragma unroll
        for (int jj = 0; jj < 8; ++jj) sb[lane][j0 + jj] = xn[jj];
        __syncthreads();
        float apd[8], aps[8];
        #pragma unroll
        for (int jj = 0; jj < 8; ++jj) { apd[jj] = 0.f; aps[jj] = 0.f; }
        #pragma unroll 4
        for (int k = 0; k < DDIM; ++k) {
            float xk = sb[lane][k];
            const float* wd = w1n + (size_t)k * DDIM + j0;
            const float* wsv = w1n + (size_t)(DDIM + k) * DDIM + j0;
            #pragma unroll
            for (int jj = 0; jj < 8; ++jj) {
                apd[jj] = fmaf(xk, wd[jj], apd[jj]);
                aps[jj] = fmaf(xk, wsv[jj], aps[jj]);
            }
        }
        if (ok) {
            float* pr = pdn + (size_t)e * DDIM + j0;
            float* qr = psn + (size_t)e * DDIM + j0;
            st4(pr + 0, make_float4(apd[0], apd[1], apd[2], apd[3]));
            st4(pr + 4, make_float4(apd[4], apd[5], apd[6], apd[7]));
            st4(qr + 0, make_float4(aps[0], aps[1], aps[2], aps[3]));
            st4(qr + 4, make_float4(aps[4], aps[5], aps[6], aps[7]));
        }
    }
}

// ---------------- pooling ----------------
__global__ void __launch_bounds__(256) pool_k(
    const float* __restrict__ x, const int* __restrict__ row,
    const int* __restrict__ batch, float* __restrict__ gfeat, int E) {
    int lane = threadIdx.x & 63;
    int esub = threadIdx.x >> 6;       // 0..3
    int e0 = blockIdx.x * PCHUNK;
    int e1 = min(e0 + PCHUNK, E);
    float sum = 0.f;
    int cur = -1;
    for (int e = e0 + esub; e < e1; e += 4) {
        int g = batch[row[e]];         // wave-uniform -> scalar load
        if (g != cur) {
            if (cur >= 0)
                __hip_atomic_fetch_add(&gfeat[cur * DDIM + lane], sum,
                                       __ATOMIC_RELAXED, __HIP_MEMORY_SCOPE_AGENT);
            cur = g;
            sum = 0.f;
        }
        sum += x[(size_t)e * DDIM + lane];
    }
    if (cur >= 0)
        __hip_atomic_fetch_add(&gfeat[cur * DDIM + lane], sum,
                               __ATOMIC_RELAXED, __HIP_MEMORY_SCOPE_AGENT);
}

static __device__ __forceinline__ int lower_bound_bb(const int* __restrict__ row,
                                                     const int* __restrict__ batch,
                                                     int E, int g) {
    int lo = 0, hi = E;
    while (lo < hi) {
        int m = (lo + hi) >> 1;
        if (batch[row[m]] < g) lo = m + 1; else hi = m;
    }
    return lo;
}

__global__ void __launch_bounds__(64) pool_final_k(
    const int* __restrict__ row, const int* __restrict__ batch,
    float* __restrict__ gfeat, int E) {
    int g = blockIdx.x, j = threadIdx.x;
    int s = lower_bound_bb(row, batch, E, g);
    int t = lower_bound_bb(row, batch, E, g + 1);
    float cnt = fmaxf((float)(t - s), 1.0f);
    gfeat[g * DDIM + j] /= cnt;
}

extern "C" void kernel_launch(void* const* d_in, const int* in_sizes, int n_in,
                              void* d_out, int out_size, void* d_ws, size_t ws_size,
                              hipStream_t stream) {
    (void)n_in; (void)out_size;
    const float* AF    = (const float*)d_in[0];
    const int*   batch = (const int*)d_in[3];
    const int*   edge_index      = (const int*)d_in[4];
    const int*   bond_edge_index = (const int*)d_in[5];
    const float* iw1 = (const float*)d_in[6];
    const float* ib1 = (const float*)d_in[7];
    const float* iw2 = (const float*)d_in[8];
    const float* ib2 = (const float*)d_in[9];
    const float* emb = (const float*)d_in[10];
    const float* mw1 = (const float*)d_in[11];
    const float* mb1 = (const float*)d_in[12];
    const float* mw2 = (const float*)d_in[13];
    const float* mb2 = (const float*)d_in[14];
    const float* uw1 = (const float*)d_in[15];
    const float* ub1 = (const float*)d_in[16];
    const float* uw2 = (const float*)d_in[17];
    const float* ub2 = (const float*)d_in[18];

    const int N  = in_sizes[0] / HDIM;
    const int E  = in_sizes[4] / 2;
    const int BE = in_sizes[5] / 2;
    const int NB = (E + 255) / 256;
    const int EB = (E + EPB - 1) / EPB;
    const int AB = (N + 4 * APW - 1) / (4 * APW);   // atom blocks (32 atoms/block)
    const int EBS = ((EB + 7) / 8) * 8;             // swizzled grid (multiple of 8)
    const int PB = (E + PCHUNK - 1) / PCHUNK;       // pooling blocks

    float* xout  = (float*)d_out;                 // [E,64]
    float* gfeat = xout + (size_t)E * DDIM;       // [16,64]

    // workspace layout
    char* w = (char*)d_ws;
    float* tt       = (float*)w;  w += sizeof(float) * 2 * NTYPES * DDIM;
    float* w2u      = (float*)w;  w += sizeof(float) * 2 * DDIM * DDIM;
    float* b2u      = (float*)w;  w += sizeof(float) * 2 * DDIM;
    int*   cnt      = (int*)w;    w += sizeof(int) * E;
    int*   offs     = (int*)w;    w += sizeof(int) * (E + 1);
    int*   cursor   = (int*)w;    w += sizeof(int) * E;
    int*   bt       = (int*)w;    w += sizeof(int) * E;
    int*   bsum     = (int*)w;    w += sizeof(int) * 1024;
    int*   bpre     = (int*)w;    w += sizeof(int) * 1024;
    int*   srclist  = (int*)w;    w += sizeof(int) * BE;
    w = (char*)(((uintptr_t)w + 15) & ~(uintptr_t)15);
    float* pd       = (float*)w;  w += sizeof(float) * (size_t)E * DDIM;
    float* ps       = (float*)w;  w += sizeof(float) * (size_t)E * DDIM;
    float* pa       = (float*)w;  w += sizeof(float) * (size_t)N * DDIM;
    float* qa       = (float*)w;  w += sizeof(float) * (size_t)N * DDIM;
    float* na       = (float*)w;  w += sizeof(float) * (size_t)N;
    // optional second proj buffers (fused-proj path)
    float* pd2      = (float*)w;  w += sizeof(float) * (size_t)E * DDIM;
    float* ps2      = (float*)w;  w += sizeof(float) * (size_t)E * DDIM;
    bool fuse_proj = ((size_t)(w - (char*)d_ws) <= ws_size);

    const int* row  = edge_index;
    const int* col  = edge_index + E;
    const int* bsrc = bond_edge_index;
    const int* bdst = bond_edge_index + BE;

    // CSR build
    hipMemsetAsync(cnt, 0, (size_t)E * sizeof(int), stream);
    count_k<<<(BE + 255) / 256, 256, 0, stream>>>(bdst, cnt, BE);
    bsum_k<<<NB, 256, 0, stream>>>(cnt, bsum, E);
    bscan_k<<<1, 1024, 0, stream>>>(bsum, bpre, NB);
    offs_k<<<NB, 256, 0, stream>>>(cnt, bpre, offs, cursor, E);
    scatter_k<<<(BE + 255) / 256, 256, 0, stream>>>(bsrc, bdst, cursor, srclist, BE);

    // constants: bond-type embeddings + fused mm weights
    tt2_k<<<2 * NTYPES, 64, 0, stream>>>(emb, mw1, mb1, tt);
    fuse_k<<<2 * 64, 64, 0, stream>>>(mw2, mb2, uw1, w2u, b2u);

    // atom projections, then bond init + layer-0 proj
    atom_proj_k<<<AB, 256, 0, stream>>>(AF, iw1, pa, qa, na, N);
    bond_init2_k<<<EBS, 512, 0, stream>>>(AF, row, col, pa, qa, na, ib1, iw2, ib2,
                                          mw1 /* layer 0 */, xout, bt, pd, ps, E);

    if (fuse_proj) {
        // layer 0: fused next-layer proj -> pd2/ps2
        layer_k<<<EBS, 512, 0, stream>>>(
            xout, pd, ps, tt, bt, offs, srclist, cnt,
            w2u, b2u, uw1, ub1, uw2, ub2,
            mw1 + (size_t)192 * 64, pd2, ps2, E);
        // layer 1: no proj
        layer_k<<<EBS, 512, 0, stream>>>(
            xout, pd2, ps2, tt + NTYPES * DDIM, bt, offs, srclist, cnt,
            w2u + DDIM * DDIM, b2u + DDIM,
            uw1 + (size_t)128 * 64, ub1 + DDIM,
            uw2 + (size_t)DDIM * DDIM, ub2 + DDIM,
            nullptr, nullptr, nullptr, E);
    } else {
        for (int l = 0; l < 2; ++l) {
            if (l > 0)
                proj_k<<<EB, 256, 0, stream>>>(xout, mw1 + (size_t)l * 192 * 64, pd, ps, E);
            layer_k<<<EBS, 512, 0, stream>>>(
                xout, pd, ps, tt + (size_t)l * NTYPES * DDIM, bt, offs, srclist, cnt,
                w2u + (size_t)l * DDIM * DDIM, b2u + (size_t)l * DDIM,
                uw1 + (size_t)l * 128 * 64, ub1 + (size_t)l * DDIM,
                uw2 + (size_t)l * DDIM * DDIM, ub2 + (size_t)l * DDIM,
                nullptr, nullptr, nullptr, E);
        }
    }

    hipMemsetAsync(gfeat, 0, NGRAPHS * DDIM * sizeof(float), stream);
    pool_k<<<PB, 256, 0, stream>>>(xout, row, batch, gfeat, E);
    pool_final_k<<<NGRAPHS, 64, 0, stream>>>(row, batch, gfeat, E);
}

// Round 12
// 380.010 us; speedup vs baseline: 1.3247x; 1.0119x over previous
//
#include <hip/hip_runtime.h>
#include <cstdint>
#include <cstddef>

#define HDIM 128
#define DDIM 64
#define NTYPES 5
#define NGRAPHS 16
#define PCHUNK 128   // edges per pooling block
#define EPB 64       // edges per block (one per lane)
#define APW 8        // atoms per wave in atom_proj

// fast silu: v_rcp_f32 (rel err ~1e-7) instead of precise-division sequence
static __device__ __forceinline__ float silu_f(float v) {
    return v * __builtin_amdgcn_rcpf(1.0f + __expf(-v));
}

static __device__ __forceinline__ float4 ld4(const float* p) {
    return *reinterpret_cast<const float4*>(p);
}

static __device__ __forceinline__ void st4(float* p, float4 v) {
    *reinterpret_cast<float4*>(p) = v;
}

static __device__ __forceinline__ float4 add4(float4 a, float4 b) {
    return make_float4(a.x + b.x, a.y + b.y, a.z + b.z, a.w + b.w);
}

static __device__ __forceinline__ void silu_acc4(float4& s, float4 v) {
    s.x += silu_f(v.x);
    s.y += silu_f(v.y);
    s.z += silu_f(v.z);
    s.w += silu_f(v.w);
}

// ---- bf16 pack/unpack (round-to-nearest-even; feature j0+0 in low half) ----
static __device__ __forceinline__ unsigned int bf16r(float f) {
    unsigned int u = __float_as_uint(f);
    return (u + 0x7FFFu + ((u >> 16) & 1u)) >> 16;
}
static __device__ __forceinline__ uint4 pack8(const float* f) {
    uint4 r;
    r.x = bf16r(f[0]) | (bf16r(f[1]) << 16);
    r.y = bf16r(f[2]) | (bf16r(f[3]) << 16);
    r.z = bf16r(f[4]) | (bf16r(f[5]) << 16);
    r.w = bf16r(f[6]) | (bf16r(f[7]) << 16);
    return r;
}
static __device__ __forceinline__ void unpack8(uint4 u, float4& a, float4& b) {
    a.x = __uint_as_float(u.x << 16);
    a.y = __uint_as_float(u.x & 0xFFFF0000u);
    a.z = __uint_as_float(u.y << 16);
    a.w = __uint_as_float(u.y & 0xFFFF0000u);
    b.x = __uint_as_float(u.z << 16);
    b.y = __uint_as_float(u.z & 0xFFFF0000u);
    b.z = __uint_as_float(u.w << 16);
    b.w = __uint_as_float(u.w & 0xFFFF0000u);
}

// XCD-affinity swizzle (heuristic blk%8 -> XCD round-robin; validated r7:
// layer_k FETCH 82 -> 25.7 MB).
static __device__ __forceinline__ int xcd_logical_block() {
    int chunk = (int)(gridDim.x >> 3);
    return (int)(blockIdx.x & 7) * chunk + (int)(blockIdx.x >> 3);
}

// ---------------- CSR build ----------------
__global__ void __launch_bounds__(256) count_k(const int* __restrict__ bdst,
                                               int* __restrict__ cnt, int BE) {
    int i = blockIdx.x * 256 + threadIdx.x;
    if (i < BE)
        __hip_atomic_fetch_add(&cnt[bdst[i]], 1, __ATOMIC_RELAXED, __HIP_MEMORY_SCOPE_AGENT);
}

__global__ void __launch_bounds__(256) bsum_k(const int* __restrict__ cnt,
                                              int* __restrict__ bsum, int E) {
    __shared__ int red[256];
    int t = threadIdx.x;
    int i = blockIdx.x * 256 + t;
    red[t] = (i < E) ? cnt[i] : 0;
    __syncthreads();
    #pragma unroll
    for (int off = 128; off > 0; off >>= 1) {
        if (t < off) red[t] += red[t + off];
        __syncthreads();
    }
    if (t == 0) bsum[blockIdx.x] = red[0];
}

__global__ void __launch_bounds__(1024) bscan_k(const int* __restrict__ bsum,
                                                int* __restrict__ bpre, int NB) {
    __shared__ int sh[1024];
    int t = threadIdx.x;
    int v0 = (t < NB) ? bsum[t] : 0;
    sh[t] = v0;
    __syncthreads();
    for (int off = 1; off < 1024; off <<= 1) {
        int v = (t >= off) ? sh[t - off] : 0;
        __syncthreads();
        sh[t] += v;
        __syncthreads();
    }
    if (t < NB) bpre[t] = sh[t] - v0;
}

__global__ void __launch_bounds__(256) offs_k(const int* __restrict__ cnt,
                                              const int* __restrict__ bpre,
                                              int* __restrict__ offs,
                                              int* __restrict__ cursor, int E) {
    __shared__ int sh[256];
    int t = threadIdx.x;
    int i = blockIdx.x * 256 + t;
    int v0 = (i < E) ? cnt[i] : 0;
    sh[t] = v0;
    __syncthreads();
    for (int off = 1; off < 256; off <<= 1) {
        int v = (t >= off) ? sh[t - off] : 0;
        __syncthreads();
        sh[t] += v;
        __syncthreads();
    }
    int ex = sh[t] - v0 + bpre[blockIdx.x];
    if (i < E) { offs[i] = ex; cursor[i] = ex; }
    if (i == E - 1) offs[E] = ex + v0;
}

__global__ void __launch_bounds__(256) scatter_k(const int* __restrict__ bsrc,
                                                 const int* __restrict__ bdst,
                                                 int* __restrict__ cursor,
                                                 int* __restrict__ srclist, int BE) {
    int i = blockIdx.x * 256 + threadIdx.x;
    if (i < BE) {
        int d = bdst[i];
        int p = __hip_atomic_fetch_add(&cursor[d], 1, __ATOMIC_RELAXED,
                                       __HIP_MEMORY_SCOPE_AGENT);
        srclist[p] = bsrc[i];
    }
}

// tt for BOTH layers
__global__ void __launch_bounds__(64) tt2_k(const float* __restrict__ emb,
                                            const float* __restrict__ mw1,
                                            const float* __restrict__ mb1,
                                            float* __restrict__ tt) {
    int b = blockIdx.x;
    int l = b / NTYPES, t = b % NTYPES, j = threadIdx.x;
    const float* embl = emb + (size_t)l * NTYPES * DDIM + (size_t)t * DDIM;
    const float* w1 = mw1 + (size_t)l * 192 * DDIM;
    float s = mb1[l * DDIM + j];
    #pragma unroll 8
    for (int k = 0; k < DDIM; ++k)
        s = fmaf(embl[k], w1[(HDIM + k) * DDIM + j], s);
    tt[(size_t)b * DDIM + j] = s;
}

// Fused weights: W2u[l] = mw2[l] @ uw1[l][0:64]; b2u[l] = mb2[l] @ uw1[l][0:64].
__global__ void __launch_bounds__(64) fuse_k(const float* __restrict__ mw2,
                                             const float* __restrict__ mb2,
                                             const float* __restrict__ uw1,
                                             float* __restrict__ w2u,
                                             float* __restrict__ b2u) {
    int l = blockIdx.x >> 6, k = blockIdx.x & 63, j = threadIdx.x;
    const float* w2 = mw2 + (size_t)l * DDIM * DDIM;
    const float* u1 = uw1 + (size_t)l * 128 * DDIM;   // rows 0..63 = mm part
    float s = 0.f;
    #pragma unroll 8
    for (int t = 0; t < DDIM; ++t)
        s = fmaf(w2[k * DDIM + t], u1[(size_t)t * DDIM + j], s);
    w2u[(size_t)l * DDIM * DDIM + (size_t)k * DDIM + j] = s;
    if (k == 0) {
        float b = 0.f;
        #pragma unroll 8
        for (int t = 0; t < DDIM; ++t)
            b = fmaf(mb2[l * DDIM + t], u1[(size_t)t * DDIM + j], b);
        b2u[l * DDIM + j] = b;
    }
}

// ---------------- atom-side projection: wave-per-8-atoms, lane = feature ----------------
__global__ void __launch_bounds__(256) atom_proj_k(
    const float* __restrict__ AF, const float* __restrict__ iw1,
    float* __restrict__ pa, float* __restrict__ qa, float* __restrict__ na, int N) {
    int lane = threadIdx.x & 63;
    int w = __builtin_amdgcn_readfirstlane((int)(threadIdx.x >> 6));
    int abase = blockIdx.x * (4 * APW) + w * APW;
    if (abase >= N) return;

    float accp[APW], accq[APW], nrm[APW];
    #pragma unroll
    for (int a = 0; a < APW; ++a) { accp[a] = 0.f; accq[a] = 0.f; nrm[a] = 0.f; }

    #pragma unroll 4
    for (int k = 0; k < HDIM; k += 4) {
        float wt[4], wb[4];
        #pragma unroll
        for (int kk = 0; kk < 4; ++kk) {
            wt[kk] = iw1[(size_t)(k + kk) * DDIM + lane];
            wb[kk] = iw1[(size_t)(HDIM + k + kk) * DDIM + lane];
        }
        #pragma unroll
        for (int a = 0; a < APW; ++a) {
            int aa = min(abase + a, N - 1);           // wave-uniform
            float4 hv = ld4(AF + (size_t)aa * HDIM + k);
            accp[a] = fmaf(hv.x, wt[0], accp[a]);
            accp[a] = fmaf(hv.y, wt[1], accp[a]);
            accp[a] = fmaf(hv.z, wt[2], accp[a]);
            accp[a] = fmaf(hv.w, wt[3], accp[a]);
            accq[a] = fmaf(hv.x, wb[0], accq[a]);
            accq[a] = fmaf(hv.y, wb[1], accq[a]);
            accq[a] = fmaf(hv.z, wb[2], accq[a]);
            accq[a] = fmaf(hv.w, wb[3], accq[a]);
            nrm[a] = fmaf(hv.x, hv.x, nrm[a]);
            nrm[a] = fmaf(hv.y, hv.y, nrm[a]);
            nrm[a] = fmaf(hv.z, hv.z, nrm[a]);
            nrm[a] = fmaf(hv.w, hv.w, nrm[a]);
        }
    }
    #pragma unroll
    for (int a = 0; a < APW; ++a) {
        int atom = abase + a;
        if (atom < N) {
            pa[(size_t)atom * DDIM + lane] = accp[a];
            qa[(size_t)atom * DDIM + lane] = accq[a];
            if (lane == 0) na[atom] = sqrtf(nrm[a]);
        }
    }
}

// ---------------- bond init (from atom projections) + layer-0 proj ----------------
// 512 threads = 8 waves; lane = bond; wave w owns 8-feature slice [8w, 8w+8).
// ps written as packed bf16 (uint4 per 8 features).
__global__ void __launch_bounds__(512) bond_init2_k(
    const float* __restrict__ AF, const int* __restrict__ row, const int* __restrict__ col,
    const float* __restrict__ pa, const float* __restrict__ qa, const float* __restrict__ na,
    const float* __restrict__ b1, const float* __restrict__ w2, const float* __restrict__ b2,
    const float* __restrict__ w1p /*[192][64] layer0 mw1*/,
    float* __restrict__ x, int* __restrict__ bt,
    float* __restrict__ pd, uint4* __restrict__ ps, int E) {
    __shared__ float hbuf[EPB][DDIM + 1];
    __shared__ float dotb[EPB][8];
    int nEB = (E + EPB - 1) / EPB;
    int lb = xcd_logical_block();
    if (lb >= nEB) return;
    int tid = threadIdx.x;
    int lane = tid & 63;
    int w = __builtin_amdgcn_readfirstlane((int)(tid >> 6));   // 0..7
    int e = lb * EPB + lane;
    bool ok = e < E;
    int eidx = ok ? e : 0;
    int r = row[eidx], c = col[eidx];
    int j0 = w * 8;

    // partial dot over K-chunk [16w, 16w+16)
    {
        const float* hi = AF + (size_t)r * HDIM + w * 16;
        const float* hj = AF + (size_t)c * HDIM + w * 16;
        float d = 0.f;
        #pragma unroll
        for (int k = 0; k < 16; k += 4) {
            float4 a4 = ld4(hi + k), b4 = ld4(hj + k);
            d += a4.x * b4.x + a4.y * b4.y + a4.z * b4.z + a4.w * b4.w;
        }
        dotb[lane][w] = d;
    }

    // layer-1 hidden slice: silu(pa[r] + qa[c] + b1)
    {
        const float* pr = pa + (size_t)r * DDIM + j0;
        const float* qc = qa + (size_t)c * DDIM + j0;
        float4 p0 = ld4(pr + 0), p1 = ld4(pr + 4);
        float4 q0 = ld4(qc + 0), q1 = ld4(qc + 4);
        hbuf[lane][j0 + 0] = silu_f(p0.x + q0.x + b1[j0 + 0]);
        hbuf[lane][j0 + 1] = silu_f(p0.y + q0.y + b1[j0 + 1]);
        hbuf[lane][j0 + 2] = silu_f(p0.z + q0.z + b1[j0 + 2]);
        hbuf[lane][j0 + 3] = silu_f(p0.w + q0.w + b1[j0 + 3]);
        hbuf[lane][j0 + 4] = silu_f(p1.x + q1.x + b1[j0 + 4]);
        hbuf[lane][j0 + 5] = silu_f(p1.y + q1.y + b1[j0 + 5]);
        hbuf[lane][j0 + 6] = silu_f(p1.z + q1.z + b1[j0 + 6]);
        hbuf[lane][j0 + 7] = silu_f(p1.w + q1.w + b1[j0 + 7]);
    }
    __syncthreads();

    if (w == 0) {
        float dot = dotb[lane][0] + dotb[lane][1] + dotb[lane][2] + dotb[lane][3]
                  + dotb[lane][4] + dotb[lane][5] + dotb[lane][6] + dotb[lane][7];
        float nr = fmaxf(na[r], 1e-8f), nc = fmaxf(na[c], 1e-8f);
        float sim = dot / (nr * nc);
        int t = 0;
        if (sim > 0.8f) t = 1;
        if (sim > 0.9f) t = 2;
        if (sim < 0.3f) t = 3;
        if (ok) bt[e] = t;
    }

    // layer-2: x = h @ w2 + b2 (K=64 from LDS)
    float o[8];
    #pragma unroll
    for (int jj = 0; jj < 8; ++jj) o[jj] = b2[j0 + jj];
    #pragma unroll 4
    for (int k = 0; k < DDIM; ++k) {
        float hk = hbuf[lane][k];
        const float* wk = w2 + (size_t)k * DDIM + j0;
        #pragma unroll
        for (int jj = 0; jj < 8; ++jj) o[jj] = fmaf(hk, wk[jj], o[jj]);
    }
    if (ok) {
        float* xr = x + (size_t)e * DDIM + j0;
        st4(xr + 0, make_float4(o[0], o[1], o[2], o[3]));
        st4(xr + 4, make_float4(o[4], o[5], o[6], o[7]));
    }
    __syncthreads();            // all reads of hbuf (h) done
    #pragma unroll
    for (int jj = 0; jj < 8; ++jj) hbuf[lane][j0 + jj] = o[jj];   // x row
    __syncthreads();

    // proj (layer 0): pd = x@W1[0:64] (fp32), ps = x@W1[64:128] (bf16 packed)
    float apd[8], aps[8];
    #pragma unroll
    for (int jj = 0; jj < 8; ++jj) { apd[jj] = 0.f; aps[jj] = 0.f; }
    #pragma unroll 4
    for (int k = 0; k < DDIM; ++k) {
        float xk = hbuf[lane][k];
        const float* wd = w1p + (size_t)k * DDIM + j0;
        const float* wsv = w1p + (size_t)(DDIM + k) * DDIM + j0;
        #pragma unroll
        for (int jj = 0; jj < 8; ++jj) {
            apd[jj] = fmaf(xk, wd[jj], apd[jj]);
            aps[jj] = fmaf(xk, wsv[jj], aps[jj]);
        }
    }
    if (ok) {
        float* pr = pd + (size_t)e * DDIM + j0;
        st4(pr + 0, make_float4(apd[0], apd[1], apd[2], apd[3]));
        st4(pr + 4, make_float4(apd[4], apd[5], apd[6], apd[7]));
        ps[(size_t)e * 8 + w] = pack8(aps);
    }
}

// proj (x from global) — fallback path only (used if ws too small for pd2/ps2)
__global__ void __launch_bounds__(256) proj_k(const float* __restrict__ x,
                                              const float* __restrict__ w1 /*[192][64]*/,
                                              float* __restrict__ pd, uint4* __restrict__ ps,
                                              int E) {
    int lane = threadIdx.x & 63;
    int w = __builtin_amdgcn_readfirstlane((int)(threadIdx.x >> 6));
    int e = blockIdx.x * EPB + lane;
    bool ok = e < E;
    int eidx = ok ? e : 0;
    int j0 = w * 16;
    const float* xr = x + (size_t)eidx * DDIM;

    float apd[16], aps[16];
    #pragma unroll
    for (int jj = 0; jj < 16; ++jj) { apd[jj] = 0.f; aps[jj] = 0.f; }
    #pragma unroll 2
    for (int c = 0; c < 16; ++c) {
        float4 v = ld4(xr + c * 4);
        float xv[4] = {v.x, v.y, v.z, v.w};
        #pragma unroll
        for (int kk = 0; kk < 4; ++kk) {
            int k = c * 4 + kk;
            const float* wd = w1 + (size_t)k * DDIM + j0;
            const float* wsv = w1 + (size_t)(DDIM + k) * DDIM + j0;
            #pragma unroll
            for (int jj = 0; jj < 16; ++jj) {
                apd[jj] = fmaf(xv[kk], wd[jj], apd[jj]);
                aps[jj] = fmaf(xv[kk], wsv[jj], aps[jj]);
            }
        }
    }
    if (ok) {
        float* pr = pd + (size_t)e * DDIM + j0;
        st4(pr + 0,  make_float4(apd[0],  apd[1],  apd[2],  apd[3]));
        st4(pr + 4,  make_float4(apd[4],  apd[5],  apd[6],  apd[7]));
        st4(pr + 8,  make_float4(apd[8],  apd[9],  apd[10], apd[11]));
        st4(pr + 12, make_float4(apd[12], apd[13], apd[14], apd[15]));
        ps[(size_t)e * 8 + 2 * w + 0] = pack8(aps + 0);
        ps[(size_t)e * 8 + 2 * w + 1] = pack8(aps + 8);
    }
}

// ---------------- fused gather + update (+ optional next-layer proj) ----------------
// 512 threads = 8 waves. P1: 8 thr/bond gather s (ps in bf16) -> sb. P3': h = silu(...).
// P4: x += h@Wu2 + ub2. P5 (if w1n): pdn (fp32) / psn (bf16) = x_new @ w1n from LDS.
__global__ void __launch_bounds__(512) layer_k(
    float* __restrict__ x, const float* __restrict__ pd, const uint4* __restrict__ ps,
    const float* __restrict__ tt_l, const int* __restrict__ bt,
    const int* __restrict__ offs, const int* __restrict__ srclist,
    const int* __restrict__ cnt,
    const float* __restrict__ w2u, const float* __restrict__ b2u,
    const float* __restrict__ uw1 /*[128][64], rows 64..127 used*/,
    const float* __restrict__ ub1,
    const float* __restrict__ uw2 /*[64][64]*/, const float* __restrict__ ub2,
    const float* __restrict__ w1n /* next-layer mw1 or nullptr */,
    float* __restrict__ pdn, uint4* __restrict__ psn, int E) {
    __shared__ float sb[EPB][DDIM + 1];
    int nEB = (E + EPB - 1) / EPB;
    int lb = xcd_logical_block();
    if (lb >= nEB) return;
    int tid = threadIdx.x;
    int lane = tid & 63;
    int w = __builtin_amdgcn_readfirstlane((int)(tid >> 6));   // 0..7
    int e = lb * EPB + lane;
    bool ok = e < E;
    int eidx = ok ? e : 0;
    int j0 = w * 8;

    // ---- P1: gather (8 threads per bond, 8 features each), 4-way unrolled ----
    {
        int d_local = tid >> 3, q = tid & 7;
        int d = lb * EPB + d_local;
        if (d < E) {
            int jq = q * 8;
            const float* pr = pd + (size_t)d * DDIM + jq;
            const float* tp = tt_l + (size_t)bt[d] * DDIM + jq;
            float4 b0 = add4(ld4(pr + 0), ld4(tp + 0));
            float4 b1 = add4(ld4(pr + 4), ld4(tp + 4));
            float4 s0 = make_float4(0, 0, 0, 0), s1 = s0;
            int p0 = offs[d], p1 = offs[d + 1];
            int p = p0;
            for (; p + 4 <= p1; p += 4) {
                uint4 u0 = ps[(size_t)srclist[p + 0] * 8 + q];
                uint4 u1 = ps[(size_t)srclist[p + 1] * 8 + q];
                uint4 u2 = ps[(size_t)srclist[p + 2] * 8 + q];
                uint4 u3 = ps[(size_t)srclist[p + 3] * 8 + q];
                float4 a, b;
                unpack8(u0, a, b);
                silu_acc4(s0, add4(b0, a));
                silu_acc4(s1, add4(b1, b));
                unpack8(u1, a, b);
                silu_acc4(s0, add4(b0, a));
                silu_acc4(s1, add4(b1, b));
                unpack8(u2, a, b);
                silu_acc4(s0, add4(b0, a));
                silu_acc4(s1, add4(b1, b));
                unpack8(u3, a, b);
                silu_acc4(s0, add4(b0, a));
                silu_acc4(s1, add4(b1, b));
            }
            for (; p < p1; ++p) {
                uint4 u0 = ps[(size_t)srclist[p] * 8 + q];
                float4 a, b;
                unpack8(u0, a, b);
                silu_acc4(s0, add4(b0, a));
                silu_acc4(s1, add4(b1, b));
            }
            st4(&sb[d_local][jq + 0], s0);
            st4(&sb[d_local][jq + 4], s1);
        }
    }
    __syncthreads();

    // ---- P3': h = silu(inv*(s@W2u) + inv*deg*b2u + x@Wu1[64:] + ub1) ----
    float degf = (float)cnt[eidx];
    float inv = 1.0f / fmaxf(degf, 1.0f);
    const float* xr = x + (size_t)eidx * DDIM;
    float h[8];
    {
        float sm[8];
        #pragma unroll
        for (int jj = 0; jj < 8; ++jj) sm[jj] = 0.f;
        #pragma unroll 4
        for (int k = 0; k < DDIM; ++k) {
            float sk = sb[lane][k];
            const float* wk = w2u + (size_t)k * DDIM + j0;
            #pragma unroll
            for (int jj = 0; jj < 8; ++jj) sm[jj] = fmaf(sk, wk[jj], sm[jj]);
        }
        float ah[8];
        float dib = degf * inv;
        #pragma unroll
        for (int jj = 0; jj < 8; ++jj)
            ah[jj] = fmaf(inv, sm[jj], fmaf(dib, b2u[j0 + jj], ub1[j0 + jj]));
        #pragma unroll 2
        for (int c = 0; c < 16; ++c) {
            float4 v = ld4(xr + c * 4);
            float xv[4] = {v.x, v.y, v.z, v.w};
            #pragma unroll
            for (int kk = 0; kk < 4; ++kk) {
                const float* wk = uw1 + (size_t)(DDIM + c * 4 + kk) * DDIM + j0;
                #pragma unroll
                for (int jj = 0; jj < 8; ++jj) ah[jj] = fmaf(xv[kk], wk[jj], ah[jj]);
            }
        }
        #pragma unroll
        for (int jj = 0; jj < 8; ++jj) h[jj] = silu_f(ah[jj]);
    }
    __syncthreads();     // all reads of sb (s) done
    #pragma unroll
    for (int jj = 0; jj < 8; ++jj) sb[lane][j0 + jj] = h[jj];
    __syncthreads();

    // ---- P4: u-layer2 + residual ----
    float xn[8];
    {
        float o[8];
        #pragma unroll
        for (int jj = 0; jj < 8; ++jj) o[jj] = ub2[j0 + jj];
        #pragma unroll 4
        for (int k = 0; k < DDIM; ++k) {
            float hk = sb[lane][k];
            const float* wk = uw2 + (size_t)k * DDIM + j0;
            #pragma unroll
            for (int jj = 0; jj < 8; ++jj) o[jj] = fmaf(hk, wk[jj], o[jj]);
        }
        float4 x0 = ld4(xr + j0), x1 = ld4(xr + j0 + 4);
        xn[0] = x0.x + o[0]; xn[1] = x0.y + o[1];
        xn[2] = x0.z + o[2]; xn[3] = x0.w + o[3];
        xn[4] = x1.x + o[4]; xn[5] = x1.y + o[5];
        xn[6] = x1.z + o[6]; xn[7] = x1.w + o[7];
        if (ok) {
            float* xw = x + (size_t)e * DDIM + j0;
            st4(xw + 0, make_float4(xn[0], xn[1], xn[2], xn[3]));
            st4(xw + 4, make_float4(xn[4], xn[5], xn[6], xn[7]));
        }
    }

    // ---- P5 (optional): next-layer proj from x_new in LDS ----
    if (w1n != nullptr) {
        __syncthreads();     // all reads of sb (h) done
        #pragma unroll
        for (int jj = 0; jj < 8; ++jj) sb[lane][j0 + jj] = xn[jj];
        __syncthreads();
        float apd[8], aps[8];
        #pragma unroll
        for (int jj = 0; jj < 8; ++jj) { apd[jj] = 0.f; aps[jj] = 0.f; }
        #pragma unroll 4
        for (int k = 0; k < DDIM; ++k) {
            float xk = sb[lane][k];
            const float* wd = w1n + (size_t)k * DDIM + j0;
            const float* wsv = w1n + (size_t)(DDIM + k) * DDIM + j0;
            #pragma unroll
            for (int jj = 0; jj < 8; ++jj) {
                apd[jj] = fmaf(xk, wd[jj], apd[jj]);
                aps[jj] = fmaf(xk, wsv[jj], aps[jj]);
            }
        }
        if (ok) {
            float* pr = pdn + (size_t)e * DDIM + j0;
            st4(pr + 0, make_float4(apd[0], apd[1], apd[2], apd[3]));
            st4(pr + 4, make_float4(apd[4], apd[5], apd[6], apd[7]));
            psn[(size_t)e * 8 + w] = pack8(aps);
        }
    }
}

// ---------------- pooling ----------------
__global__ void __launch_bounds__(256) pool_k(
    const float* __restrict__ x, const int* __restrict__ row,
    const int* __restrict__ batch, float* __restrict__ gfeat, int E) {
    int lane = threadIdx.x & 63;
    int esub = threadIdx.x >> 6;       // 0..3
    int e0 = blockIdx.x * PCHUNK;
    int e1 = min(e0 + PCHUNK, E);
    float sum = 0.f;
    int cur = -1;
    for (int e = e0 + esub; e < e1; e += 4) {
        int g = batch[row[e]];         // wave-uniform -> scalar load
        if (g != cur) {
            if (cur >= 0)
                __hip_atomic_fetch_add(&gfeat[cur * DDIM + lane], sum,
                                       __ATOMIC_RELAXED, __HIP_MEMORY_SCOPE_AGENT);
            cur = g;
            sum = 0.f;
        }
        sum += x[(size_t)e * DDIM + lane];
    }
    if (cur >= 0)
        __hip_atomic_fetch_add(&gfeat[cur * DDIM + lane], sum,
                               __ATOMIC_RELAXED, __HIP_MEMORY_SCOPE_AGENT);
}

static __device__ __forceinline__ int lower_bound_bb(const int* __restrict__ row,
                                                     const int* __restrict__ batch,
                                                     int E, int g) {
    int lo = 0, hi = E;
    while (lo < hi) {
        int m = (lo + hi) >> 1;
        if (batch[row[m]] < g) lo = m + 1; else hi = m;
    }
    return lo;
}

__global__ void __launch_bounds__(64) pool_final_k(
    const int* __restrict__ row, const int* __restrict__ batch,
    float* __restrict__ gfeat, int E) {
    int g = blockIdx.x, j = threadIdx.x;
    int s = lower_bound_bb(row, batch, E, g);
    int t = lower_bound_bb(row, batch, E, g + 1);
    float cnt = fmaxf((float)(t - s), 1.0f);
    gfeat[g * DDIM + j] /= cnt;
}

extern "C" void kernel_launch(void* const* d_in, const int* in_sizes, int n_in,
                              void* d_out, int out_size, void* d_ws, size_t ws_size,
                              hipStream_t stream) {
    (void)n_in; (void)out_size;
    const float* AF    = (const float*)d_in[0];
    const int*   batch = (const int*)d_in[3];
    const int*   edge_index      = (const int*)d_in[4];
    const int*   bond_edge_index = (const int*)d_in[5];
    const float* iw1 = (const float*)d_in[6];
    const float* ib1 = (const float*)d_in[7];
    const float* iw2 = (const float*)d_in[8];
    const float* ib2 = (const float*)d_in[9];
    const float* emb = (const float*)d_in[10];
    const float* mw1 = (const float*)d_in[11];
    const float* mb1 = (const float*)d_in[12];
    const float* mw2 = (const float*)d_in[13];
    const float* mb2 = (const float*)d_in[14];
    const float* uw1 = (const float*)d_in[15];
    const float* ub1 = (const float*)d_in[16];
    const float* uw2 = (const float*)d_in[17];
    const float* ub2 = (const float*)d_in[18];

    const int N  = in_sizes[0] / HDIM;
    const int E  = in_sizes[4] / 2;
    const int BE = in_sizes[5] / 2;
    const int NB = (E + 255) / 256;
    const int EB = (E + EPB - 1) / EPB;
    const int AB = (N + 4 * APW - 1) / (4 * APW);   // atom blocks (32 atoms/block)
    const int EBS = ((EB + 7) / 8) * 8;             // swizzled grid (multiple of 8)
    const int PB = (E + PCHUNK - 1) / PCHUNK;       // pooling blocks

    float* xout  = (float*)d_out;                 // [E,64]
    float* gfeat = xout + (size_t)E * DDIM;       // [16,64]

    // workspace layout
    char* w = (char*)d_ws;
    float* tt       = (float*)w;  w += sizeof(float) * 2 * NTYPES * DDIM;
    float* w2u      = (float*)w;  w += sizeof(float) * 2 * DDIM * DDIM;
    float* b2u      = (float*)w;  w += sizeof(float) * 2 * DDIM;
    int*   cnt      = (int*)w;    w += sizeof(int) * E;
    int*   offs     = (int*)w;    w += sizeof(int) * (E + 1);
    int*   cursor   = (int*)w;    w += sizeof(int) * E;
    int*   bt       = (int*)w;    w += sizeof(int) * E;
    int*   bsum     = (int*)w;    w += sizeof(int) * 1024;
    int*   bpre     = (int*)w;    w += sizeof(int) * 1024;
    int*   srclist  = (int*)w;    w += sizeof(int) * BE;
    w = (char*)(((uintptr_t)w + 15) & ~(uintptr_t)15);
    float* pd       = (float*)w;  w += sizeof(float) * (size_t)E * DDIM;
    uint4* ps       = (uint4*)w;  w += sizeof(unsigned short) * (size_t)E * DDIM;
    float* pa       = (float*)w;  w += sizeof(float) * (size_t)N * DDIM;
    float* qa       = (float*)w;  w += sizeof(float) * (size_t)N * DDIM;
    float* na       = (float*)w;  w += sizeof(float) * (size_t)N;
    w = (char*)(((uintptr_t)w + 15) & ~(uintptr_t)15);
    // optional second proj buffers (fused-proj path)
    float* pd2      = (float*)w;  w += sizeof(float) * (size_t)E * DDIM;
    uint4* ps2      = (uint4*)w;  w += sizeof(unsigned short) * (size_t)E * DDIM;
    bool fuse_proj = ((size_t)(w - (char*)d_ws) <= ws_size);

    const int* row  = edge_index;
    const int* col  = edge_index + E;
    const int* bsrc = bond_edge_index;
    const int* bdst = bond_edge_index + BE;

    // CSR build
    hipMemsetAsync(cnt, 0, (size_t)E * sizeof(int), stream);
    count_k<<<(BE + 255) / 256, 256, 0, stream>>>(bdst, cnt, BE);
    bsum_k<<<NB, 256, 0, stream>>>(cnt, bsum, E);
    bscan_k<<<1, 1024, 0, stream>>>(bsum, bpre, NB);
    offs_k<<<NB, 256, 0, stream>>>(cnt, bpre, offs, cursor, E);
    scatter_k<<<(BE + 255) / 256, 256, 0, stream>>>(bsrc, bdst, cursor, srclist, BE);

    // constants: bond-type embeddings + fused mm weights
    tt2_k<<<2 * NTYPES, 64, 0, stream>>>(emb, mw1, mb1, tt);
    fuse_k<<<2 * 64, 64, 0, stream>>>(mw2, mb2, uw1, w2u, b2u);

    // atom projections, then bond init + layer-0 proj
    atom_proj_k<<<AB, 256, 0, stream>>>(AF, iw1, pa, qa, na, N);
    bond_init2_k<<<EBS, 512, 0, stream>>>(AF, row, col, pa, qa, na, ib1, iw2, ib2,
                                          mw1 /* layer 0 */, xout, bt, pd, ps, E);

    if (fuse_proj) {
        // layer 0: fused next-layer proj -> pd2/ps2
        layer_k<<<EBS, 512, 0, stream>>>(
            xout, pd, ps, tt, bt, offs, srclist, cnt,
            w2u, b2u, uw1, ub1, uw2, ub2,
            mw1 + (size_t)192 * 64, pd2, ps2, E);
        // layer 1: no proj
        layer_k<<<EBS, 512, 0, stream>>>(
            xout, pd2, ps2, tt + NTYPES * DDIM, bt, offs, srclist, cnt,
            w2u + DDIM * DDIM, b2u + DDIM,
            uw1 + (size_t)128 * 64, ub1 + DDIM,
            uw2 + (size_t)DDIM * DDIM, ub2 + DDIM,
            nullptr, nullptr, nullptr, E);
    } else {
        for (int l = 0; l < 2; ++l) {
            if (l > 0)
                proj_k<<<EB, 256, 0, stream>>>(xout, mw1 + (size_t)l * 192 * 64, pd, ps, E);
            layer_k<<<EBS, 512, 0, stream>>>(
                xout, pd, ps, tt + (size_t)l * NTYPES * DDIM, bt, offs, srclist, cnt,
                w2u + (size_t)l * DDIM * DDIM, b2u + (size_t)l * DDIM,
                uw1 + (size_t)l * 128 * 64, ub1 + (size_t)l * DDIM,
                uw2 + (size_t)l * DDIM * DDIM, ub2 + (size_t)l * DDIM,
                nullptr, nullptr, nullptr, E);
        }
    }

    hipMemsetAsync(gfeat, 0, NGRAPHS * DDIM * sizeof(float), stream);
    pool_k<<<PB, 256, 0, stream>>>(xout, row, batch, gfeat, E);
    pool_final_k<<<NGRAPHS, 64, 0, stream>>>(row, batch, gfeat, E);
}